// Round 8
// baseline (8708.511 us; speedup 1.0000x reference)
//
#include <hip/hip_runtime.h>
#include <hip/hip_cooperative_groups.h>

namespace cg = cooperative_groups;

// DecoderLSTM: V=32000 E=512 H=1024 B=64 T=32, fp32, greedy decode.
// Design (round 8): whole decode loop in ONE cooperative kernel.
//  r7 analysis: per-step compute ~20us but 69us measured -> ~50us/step is
//  launch/gap overhead across 4 dependent graph nodes. Fix: 1 cooperative
//  kernel, 4 grid.sync() phases/step (refine | gates | cell | logits),
//  c-state in registers. Math is bit-identical to the passing r7 kernels.
//  Fallbacks: coop launch error -> proven per-step path; small ws -> f32.

#define VSZ 32000
#define ESZ 512
#define HSZ 1024
#define BSZ 64
#define TSZ 32
#define G4H 4096

typedef unsigned short u16;
typedef unsigned int u32;
typedef unsigned long long u64;
typedef __attribute__((ext_vector_type(8))) short bf16x8;
typedef __attribute__((ext_vector_type(4))) float f32x4;

__device__ __forceinline__ unsigned ordf(float f) {
  unsigned u = __float_as_uint(f);
  return (u & 0x80000000u) ? ~u : (u | 0x80000000u);  // monotone float->uint
}
__device__ __forceinline__ u16 f2bf(float f) {  // f32 -> bf16 RNE
  u32 u = __float_as_uint(f);
  return (u16)((u + 0x7FFFu + ((u >> 16) & 1u)) >> 16);
}
__device__ __forceinline__ float bf2f(u16 s) {
  return __uint_as_float(((u32)s) << 16);
}
// 3-way bf16 split of a double (captures ~24 bits)
__device__ __forceinline__ void split3(double v, u16& s0, u16& s1, u16& s2) {
  s0 = f2bf((float)v);
  double r = v - (double)bf2f(s0);
  s1 = f2bf((float)r);
  double r2 = r - (double)bf2f(s1);
  s2 = f2bf((float)r2);
}

// pack h (f64) into HA2 (logits A: single bf16) and HA3 (gates A: 3 terms)
__device__ __forceinline__ void pack_h(int j, int b, double h,
                                       u16* __restrict__ HA2,
                                       u16* __restrict__ HA3) {
  u16 s0, s1, s2;
  split3(h, s0, s1, s2);
  int kc = j >> 5, kj = j & 31;
  int lane = (b & 15) | ((kj >> 3) << 4);
  int Mt = b >> 4;
  int e = kj & 7;
  HA2[(size_t)(kc * 4 + Mt) * 512 + lane * 8 + e] = s0;
  size_t b3 = ((size_t)(kc * 4 + Mt) * 3) * 512 + lane * 8 + e;
  HA3[b3] = s0;
  HA3[b3 + 512] = s1;
  HA3[b3 + 1024] = s2;
}

// sorted-4 (desc) insert, branchless
__device__ __forceinline__ void ins4(u64 v, u64& t0, u64& t1, u64& t2,
                                     u64& t3) {
  bool g0 = v > t0, g1 = v > t1, g2 = v > t2, g3 = v > t3;
  t3 = g2 ? t2 : (g3 ? v : t3);
  t2 = g1 ? t1 : (g2 ? v : t2);
  t1 = g0 ? t0 : (g1 ? v : t1);
  t0 = g0 ? v : t0;
}
// top-4 of two sorted-desc 4-lists (bitonic)
__device__ __forceinline__ void merge4(u64& a0, u64& a1, u64& a2, u64& a3,
                                       u64 b0, u64 b1, u64 b2, u64 b3) {
  u64 m0 = a0 > b3 ? a0 : b3;
  u64 m1 = a1 > b2 ? a1 : b2;
  u64 m2 = a2 > b1 ? a2 : b1;
  u64 m3 = a3 > b0 ? a3 : b0;
  u64 e0 = m0 > m2 ? m0 : m2, e2 = m0 > m2 ? m2 : m0;
  u64 e1 = m1 > m3 ? m1 : m3, e3 = m1 > m3 ? m3 : m1;
  a0 = e0 > e1 ? e0 : e1;
  a1 = e0 > e1 ? e1 : e0;
  a2 = e2 > e3 ? e2 : e3;
  a3 = e2 > e3 ? e3 : e2;
}

// ---- init: c0,h0 -> f64 state; pack h0 frags (cT64 kept for fallback) ----
__global__ __launch_bounds__(256) void k_init(const float* __restrict__ h0,
                                              const float* __restrict__ c0,
                                              double* __restrict__ cT64,
                                              double* __restrict__ h64,
                                              u16* __restrict__ HA2,
                                              u16* __restrict__ HA3) {
  int idx = blockIdx.x * 256 + threadIdx.x;  // 65536
  int j = idx >> 6, b = idx & 63;
  double h = (double)h0[b * HSZ + j];
  cT64[idx] = (double)c0[b * HSZ + j];
  h64[idx] = h;
  pack_h(j, b, h, HA2, HA3);
}

// ---- pack Wout (f32 [K=1024][V]) into logits B single bf16, once ----
// WBL layout: [Nt=2000][kc=32][lane=64][e=8]
__global__ __launch_bounds__(256) void k_wpackL(const float* __restrict__ Wout,
                                                u16* __restrict__ WBL) {
  __shared__ float ls[32][64];
  int tid = threadIdx.x;
  int j0 = blockIdx.x * 64;
  int Nt0 = blockIdx.x * 4;
  for (int kc = 0; kc < 32; ++kc) {
    __syncthreads();
    #pragma unroll
    for (int rr = 0; rr < 8; ++rr) {
      int row = rr * 4 + (tid >> 6);
      ls[row][tid & 63] = Wout[(size_t)(kc * 32 + row) * VSZ + j0 + (tid & 63)];
    }
    __syncthreads();
    int lane = tid & 63, Ntl = tid >> 6;
    int col = Ntl * 16 + (lane & 15);
    int kb = (lane >> 4) * 8;
    alignas(16) u16 hibuf[8];
    #pragma unroll
    for (int e = 0; e < 8; ++e) hibuf[e] = f2bf(ls[kb + e][col]);
    size_t base = ((size_t)((Nt0 + Ntl) * 32 + kc)) * 512 + lane * 8;
    *(bf16x8*)&WBL[base] = *(const bf16x8*)hibuf;
  }
}

// ---- pack [Wx;Wh] (f32 [K=1536][4096]) into gates B 3-term, once ----
// WBG layout: [Nt=256][kc=48][term=3][lane=64][e=8]
__global__ __launch_bounds__(256) void k_wpackG(const float* __restrict__ Wx,
                                                const float* __restrict__ Wh,
                                                u16* __restrict__ WBG) {
  int tid = threadIdx.x;
  int Nt = blockIdx.x;  // 256 blocks
  int lane = tid & 63, w = tid >> 6;
  int col = Nt * 16 + (lane & 15);
  for (int i = 0; i < 12; ++i) {
    int kc = w * 12 + i;
    int kb = kc * 32 + (lane >> 4) * 8;
    alignas(16) u16 b0[8], b1[8], b2[8];
    #pragma unroll
    for (int e = 0; e < 8; ++e) {
      int k = kb + e;
      float v = (k < ESZ) ? Wx[(size_t)k * G4H + col]
                          : Wh[(size_t)(k - ESZ) * G4H + col];
      u16 s0, s1, s2;
      split3((double)v, s0, s1, s2);
      b0[e] = s0; b1[e] = s1; b2[e] = s2;
    }
    size_t base = ((size_t)(Nt * 48 + kc) * 3) * 512 + lane * 8;
    *(bf16x8*)&WBG[base] = *(const bf16x8*)b0;
    *(bf16x8*)&WBG[base + 512] = *(const bf16x8*)b1;
    *(bf16x8*)&WBG[base + 1024] = *(const bf16x8*)b2;
  }
}

// ================= cooperative main: whole T=32 loop, 256 blocks ==========
__global__ __launch_bounds__(256) void k_main(
    const int* __restrict__ sos, const float* __restrict__ emb,
    const u16* __restrict__ WBG, const u16* __restrict__ WBL,
    const float* __restrict__ Wout, const float* __restrict__ bx,
    const float* __restrict__ bh, const float* __restrict__ bout,
    const float* __restrict__ c0, double* __restrict__ h64,
    u16* __restrict__ HA2, u16* __restrict__ HA3, double* __restrict__ gG,
    u64* __restrict__ p2, int* __restrict__ tokb, float* __restrict__ out) {
  cg::grid_group grid = cg::this_grid();
  __shared__ int s_tok[64];
  __shared__ u64 sm[256][4];
  __shared__ double rr[256][4];
  __shared__ int s_i[4];
  int blk = blockIdx.x, tid = threadIdx.x, lane = tid & 63, w = tid >> 6;
  const int nks = 4;  // gridDim fixed at 256 = 4 ksplits x 64 Nt-groups

  // cell-state in register: thread (blk<256, tid) owns idx = blk*256+tid
  int cidx = blk * 256 + tid;
  int cj = cidx >> 6, cb = cidx & 63;
  double creg = (double)c0[cb * HSZ + cj];

  for (int t = 0; t < TSZ; ++t) {
    // ---- phase R: exact top-4 refine of step t-1 (blocks 0..63) ----
    if (t > 0 && blk < 64) {
      int b = blk;
      u64 t0 = 0, t1 = 0, t2 = 0, t3 = 0;
      for (int i = tid; i < 2000; i += 256) {
        u64 x = p2[((size_t)b * 2000 + i) * 2];
        u64 y = p2[((size_t)b * 2000 + i) * 2 + 1];
        ins4(x, t0, t1, t2, t3);
        ins4(y, t0, t1, t2, t3);
      }
      sm[tid][0] = t0; sm[tid][1] = t1; sm[tid][2] = t2; sm[tid][3] = t3;
      __syncthreads();
      for (int off = 128; off > 0; off >>= 1) {
        if (tid < off) {
          u64 a0 = sm[tid][0], a1 = sm[tid][1], a2 = sm[tid][2],
              a3 = sm[tid][3];
          merge4(a0, a1, a2, a3, sm[tid + off][0], sm[tid + off][1],
                 sm[tid + off][2], sm[tid + off][3]);
          sm[tid][0] = a0; sm[tid][1] = a1; sm[tid][2] = a2; sm[tid][3] = a3;
        }
        __syncthreads();
      }
      if (tid < 4) s_i[tid] = (int)(~(u32)(sm[0][tid] & 0xFFFFFFFFull));
      __syncthreads();
      int i0 = s_i[0], i1 = s_i[1], i2 = s_i[2], i3 = s_i[3];
      double a0 = 0.0, a1 = 0.0, a2 = 0.0, a3 = 0.0;
      #pragma unroll
      for (int q = 0; q < 4; ++q) {
        int k = tid * 4 + q;
        double h = h64[(size_t)k * 64 + b];
        const float* wr = Wout + (size_t)k * VSZ;
        a0 += h * (double)wr[i0];
        a1 += h * (double)wr[i1];
        a2 += h * (double)wr[i2];
        a3 += h * (double)wr[i3];
      }
      rr[tid][0] = a0; rr[tid][1] = a1; rr[tid][2] = a2; rr[tid][3] = a3;
      __syncthreads();
      for (int off = 128; off > 0; off >>= 1) {
        if (tid < off) {
          rr[tid][0] += rr[tid + off][0];
          rr[tid][1] += rr[tid + off][1];
          rr[tid][2] += rr[tid + off][2];
          rr[tid][3] += rr[tid + off][3];
        }
        __syncthreads();
      }
      if (tid == 0) {
        double v0 = rr[0][0] + (double)bout[i0];
        double v1 = rr[0][1] + (double)bout[i1];
        double v2 = rr[0][2] + (double)bout[i2];
        double v3 = rr[0][3] + (double)bout[i3];
        double bv = v0; int bi = i0;
        if (v1 > bv || (v1 == bv && i1 < bi)) { bv = v1; bi = i1; }
        if (v2 > bv || (v2 == bv && i2 < bi)) { bv = v2; bi = i2; }
        if (v3 > bv || (v3 == bv && i3 < bi)) { bv = v3; bi = i3; }
        tokb[b] = bi;
      }
    }
    grid.sync();

    // ---- phase G: gates 6-term split-bf16 MFMA (k-split nks=4) ----
    {
      const int* tok = (t == 0) ? sos : tokb;
      if (tid < 64) s_tok[tid] = tok[tid];
      __syncthreads();
      int Ntg = blk & 63, ks = blk >> 6;  // 256 blocks = 4 x 64
      int Nt = Ntg * 4 + w;
      int myTok[4];
      #pragma unroll
      for (int Mt = 0; Mt < 4; ++Mt) myTok[Mt] = s_tok[Mt * 16 + (lane & 15)];
      double big[4][4];
      f32x4 accs[4];
      #pragma unroll
      for (int Mt = 0; Mt < 4; ++Mt) {
        accs[Mt] = (f32x4){0.f, 0.f, 0.f, 0.f};
        #pragma unroll
        for (int r = 0; r < 4; ++r) big[Mt][r] = 0.0;
      }
      const f32x4 zz = {0.f, 0.f, 0.f, 0.f};
      const int nch = 48 / nks;
      for (int i = 0; i < nch; ++i) {
        int kc = ks * nch + i;
        const u16* wb = WBG + ((size_t)(Nt * 48 + kc) * 3) * 512 + lane * 8;
        bf16x8 b0 = *(const bf16x8*)wb;
        bf16x8 b1 = *(const bf16x8*)(wb + 512);
        bf16x8 b2 = *(const bf16x8*)(wb + 1024);
        #pragma unroll
        for (int Mt = 0; Mt < 4; ++Mt) {
          bf16x8 a0, a1, a2;
          if (kc < 16) {  // x from embedding: split on the fly
            const float* p =
                emb + (size_t)myTok[Mt] * ESZ + kc * 32 + (lane >> 4) * 8;
            alignas(16) u16 t0[8], t1[8], t2[8];
            #pragma unroll
            for (int e = 0; e < 8; ++e) {
              u16 s0, s1, s2;
              split3((double)p[e], s0, s1, s2);
              t0[e] = s0; t1[e] = s1; t2[e] = s2;
            }
            a0 = *(const bf16x8*)t0; a1 = *(const bf16x8*)t1;
            a2 = *(const bf16x8*)t2;
          } else {  // x from h: pre-split A-frags
            const u16* ha =
                HA3 + ((size_t)((kc - 16) * 4 + Mt) * 3) * 512 + lane * 8;
            a0 = *(const bf16x8*)ha;
            a1 = *(const bf16x8*)(ha + 512);
            a2 = *(const bf16x8*)(ha + 1024);
          }
          f32x4 tb =
              __builtin_amdgcn_mfma_f32_16x16x32_bf16(a0, b0, zz, 0, 0, 0);
          #pragma unroll
          for (int r = 0; r < 4; ++r) big[Mt][r] += (double)tb[r];
          accs[Mt] = __builtin_amdgcn_mfma_f32_16x16x32_bf16(a1, b0, accs[Mt], 0, 0, 0);
          accs[Mt] = __builtin_amdgcn_mfma_f32_16x16x32_bf16(a0, b1, accs[Mt], 0, 0, 0);
          accs[Mt] = __builtin_amdgcn_mfma_f32_16x16x32_bf16(a1, b1, accs[Mt], 0, 0, 0);
          accs[Mt] = __builtin_amdgcn_mfma_f32_16x16x32_bf16(a2, b0, accs[Mt], 0, 0, 0);
          accs[Mt] = __builtin_amdgcn_mfma_f32_16x16x32_bf16(a0, b2, accs[Mt], 0, 0, 0);
        }
      }
      int col = Nt * 16 + (lane & 15);
      #pragma unroll
      for (int Mt = 0; Mt < 4; ++Mt) {
        #pragma unroll
        for (int r = 0; r < 4; ++r) {
          int b = Mt * 16 + (lane >> 4) * 4 + r;  // C/D map (m89)
          gG[((size_t)ks * G4H + col) * 64 + b] =
              big[Mt][r] + (double)accs[Mt][r];
        }
      }
    }
    grid.sync();

    // ---- phase C: cell (f64), c in register; pack h frags ----
    {
      int j = cj, b = cb;
      double gv[4];
      #pragma unroll
      for (int g = 0; g < 4; ++g) {
        size_t col = (size_t)g * 1024 + j;
        double s = 0.0;
        #pragma unroll
        for (int ks = 0; ks < nks; ++ks)
          s += gG[((size_t)ks * G4H + col) * 64 + b];
        gv[g] = s + (double)bx[col] + (double)bh[col];
      }
      double f = 1.0 / (1.0 + exp(-gv[0]));
      double i = 1.0 / (1.0 + exp(-gv[1]));
      double g = tanh(gv[2]);
      double o = 1.0 / (1.0 + exp(-gv[3]));
      creg = f * creg + i * g;
      double h = o * tanh(creg);
      h64[cidx] = h;
      pack_h(j, b, h, HA2, HA3);
    }
    grid.sync();

    // ---- phase D: logits (single-term bf16 MFMA), grid-stride tiles ----
    {
      float* orow = out + (size_t)t * BSZ * VSZ;
      for (int Nt = blk * 4 + w; Nt < 2000; Nt += 1024) {
        int colw = Nt * 16 + (lane & 15);
        const u16* wbp = WBL + (size_t)Nt * 16384 + lane * 8;
        f32x4 acc[4] = {};
        for (int kc = 0; kc < 32; ++kc) {
          bf16x8 bhv = *(const bf16x8*)(wbp + (size_t)kc * 512);
          const u16* ha = HA2 + (size_t)kc * 2048 + lane * 8;
          #pragma unroll
          for (int Mt = 0; Mt < 4; ++Mt) {
            bf16x8 ah = *(const bf16x8*)(ha + Mt * 512);
            acc[Mt] =
                __builtin_amdgcn_mfma_f32_16x16x32_bf16(ah, bhv, acc[Mt], 0, 0, 0);
          }
        }
        float bo = bout[colw];
        u64 mykey = 0, mykey2 = 0;
        #pragma unroll
        for (int Mt = 0; Mt < 4; ++Mt) {
          #pragma unroll
          for (int r = 0; r < 4; ++r) {
            float v = acc[Mt][r] + bo;
            orow[(size_t)(Mt * 16 + (lane >> 4) * 4 + r) * VSZ + colw] = v;
            u64 kb_ = ((u64)ordf(v) << 32) | (unsigned)(~colw);
            u64 ks_ = 0;
            #pragma unroll
            for (int s = 1; s < 16; s <<= 1) {
              u64 ob = __shfl_xor(kb_, s, 64);
              u64 os = __shfl_xor(ks_, s, 64);
              u64 nb = kb_ > ob ? kb_ : ob;
              u64 lo = kb_ > ob ? ob : kb_;
              u64 s2 = ks_ > os ? ks_ : os;
              kb_ = nb;
              ks_ = lo > s2 ? lo : s2;
            }
            if ((lane & 15) == Mt * 4 + r) { mykey = kb_; mykey2 = ks_; }
          }
        }
        int batch = ((lane & 15) >> 2) * 16 + (lane >> 4) * 4 + (lane & 3);
        size_t slot = (size_t)batch * 2000 + Nt;
        p2[slot * 2] = mykey;
        p2[slot * 2 + 1] = mykey2;
      }
    }
    grid.sync();
  }
}

// ============ per-step proven path (round-7) as coop fallback =============

__global__ __launch_bounds__(256) void k_gates6(
    int t, int nch, const int* __restrict__ sos,
    const int* __restrict__ tokbuf, const float* __restrict__ emb,
    const u16* __restrict__ WBG, const u16* __restrict__ HA3,
    double* __restrict__ gG) {
  __shared__ int s_tok[64];
  int tid = threadIdx.x, lane = tid & 63, w = tid >> 6;
  const int* tok = (t == 0) ? sos : tokbuf;
  if (tid < 64) s_tok[tid] = tok[tid];
  __syncthreads();
  int Ntg = blockIdx.x & 63, ks = blockIdx.x >> 6;
  int Nt = Ntg * 4 + w;
  int myTok[4];
  #pragma unroll
  for (int Mt = 0; Mt < 4; ++Mt) myTok[Mt] = s_tok[Mt * 16 + (lane & 15)];
  double big[4][4];
  f32x4 accs[4];
  #pragma unroll
  for (int Mt = 0; Mt < 4; ++Mt) {
    accs[Mt] = (f32x4){0.f, 0.f, 0.f, 0.f};
    #pragma unroll
    for (int r = 0; r < 4; ++r) big[Mt][r] = 0.0;
  }
  const f32x4 zz = {0.f, 0.f, 0.f, 0.f};
  for (int i = 0; i < nch; ++i) {
    int kc = ks * nch + i;
    const u16* wb = WBG + ((size_t)(Nt * 48 + kc) * 3) * 512 + lane * 8;
    bf16x8 b0 = *(const bf16x8*)wb;
    bf16x8 b1 = *(const bf16x8*)(wb + 512);
    bf16x8 b2 = *(const bf16x8*)(wb + 1024);
    #pragma unroll
    for (int Mt = 0; Mt < 4; ++Mt) {
      bf16x8 a0, a1, a2;
      if (kc < 16) {
        const float* p =
            emb + (size_t)myTok[Mt] * ESZ + kc * 32 + (lane >> 4) * 8;
        alignas(16) u16 t0[8], t1[8], t2[8];
        #pragma unroll
        for (int e = 0; e < 8; ++e) {
          u16 s0, s1, s2;
          split3((double)p[e], s0, s1, s2);
          t0[e] = s0; t1[e] = s1; t2[e] = s2;
        }
        a0 = *(const bf16x8*)t0; a1 = *(const bf16x8*)t1;
        a2 = *(const bf16x8*)t2;
      } else {
        const u16* ha =
            HA3 + ((size_t)((kc - 16) * 4 + Mt) * 3) * 512 + lane * 8;
        a0 = *(const bf16x8*)ha;
        a1 = *(const bf16x8*)(ha + 512);
        a2 = *(const bf16x8*)(ha + 1024);
      }
      f32x4 tb = __builtin_amdgcn_mfma_f32_16x16x32_bf16(a0, b0, zz, 0, 0, 0);
      #pragma unroll
      for (int r = 0; r < 4; ++r) big[Mt][r] += (double)tb[r];
      accs[Mt] = __builtin_amdgcn_mfma_f32_16x16x32_bf16(a1, b0, accs[Mt], 0, 0, 0);
      accs[Mt] = __builtin_amdgcn_mfma_f32_16x16x32_bf16(a0, b1, accs[Mt], 0, 0, 0);
      accs[Mt] = __builtin_amdgcn_mfma_f32_16x16x32_bf16(a1, b1, accs[Mt], 0, 0, 0);
      accs[Mt] = __builtin_amdgcn_mfma_f32_16x16x32_bf16(a2, b0, accs[Mt], 0, 0, 0);
      accs[Mt] = __builtin_amdgcn_mfma_f32_16x16x32_bf16(a0, b2, accs[Mt], 0, 0, 0);
    }
  }
  int col = Nt * 16 + (lane & 15);
  #pragma unroll
  for (int Mt = 0; Mt < 4; ++Mt) {
    #pragma unroll
    for (int r = 0; r < 4; ++r) {
      int b = Mt * 16 + (lane >> 4) * 4 + r;
      gG[((size_t)ks * G4H + col) * 64 + b] = big[Mt][r] + (double)accs[Mt][r];
    }
  }
}

__global__ __launch_bounds__(256) void k_cell(int nks,
                                              const double* __restrict__ gG,
                                              const float* __restrict__ bx,
                                              const float* __restrict__ bh,
                                              double* __restrict__ cT64,
                                              double* __restrict__ h64,
                                              u16* __restrict__ HA2,
                                              u16* __restrict__ HA3) {
  int idx = blockIdx.x * 256 + threadIdx.x;
  int j = idx >> 6, b = idx & 63;
  double gv[4];
  #pragma unroll
  for (int g = 0; g < 4; ++g) {
    size_t col = (size_t)g * 1024 + j;
    double s = 0.0;
    for (int ks = 0; ks < nks; ++ks)
      s += gG[((size_t)ks * G4H + col) * 64 + b];
    gv[g] = s + (double)bx[col] + (double)bh[col];
  }
  double c = cT64[idx];
  double f = 1.0 / (1.0 + exp(-gv[0]));
  double i = 1.0 / (1.0 + exp(-gv[1]));
  double g = tanh(gv[2]);
  double o = 1.0 / (1.0 + exp(-gv[3]));
  c = f * c + i * g;
  double h = o * tanh(c);
  cT64[idx] = c;
  h64[idx] = h;
  pack_h(j, b, h, HA2, HA3);
}

__global__ __launch_bounds__(256) void k_logits_mfma(
    int t, const u16* __restrict__ HA2, const u16* __restrict__ WBL,
    const float* __restrict__ bout, float* __restrict__ out,
    u64* __restrict__ p2) {
  int tid = threadIdx.x, lane = tid & 63, w = tid >> 6;
  int Nt = blockIdx.x * 4 + w;
  int colw = Nt * 16 + (lane & 15);
  const u16* wb = WBL + (size_t)Nt * 16384 + lane * 8;
  f32x4 acc[4] = {};
  for (int kc = 0; kc < 32; ++kc) {
    bf16x8 bhv = *(const bf16x8*)(wb + (size_t)kc * 512);
    const u16* ha = HA2 + (size_t)kc * 2048 + lane * 8;
    #pragma unroll
    for (int Mt = 0; Mt < 4; ++Mt) {
      bf16x8 ah = *(const bf16x8*)(ha + Mt * 512);
      acc[Mt] = __builtin_amdgcn_mfma_f32_16x16x32_bf16(ah, bhv, acc[Mt], 0, 0, 0);
    }
  }
  float bo = bout[colw];
  float* orow = out + (size_t)t * BSZ * VSZ;
  u64 mykey = 0, mykey2 = 0;
  #pragma unroll
  for (int Mt = 0; Mt < 4; ++Mt) {
    #pragma unroll
    for (int r = 0; r < 4; ++r) {
      float v = acc[Mt][r] + bo;
      orow[(size_t)(Mt * 16 + (lane >> 4) * 4 + r) * VSZ + colw] = v;
      u64 kb_ = ((u64)ordf(v) << 32) | (unsigned)(~colw);
      u64 ks_ = 0;
      #pragma unroll
      for (int s = 1; s < 16; s <<= 1) {
        u64 ob = __shfl_xor(kb_, s, 64);
        u64 os = __shfl_xor(ks_, s, 64);
        u64 nb = kb_ > ob ? kb_ : ob;
        u64 lo = kb_ > ob ? ob : kb_;
        u64 s2 = ks_ > os ? ks_ : os;
        kb_ = nb;
        ks_ = lo > s2 ? lo : s2;
      }
      if ((lane & 15) == Mt * 4 + r) { mykey = kb_; mykey2 = ks_; }
    }
  }
  int batch = ((lane & 15) >> 2) * 16 + (lane >> 4) * 4 + (lane & 3);
  size_t slot = (size_t)batch * 2000 + blockIdx.x * 4 + w;
  p2[slot * 2] = mykey;
  p2[slot * 2 + 1] = mykey2;
}

__global__ __launch_bounds__(256) void k_refine(
    const u64* __restrict__ p2, const double* __restrict__ h64,
    const float* __restrict__ Wout, const float* __restrict__ bout,
    int* __restrict__ tokbuf) {
  __shared__ u64 sm[256][4];
  __shared__ double rr[256][4];
  __shared__ int s_i[4];
  int b = blockIdx.x, tid = threadIdx.x;
  u64 t0 = 0, t1 = 0, t2 = 0, t3 = 0;
  for (int i = tid; i < 2000; i += 256) {
    u64 x = p2[((size_t)b * 2000 + i) * 2];
    u64 y = p2[((size_t)b * 2000 + i) * 2 + 1];
    ins4(x, t0, t1, t2, t3);
    ins4(y, t0, t1, t2, t3);
  }
  sm[tid][0] = t0; sm[tid][1] = t1; sm[tid][2] = t2; sm[tid][3] = t3;
  __syncthreads();
  for (int off = 128; off > 0; off >>= 1) {
    if (tid < off) {
      u64 a0 = sm[tid][0], a1 = sm[tid][1], a2 = sm[tid][2], a3 = sm[tid][3];
      merge4(a0, a1, a2, a3, sm[tid + off][0], sm[tid + off][1],
             sm[tid + off][2], sm[tid + off][3]);
      sm[tid][0] = a0; sm[tid][1] = a1; sm[tid][2] = a2; sm[tid][3] = a3;
    }
    __syncthreads();
  }
  if (tid < 4) s_i[tid] = (int)(~(u32)(sm[0][tid] & 0xFFFFFFFFull));
  __syncthreads();
  int i0 = s_i[0], i1 = s_i[1], i2 = s_i[2], i3 = s_i[3];
  double a0 = 0.0, a1 = 0.0, a2 = 0.0, a3 = 0.0;
  #pragma unroll
  for (int q = 0; q < 4; ++q) {
    int k = tid * 4 + q;
    double h = h64[(size_t)k * 64 + b];
    const float* wr = Wout + (size_t)k * VSZ;
    a0 += h * (double)wr[i0];
    a1 += h * (double)wr[i1];
    a2 += h * (double)wr[i2];
    a3 += h * (double)wr[i3];
  }
  rr[tid][0] = a0; rr[tid][1] = a1; rr[tid][2] = a2; rr[tid][3] = a3;
  __syncthreads();
  for (int off = 128; off > 0; off >>= 1) {
    if (tid < off) {
      rr[tid][0] += rr[tid + off][0];
      rr[tid][1] += rr[tid + off][1];
      rr[tid][2] += rr[tid + off][2];
      rr[tid][3] += rr[tid + off][3];
    }
    __syncthreads();
  }
  if (tid == 0) {
    double v0 = rr[0][0] + (double)bout[i0];
    double v1 = rr[0][1] + (double)bout[i1];
    double v2 = rr[0][2] + (double)bout[i2];
    double v3 = rr[0][3] + (double)bout[i3];
    double bv = v0; int bi = i0;
    if (v1 > bv || (v1 == bv && i1 < bi)) { bv = v1; bi = i1; }
    if (v2 > bv || (v2 == bv && i2 < bi)) { bv = v2; bi = i2; }
    if (v3 > bv || (v3 == bv && i3 < bi)) { bv = v3; bi = i3; }
    tokbuf[b] = bi;
  }
}

// ================= fallback all-f32 path (round-1, proven) =================

__global__ __launch_bounds__(256) void k_initF(const float* __restrict__ h0,
                                               const float* __restrict__ c0,
                                               float* __restrict__ hT,
                                               float* __restrict__ cT) {
  int idx = blockIdx.x * 256 + threadIdx.x;
  int j = idx >> 6, b = idx & 63;
  hT[idx] = h0[b * HSZ + j];
  cT[idx] = c0[b * HSZ + j];
}

__global__ __launch_bounds__(256) void k_gatesF(
    int t, const int* __restrict__ sos, const u64* __restrict__ partials,
    const float* __restrict__ emb, const float* __restrict__ Wx,
    const float* __restrict__ Wh, const float* __restrict__ hT,
    float* __restrict__ gP) {
  __shared__ float xs[128 * 64];
  __shared__ u64 s_red[256];
  __shared__ int s_tok[64];
  int tid = threadIdx.x;
  if (t == 0) {
    if (tid < 64) s_tok[tid] = sos[tid];
  } else {
    int b = tid >> 2, q = tid & 3;
    u64 best = 0ull;
    int i0 = q * 63, i1 = i0 + 63;
    if (i1 > 250) i1 = 250;
    for (int i = i0; i < i1; ++i) {
      u64 v = partials[b * 512 + i];
      if (v > best) best = v;
    }
    s_red[tid] = best;
    __syncthreads();
    if (q == 0) {
      u64 m = best;
      #pragma unroll
      for (int k = 1; k < 4; ++k) {
        u64 v = s_red[tid + k];
        if (v > m) m = v;
      }
      s_tok[b] = (int)(~(unsigned)(m & 0xFFFFFFFFull));
    }
  }
  __syncthreads();
  int colblk = blockIdx.x & 63, ks = blockIdx.x >> 6;
  int col = colblk * 16 + (tid & 15);
  int b0 = (tid >> 4) * 4;
  float acc[4][4];
  #pragma unroll
  for (int g = 0; g < 4; ++g)
    #pragma unroll
    for (int bb = 0; bb < 4; ++bb) acc[g][bb] = 0.f;
  for (int kc = 0; kc < 3; ++kc) {
    int k0 = ks * 384 + kc * 128;
    __syncthreads();
    if (k0 < 512) {
      int b = tid & 63;
      int kk0 = (tid >> 6) * 32;
      const float* erow = emb + (size_t)s_tok[b] * ESZ + k0 + kk0;
      #pragma unroll
      for (int i = 0; i < 32; i += 4) {
        float4 v = *(const float4*)(erow + i);
        xs[(kk0 + i) * 64 + b] = v.x;
        xs[(kk0 + i + 1) * 64 + b] = v.y;
        xs[(kk0 + i + 2) * 64 + b] = v.z;
        xs[(kk0 + i + 3) * 64 + b] = v.w;
      }
    } else {
      const float* src = hT + (size_t)(k0 - 512) * 64;
      #pragma unroll
      for (int i = 0; i < 8192; i += 1024)
        *(float4*)&xs[i + tid * 4] = *(const float4*)(src + i + tid * 4);
    }
    __syncthreads();
    const float* Wb = (k0 < 512) ? (Wx + (size_t)k0 * G4H + col)
                                 : (Wh + (size_t)(k0 - 512) * G4H + col);
    #pragma unroll 4
    for (int kk = 0; kk < 128; ++kk) {
      float4 xv = *(const float4*)&xs[kk * 64 + b0];
      const float* wr = Wb + (size_t)kk * G4H;
      float w0 = wr[0], w1 = wr[1024], w2 = wr[2048], w3 = wr[3072];
      acc[0][0] += w0 * xv.x; acc[0][1] += w0 * xv.y;
      acc[0][2] += w0 * xv.z; acc[0][3] += w0 * xv.w;
      acc[1][0] += w1 * xv.x; acc[1][1] += w1 * xv.y;
      acc[1][2] += w1 * xv.z; acc[1][3] += w1 * xv.w;
      acc[2][0] += w2 * xv.x; acc[2][1] += w2 * xv.y;
      acc[2][2] += w2 * xv.z; acc[2][3] += w2 * xv.w;
      acc[3][0] += w3 * xv.x; acc[3][1] += w3 * xv.y;
      acc[3][2] += w3 * xv.z; acc[3][3] += w3 * xv.w;
    }
  }
  #pragma unroll
  for (int g = 0; g < 4; ++g) {
    float4 v = make_float4(acc[g][0], acc[g][1], acc[g][2], acc[g][3]);
    *(float4*)&gP[((size_t)ks * G4H + g * 1024 + col) * 64 + b0] = v;
  }
}

__global__ __launch_bounds__(256) void k_cellF(const float* __restrict__ gP,
                                               const float* __restrict__ bx,
                                               const float* __restrict__ bh,
                                               float* __restrict__ hT,
                                               float* __restrict__ cT) {
  int flat = (blockIdx.x * 256 + threadIdx.x) * 2;
  int j = flat >> 6;
  float2 gv[4];
  #pragma unroll
  for (int g = 0; g < 4; ++g) {
    size_t base = ((size_t)g * 1024 + j) * 64 + (flat & 63);
    float2 s = *(const float2*)&gP[base];
    #pragma unroll
    for (int ks = 1; ks < 4; ++ks) {
      float2 p = *(const float2*)&gP[(size_t)ks * 262144 + base];
      s.x += p.x; s.y += p.y;
    }
    float bias = bx[g * 1024 + j] + bh[g * 1024 + j];
    s.x += bias; s.y += bias;
    gv[g] = s;
  }
  float2 c = *(const float2*)&cT[flat];
  float fx = 1.f / (1.f + expf(-gv[0].x)), fy = 1.f / (1.f + expf(-gv[0].y));
  float ix = 1.f / (1.f + expf(-gv[1].x)), iy = 1.f / (1.f + expf(-gv[1].y));
  float gx = tanhf(gv[2].x), gy = tanhf(gv[2].y);
  float ox = 1.f / (1.f + expf(-gv[3].x)), oy = 1.f / (1.f + expf(-gv[3].y));
  float cx = fx * c.x + ix * gx, cy = fy * c.y + iy * gy;
  float hx = ox * tanhf(cx), hy = oy * tanhf(cy);
  *(float2*)&cT[flat] = make_float2(cx, cy);
  *(float2*)&hT[flat] = make_float2(hx, hy);
}

__global__ __launch_bounds__(512) void k_logitsF(
    int t, const float* __restrict__ hT, const float* __restrict__ Wout,
    const float* __restrict__ bout, float* __restrict__ out,
    u64* __restrict__ partials) {
  __shared__ float hs[128 * 64];
  int tid = threadIdx.x;
  int lane = tid & 63;
  int bg = tid >> 6;
  int b0 = bg * 8;
  int j0 = blockIdx.x * 128 + lane * 2;
  float a0[8], a1[8];
  #pragma unroll
  for (int i = 0; i < 8; ++i) { a0[i] = 0.f; a1[i] = 0.f; }
  for (int kc = 0; kc < 8; ++kc) {
    int k0 = kc * 128;
    __syncthreads();
    #pragma unroll
    for (int i = 0; i < 8192; i += 2048)
      *(float4*)&hs[i + tid * 4] =
          *(const float4*)&hT[(size_t)k0 * 64 + i + tid * 4];
    __syncthreads();
    #pragma unroll 4
    for (int kk = 0; kk < 128; ++kk) {
      float2 wv = *(const float2*)(Wout + (size_t)(k0 + kk) * VSZ + j0);
      const float* hrow = &hs[kk * 64 + b0];
      float4 h0v = *(const float4*)(hrow);
      float4 h1v = *(const float4*)(hrow + 4);
      a0[0] += h0v.x * wv.x; a1[0] += h0v.x * wv.y;
      a0[1] += h0v.y * wv.x; a1[1] += h0v.y * wv.y;
      a0[2] += h0v.z * wv.x; a1[2] += h0v.z * wv.y;
      a0[3] += h0v.w * wv.x; a1[3] += h0v.w * wv.y;
      a0[4] += h1v.x * wv.x; a1[4] += h1v.x * wv.y;
      a0[5] += h1v.y * wv.x; a1[5] += h1v.y * wv.y;
      a0[6] += h1v.z * wv.x; a1[6] += h1v.z * wv.y;
      a0[7] += h1v.w * wv.x; a1[7] += h1v.w * wv.y;
    }
  }
  float bo0 = bout[j0], bo1 = bout[j0 + 1];
  float* orow = out + (size_t)t * BSZ * VSZ;
  #pragma unroll
  for (int bb = 0; bb < 8; ++bb) {
    float v0 = a0[bb] + bo0, v1 = a1[bb] + bo1;
    *(float2*)(orow + (size_t)(b0 + bb) * VSZ + j0) = make_float2(v0, v1);
    float m; int mi;
    if (v1 > v0) { m = v1; mi = j0 + 1; } else { m = v0; mi = j0; }
    u64 key = ((u64)ordf(m) << 32) | (unsigned)(~mi);
    #pragma unroll
    for (int s = 32; s > 0; s >>= 1) {
      u64 o = __shfl_xor(key, s, 64);
      if (o > key) key = o;
    }
    if (lane == bb) partials[(size_t)(b0 + bb) * 512 + blockIdx.x] = key;
  }
}

extern "C" void kernel_launch(void* const* d_in, const int* in_sizes, int n_in,
                              void* d_out, int out_size, void* d_ws,
                              size_t ws_size, hipStream_t stream) {
  const float* emb  = (const float*)d_in[0];
  const float* Wx   = (const float*)d_in[1];
  const float* bx   = (const float*)d_in[2];
  const float* Wh   = (const float*)d_in[3];
  const float* bh   = (const float*)d_in[4];
  const float* Wout = (const float*)d_in[5];
  const float* bout = (const float*)d_in[6];
  const float* h0   = (const float*)d_in[7];
  const float* c0   = (const float*)d_in[8];
  const int*   sos  = (const int*)d_in[9];
  float* out = (float*)d_out;

  size_t gGsz = 16777216;  // room for up to nks=8 (coop uses 4)
  bool mfma = ws_size >= 123814912ULL;

  char* base = (char*)d_ws;
  double* gG   = (double*)(base);
  double* cT64 = (double*)(base + gGsz);
  double* h64  = (double*)(base + gGsz + 524288);
  u16*    HA2  = (u16*)(base + gGsz + 1048576);   // 131072 B (+pad)
  u16*    HA3  = (u16*)(base + gGsz + 1310720);   // 393216 B
  int*    tokb = (int*)(base + gGsz + 1703936);   // 1024 B
  u64*    p2   = (u64*)(base + gGsz + 1704960);   // 2048000 B
  u16*    WBL  = (u16*)(base + gGsz + 3752960);   // 65536000 B
  u16*    WBG  = (u16*)(base + gGsz + 69288960);  // 37748736 B
  // f32-fallback layout overlaps (paths exclusive)
  float* hT = (float*)(base);
  float* cT = (float*)(base + 262144);
  float* gP = (float*)(base + 524288);
  u64* partials = (u64*)(base + 4718592);

  if (mfma) {
    k_wpackL<<<500, 256, 0, stream>>>(Wout, WBL);
    k_wpackG<<<256, 256, 0, stream>>>(Wx, Wh, WBG);
    k_init<<<256, 256, 0, stream>>>(h0, c0, cT64, h64, HA2, HA3);
    // one cooperative kernel for the whole T=32 loop
    void* args[] = {(void*)&sos, (void*)&emb,  (void*)&WBG, (void*)&WBL,
                    (void*)&Wout,(void*)&bx,   (void*)&bh,  (void*)&bout,
                    (void*)&c0,  (void*)&h64,  (void*)&HA2, (void*)&HA3,
                    (void*)&gG,  (void*)&p2,   (void*)&tokb,(void*)&out};
    hipError_t e = hipLaunchCooperativeKernel((void*)k_main, dim3(256),
                                              dim3(256), args, 0, stream);
    if (e != hipSuccess) {
      // proven per-step path (bit-identical math)
      for (int t = 0; t < TSZ; ++t) {
        k_gates6<<<256, 256, 0, stream>>>(t, 12, sos, tokb, emb, WBG, HA3, gG);
        k_cell<<<256, 256, 0, stream>>>(4, gG, bx, bh, cT64, h64, HA2, HA3);
        k_logits_mfma<<<500, 256, 0, stream>>>(t, HA2, WBL, bout, out, p2);
        if (t + 1 < TSZ)
          k_refine<<<64, 256, 0, stream>>>(p2, h64, Wout, bout, tokb);
      }
    }
  } else {
    k_initF<<<256, 256, 0, stream>>>(h0, c0, hT, cT);
    for (int t = 0; t < TSZ; ++t) {
      k_gatesF<<<256, 256, 0, stream>>>(t, sos, partials, emb, Wx, Wh, hT, gP);
      k_cellF<<<128, 256, 0, stream>>>(gP, bx, bh, hT, cT);
      k_logitsF<<<250, 512, 0, stream>>>(t, hT, Wout, bout, out, partials);
    }
  }
}

// Round 10
// 5003.526 us; speedup vs baseline: 1.7405x; 1.7405x over previous
//
#include <hip/hip_runtime.h>

// DecoderLSTM: V=32000 E=512 H=1024 B=64 T=32, fp32, greedy decode.
// Design (round 10 = round 9 + const fix): r7 per-step structure (proven,
// 2210us) with node-count reduction via intra-kernel "last-finishers
// continuation" (NOT coop grid sync -- r8 showed grid.sync forces 1
// wave/SIMD + L2 thrash, 4x slower):
//  - k_gates_fused (512 blocks): 6-term split-bf16 MFMA gates; every block
//    does threadfence+atomicAdd on a per-step counter BEFORE any wait (so
//    the counter always completes -> no deadlock); the last 256 finishers
//    spin until count==512 then run the f64 cell chunk (prev-256).
//  - k_logits_fused (500 blocks): single-term bf16 logits + per-wave top-2
//    keys; last 64 finishers spin until 500 then refine one batch each
//    (global top-4, exact f64 recompute, first-index tiebreak).
// Math is bit-identical to round 7 (absmax 3.9e-3). 67 graph nodes vs 131.
// Falls back to the round-1 all-f32 path if ws too small.

#define VSZ 32000
#define ESZ 512
#define HSZ 1024
#define BSZ 64
#define TSZ 32
#define G4H 4096

typedef unsigned short u16;
typedef unsigned int u32;
typedef unsigned long long u64;
typedef __attribute__((ext_vector_type(8))) short bf16x8;
typedef __attribute__((ext_vector_type(4))) float f32x4;

__device__ __forceinline__ unsigned ordf(float f) {
  unsigned u = __float_as_uint(f);
  return (u & 0x80000000u) ? ~u : (u | 0x80000000u);  // monotone float->uint
}
__device__ __forceinline__ u16 f2bf(float f) {  // f32 -> bf16 RNE
  u32 u = __float_as_uint(f);
  return (u16)((u + 0x7FFFu + ((u >> 16) & 1u)) >> 16);
}
__device__ __forceinline__ float bf2f(u16 s) {
  return __uint_as_float(((u32)s) << 16);
}
// 3-way bf16 split of a double (captures ~24 bits)
__device__ __forceinline__ void split3(double v, u16& s0, u16& s1, u16& s2) {
  s0 = f2bf((float)v);
  double r = v - (double)bf2f(s0);
  s1 = f2bf((float)r);
  double r2 = r - (double)bf2f(s1);
  s2 = f2bf((float)r2);
}

// pack h (f64) into HA2 (logits A: single bf16) and HA3 (gates A: 3 terms)
__device__ __forceinline__ void pack_h(int j, int b, double h,
                                       u16* __restrict__ HA2,
                                       u16* __restrict__ HA3) {
  u16 s0, s1, s2;
  split3(h, s0, s1, s2);
  int kc = j >> 5, kj = j & 31;
  int lane = (b & 15) | ((kj >> 3) << 4);
  int Mt = b >> 4;
  int e = kj & 7;
  HA2[(size_t)(kc * 4 + Mt) * 512 + lane * 8 + e] = s0;
  size_t b3 = ((size_t)(kc * 4 + Mt) * 3) * 512 + lane * 8 + e;
  HA3[b3] = s0;
  HA3[b3 + 512] = s1;
  HA3[b3 + 1024] = s2;
}

// sorted-4 (desc) insert, branchless
__device__ __forceinline__ void ins4(u64 v, u64& t0, u64& t1, u64& t2,
                                     u64& t3) {
  bool g0 = v > t0, g1 = v > t1, g2 = v > t2, g3 = v > t3;
  t3 = g2 ? t2 : (g3 ? v : t3);
  t2 = g1 ? t1 : (g2 ? v : t2);
  t1 = g0 ? t0 : (g1 ? v : t1);
  t0 = g0 ? v : t0;
}
// top-4 of two sorted-desc 4-lists (bitonic)
__device__ __forceinline__ void merge4(u64& a0, u64& a1, u64& a2, u64& a3,
                                       u64 b0, u64 b1, u64 b2, u64 b3) {
  u64 m0 = a0 > b3 ? a0 : b3;
  u64 m1 = a1 > b2 ? a1 : b2;
  u64 m2 = a2 > b1 ? a2 : b1;
  u64 m3 = a3 > b0 ? a3 : b0;
  u64 e0 = m0 > m2 ? m0 : m2, e2 = m0 > m2 ? m2 : m0;
  u64 e1 = m1 > m3 ? m1 : m3, e3 = m1 > m3 ? m3 : m1;
  a0 = e0 > e1 ? e0 : e1;
  a1 = e0 > e1 ? e1 : e0;
  a2 = e2 > e3 ? e2 : e3;
  a3 = e2 > e3 ? e3 : e2;
}

// arrive/wait: increment ALWAYS happens before any wait -> counter always
// reaches grid size -> no deadlock regardless of scheduling/occupancy.
__device__ __forceinline__ int arrive(int* cnt) {
  __threadfence();  // release all prior global writes
  return __hip_atomic_fetch_add(cnt, 1, __ATOMIC_ACQ_REL,
                                __HIP_MEMORY_SCOPE_AGENT);
}
__device__ __forceinline__ void waitfor(int* cnt, int target) {
  while (__hip_atomic_load(cnt, __ATOMIC_ACQUIRE, __HIP_MEMORY_SCOPE_AGENT) <
         target)
    __builtin_amdgcn_s_sleep(2);
  __threadfence();  // acquire: see all arrivers' writes
}

// ---- init: c0,h0 -> f64 state; pack h0 frags; zero step counters ----
__global__ __launch_bounds__(256) void k_init(const float* __restrict__ h0,
                                              const float* __restrict__ c0,
                                              double* __restrict__ cT64,
                                              double* __restrict__ h64,
                                              u16* __restrict__ HA2,
                                              u16* __restrict__ HA3,
                                              int* __restrict__ cntG,
                                              int* __restrict__ cntL) {
  if (blockIdx.x == 0 && threadIdx.x < 64) {
    if (threadIdx.x < 32) cntG[threadIdx.x] = 0;
    else cntL[threadIdx.x - 32] = 0;
  }
  int idx = blockIdx.x * 256 + threadIdx.x;  // 65536
  int j = idx >> 6, b = idx & 63;
  double h = (double)h0[b * HSZ + j];
  cT64[idx] = (double)c0[b * HSZ + j];
  h64[idx] = h;
  pack_h(j, b, h, HA2, HA3);
}

// ---- pack Wout (f32 [K=1024][V]) into logits B single bf16, once ----
// WBL layout: [Nt=2000][kc=32][lane=64][e=8]
__global__ __launch_bounds__(256) void k_wpackL(const float* __restrict__ Wout,
                                                u16* __restrict__ WBL) {
  __shared__ float ls[32][64];
  int tid = threadIdx.x;
  int j0 = blockIdx.x * 64;
  int Nt0 = blockIdx.x * 4;
  for (int kc = 0; kc < 32; ++kc) {
    __syncthreads();
    #pragma unroll
    for (int rr = 0; rr < 8; ++rr) {
      int row = rr * 4 + (tid >> 6);
      ls[row][tid & 63] = Wout[(size_t)(kc * 32 + row) * VSZ + j0 + (tid & 63)];
    }
    __syncthreads();
    int lane = tid & 63, Ntl = tid >> 6;
    int col = Ntl * 16 + (lane & 15);
    int kb = (lane >> 4) * 8;
    alignas(16) u16 hibuf[8];
    #pragma unroll
    for (int e = 0; e < 8; ++e) hibuf[e] = f2bf(ls[kb + e][col]);
    size_t base = ((size_t)((Nt0 + Ntl) * 32 + kc)) * 512 + lane * 8;
    *(bf16x8*)&WBL[base] = *(const bf16x8*)hibuf;
  }
}

// ---- pack [Wx;Wh] (f32 [K=1536][4096]) into gates B 3-term, once ----
// WBG layout: [Nt=256][kc=48][term=3][lane=64][e=8]
__global__ __launch_bounds__(256) void k_wpackG(const float* __restrict__ Wx,
                                                const float* __restrict__ Wh,
                                                u16* __restrict__ WBG) {
  int tid = threadIdx.x;
  int Nt = blockIdx.x;  // 256 blocks
  int lane = tid & 63, w = tid >> 6;
  int col = Nt * 16 + (lane & 15);
  for (int i = 0; i < 12; ++i) {
    int kc = w * 12 + i;
    int kb = kc * 32 + (lane >> 4) * 8;
    alignas(16) u16 b0[8], b1[8], b2[8];
    #pragma unroll
    for (int e = 0; e < 8; ++e) {
      int k = kb + e;
      float v = (k < ESZ) ? Wx[(size_t)k * G4H + col]
                          : Wh[(size_t)(k - ESZ) * G4H + col];
      u16 s0, s1, s2;
      split3((double)v, s0, s1, s2);
      b0[e] = s0; b1[e] = s1; b2[e] = s2;
    }
    size_t base = ((size_t)(Nt * 48 + kc) * 3) * 512 + lane * 8;
    *(bf16x8*)&WBG[base] = *(const bf16x8*)b0;
    *(bf16x8*)&WBG[base + 512] = *(const bf16x8*)b1;
    *(bf16x8*)&WBG[base + 1024] = *(const bf16x8*)b2;
  }
}

// ---- gates (512 blocks = 8 ksplits x 64 Nt-groups) + fused cell ----
// nks=8, nch=6. Last 256 finishers run the f64 cell chunk (prev-256).
// HA3 is non-const: read in gates phase, written by fused cell (ordered by
// the arrive/wait acquire-release fences).
__global__ __launch_bounds__(256) void k_gates_fused(
    int t, const int* __restrict__ sos, const int* __restrict__ tokbuf,
    const float* __restrict__ emb, const u16* __restrict__ WBG,
    u16* __restrict__ HA3, double* __restrict__ gG,
    const float* __restrict__ bx, const float* __restrict__ bh,
    double* __restrict__ cT64, double* __restrict__ h64,
    u16* __restrict__ HA2, int* __restrict__ cnt) {
  __shared__ int s_tok[64];
  __shared__ int s_prev;
  int tid = threadIdx.x, lane = tid & 63, w = tid >> 6;
  const int* tok = (t == 0) ? sos : tokbuf;
  if (tid < 64) s_tok[tid] = tok[tid];
  __syncthreads();

  int Ntg = blockIdx.x & 63, ks = blockIdx.x >> 6;  // ks in [0,8)
  int Nt = Ntg * 4 + w;
  int myTok[4];
  #pragma unroll
  for (int Mt = 0; Mt < 4; ++Mt) myTok[Mt] = s_tok[Mt * 16 + (lane & 15)];

  double big[4][4];
  f32x4 accs[4];
  #pragma unroll
  for (int Mt = 0; Mt < 4; ++Mt) {
    accs[Mt] = (f32x4){0.f, 0.f, 0.f, 0.f};
    #pragma unroll
    for (int r = 0; r < 4; ++r) big[Mt][r] = 0.0;
  }
  const f32x4 zz = {0.f, 0.f, 0.f, 0.f};

  for (int i = 0; i < 6; ++i) {
    int kc = ks * 6 + i;  // global K chunk (48 total)
    const u16* wb = WBG + ((size_t)(Nt * 48 + kc) * 3) * 512 + lane * 8;
    bf16x8 b0 = *(const bf16x8*)wb;
    bf16x8 b1 = *(const bf16x8*)(wb + 512);
    bf16x8 b2 = *(const bf16x8*)(wb + 1024);
    #pragma unroll
    for (int Mt = 0; Mt < 4; ++Mt) {
      bf16x8 a0, a1, a2;
      if (kc < 16) {  // x from embedding: split on the fly
        const float* p =
            emb + (size_t)myTok[Mt] * ESZ + kc * 32 + (lane >> 4) * 8;
        alignas(16) u16 t0[8], t1[8], t2[8];
        #pragma unroll
        for (int e = 0; e < 8; ++e) {
          u16 s0, s1, s2;
          split3((double)p[e], s0, s1, s2);
          t0[e] = s0; t1[e] = s1; t2[e] = s2;
        }
        a0 = *(const bf16x8*)t0; a1 = *(const bf16x8*)t1;
        a2 = *(const bf16x8*)t2;
      } else {  // x from h: pre-split A-frags
        const u16* ha =
            HA3 + ((size_t)((kc - 16) * 4 + Mt) * 3) * 512 + lane * 8;
        a0 = *(const bf16x8*)ha;
        a1 = *(const bf16x8*)(ha + 512);
        a2 = *(const bf16x8*)(ha + 1024);
      }
      // dominant term: isolated MFMA, promoted to f64 per chunk
      f32x4 tb = __builtin_amdgcn_mfma_f32_16x16x32_bf16(a0, b0, zz, 0, 0, 0);
      #pragma unroll
      for (int r = 0; r < 4; ++r) big[Mt][r] += (double)tb[r];
      // 5 cross terms (i+j<=2): chained f32 accumulation
      accs[Mt] = __builtin_amdgcn_mfma_f32_16x16x32_bf16(a1, b0, accs[Mt], 0, 0, 0);
      accs[Mt] = __builtin_amdgcn_mfma_f32_16x16x32_bf16(a0, b1, accs[Mt], 0, 0, 0);
      accs[Mt] = __builtin_amdgcn_mfma_f32_16x16x32_bf16(a1, b1, accs[Mt], 0, 0, 0);
      accs[Mt] = __builtin_amdgcn_mfma_f32_16x16x32_bf16(a2, b0, accs[Mt], 0, 0, 0);
      accs[Mt] = __builtin_amdgcn_mfma_f32_16x16x32_bf16(a0, b2, accs[Mt], 0, 0, 0);
    }
  }
  int col = Nt * 16 + (lane & 15);
  #pragma unroll
  for (int Mt = 0; Mt < 4; ++Mt) {
    #pragma unroll
    for (int r = 0; r < 4; ++r) {
      int b = Mt * 16 + (lane >> 4) * 4 + r;  // C/D map (m89)
      gG[((size_t)ks * G4H + col) * 64 + b] = big[Mt][r] + (double)accs[Mt][r];
    }
  }

  // ---- fused cell: last 256 finishers each do 256 cells ----
  __syncthreads();
  if (tid == 0) s_prev = arrive(cnt);
  __syncthreads();
  int prev = s_prev;
  if (prev < 256) return;  // early finishers free their CU slot
  if (tid == 0) waitfor(cnt, 512);
  __syncthreads();
  int idx = (prev - 256) * 256 + tid;  // chunk set = [0,65536) exactly once
  int j = idx >> 6, b = idx & 63;
  double gv[4];
  #pragma unroll
  for (int g = 0; g < 4; ++g) {
    size_t colc = (size_t)g * 1024 + j;
    double s = 0.0;
    #pragma unroll
    for (int ks2 = 0; ks2 < 8; ++ks2)
      s += gG[((size_t)ks2 * G4H + colc) * 64 + b];
    gv[g] = s + (double)bx[colc] + (double)bh[colc];
  }
  double c = cT64[idx];
  double f = 1.0 / (1.0 + exp(-gv[0]));
  double i2 = 1.0 / (1.0 + exp(-gv[1]));
  double g2 = tanh(gv[2]);
  double o = 1.0 / (1.0 + exp(-gv[3]));
  c = f * c + i2 * g2;
  double h = o * tanh(c);
  cT64[idx] = c;
  h64[idx] = h;
  pack_h(j, b, h, HA2, HA3);
}

// ---- logits (500 blocks) + fused top-4 refine (last 64 finishers) ----
__global__ __launch_bounds__(256) void k_logits_fused(
    int t, const u16* __restrict__ HA2, const u16* __restrict__ WBL,
    const float* __restrict__ bout, float* __restrict__ out,
    u64* __restrict__ p2, const double* __restrict__ h64,
    const float* __restrict__ Wout, int* __restrict__ tokbuf,
    int* __restrict__ cnt, int dorefine) {
  __shared__ u64 sm[256][4];
  __shared__ double rr[256][4];
  __shared__ int s_i[4];
  __shared__ int s_prev;
  int tid = threadIdx.x, lane = tid & 63, w = tid >> 6;
  int Nt = blockIdx.x * 4 + w;
  int colw = Nt * 16 + (lane & 15);
  const u16* wb = WBL + (size_t)Nt * 16384 + lane * 8;
  f32x4 acc[4] = {};

  for (int kc = 0; kc < 32; ++kc) {
    bf16x8 bhv = *(const bf16x8*)(wb + (size_t)kc * 512);
    const u16* ha = HA2 + (size_t)kc * 2048 + lane * 8;
    #pragma unroll
    for (int Mt = 0; Mt < 4; ++Mt) {
      bf16x8 ah = *(const bf16x8*)(ha + Mt * 512);
      acc[Mt] = __builtin_amdgcn_mfma_f32_16x16x32_bf16(ah, bhv, acc[Mt], 0, 0, 0);
    }
  }

  float bo = bout[colw];
  float* orow = out + (size_t)t * BSZ * VSZ;
  u64 mykey = 0, mykey2 = 0;
  #pragma unroll
  for (int Mt = 0; Mt < 4; ++Mt) {
    #pragma unroll
    for (int r = 0; r < 4; ++r) {
      float v = acc[Mt][r] + bo;
      orow[(size_t)(Mt * 16 + (lane >> 4) * 4 + r) * VSZ + colw] = v;
      // top-2 butterfly over the 16 col-lanes (disjoint-set top2 merge)
      u64 kb_ = ((u64)ordf(v) << 32) | (unsigned)(~colw);
      u64 ks_ = 0;
      #pragma unroll
      for (int s = 1; s < 16; s <<= 1) {
        u64 ob = __shfl_xor(kb_, s, 64);
        u64 os = __shfl_xor(ks_, s, 64);
        u64 nb = kb_ > ob ? kb_ : ob;
        u64 lo = kb_ > ob ? ob : kb_;
        u64 s2 = ks_ > os ? ks_ : os;
        kb_ = nb;
        ks_ = lo > s2 ? lo : s2;
      }
      if ((lane & 15) == Mt * 4 + r) { mykey = kb_; mykey2 = ks_; }
    }
  }
  // batch = Mt*16 + rowgrp*4 + r, bijective in lane; slot unique PER WAVE.
  int batch = ((lane & 15) >> 2) * 16 + (lane >> 4) * 4 + (lane & 3);
  size_t slot = (size_t)batch * 2000 + blockIdx.x * 4 + w;
  p2[slot * 2] = mykey;
  p2[slot * 2 + 1] = mykey2;

  // ---- fused refine: last 64 finishers each refine one batch ----
  if (!dorefine) return;
  __syncthreads();
  if (tid == 0) s_prev = arrive(cnt);
  __syncthreads();
  int prev = s_prev;
  if (prev < 436) return;
  if (tid == 0) waitfor(cnt, 500);
  __syncthreads();
  int b = prev - 436;  // batch set = [0,64) exactly once
  u64 t0 = 0, t1 = 0, t2 = 0, t3 = 0;
  for (int i = tid; i < 2000; i += 256) {
    u64 x = p2[((size_t)b * 2000 + i) * 2];
    u64 y = p2[((size_t)b * 2000 + i) * 2 + 1];
    ins4(x, t0, t1, t2, t3);
    ins4(y, t0, t1, t2, t3);
  }
  sm[tid][0] = t0; sm[tid][1] = t1; sm[tid][2] = t2; sm[tid][3] = t3;
  __syncthreads();
  for (int off = 128; off > 0; off >>= 1) {
    if (tid < off) {
      u64 a0 = sm[tid][0], a1 = sm[tid][1], a2 = sm[tid][2], a3 = sm[tid][3];
      merge4(a0, a1, a2, a3, sm[tid + off][0], sm[tid + off][1],
             sm[tid + off][2], sm[tid + off][3]);
      sm[tid][0] = a0; sm[tid][1] = a1; sm[tid][2] = a2; sm[tid][3] = a3;
    }
    __syncthreads();
  }
  if (tid < 4) s_i[tid] = (int)(~(u32)(sm[0][tid] & 0xFFFFFFFFull));
  __syncthreads();
  int i0 = s_i[0], i1 = s_i[1], i2 = s_i[2], i3 = s_i[3];
  double a0 = 0.0, a1 = 0.0, a2 = 0.0, a3 = 0.0;
  #pragma unroll
  for (int q = 0; q < 4; ++q) {
    int k = tid * 4 + q;
    double h = h64[(size_t)k * 64 + b];
    const float* wr = Wout + (size_t)k * VSZ;
    a0 += h * (double)wr[i0];
    a1 += h * (double)wr[i1];
    a2 += h * (double)wr[i2];
    a3 += h * (double)wr[i3];
  }
  rr[tid][0] = a0; rr[tid][1] = a1; rr[tid][2] = a2; rr[tid][3] = a3;
  __syncthreads();
  for (int off = 128; off > 0; off >>= 1) {
    if (tid < off) {
      rr[tid][0] += rr[tid + off][0];
      rr[tid][1] += rr[tid + off][1];
      rr[tid][2] += rr[tid + off][2];
      rr[tid][3] += rr[tid + off][3];
    }
    __syncthreads();
  }
  if (tid == 0) {
    double v0 = rr[0][0] + (double)bout[i0];
    double v1 = rr[0][1] + (double)bout[i1];
    double v2 = rr[0][2] + (double)bout[i2];
    double v3 = rr[0][3] + (double)bout[i3];
    double bv = v0; int bi = i0;
    if (v1 > bv || (v1 == bv && i1 < bi)) { bv = v1; bi = i1; }
    if (v2 > bv || (v2 == bv && i2 < bi)) { bv = v2; bi = i2; }
    if (v3 > bv || (v3 == bv && i3 < bi)) { bv = v3; bi = i3; }
    tokbuf[b] = bi;
  }
}

// ================= fallback all-f32 path (round-1, proven) =================

__global__ __launch_bounds__(256) void k_initF(const float* __restrict__ h0,
                                               const float* __restrict__ c0,
                                               float* __restrict__ hT,
                                               float* __restrict__ cT) {
  int idx = blockIdx.x * 256 + threadIdx.x;
  int j = idx >> 6, b = idx & 63;
  hT[idx] = h0[b * HSZ + j];
  cT[idx] = c0[b * HSZ + j];
}

__global__ __launch_bounds__(256) void k_gatesF(
    int t, const int* __restrict__ sos, const u64* __restrict__ partials,
    const float* __restrict__ emb, const float* __restrict__ Wx,
    const float* __restrict__ Wh, const float* __restrict__ hT,
    float* __restrict__ gP) {
  __shared__ float xs[128 * 64];
  __shared__ u64 s_red[256];
  __shared__ int s_tok[64];
  int tid = threadIdx.x;
  if (t == 0) {
    if (tid < 64) s_tok[tid] = sos[tid];
  } else {
    int b = tid >> 2, q = tid & 3;
    u64 best = 0ull;
    int i0 = q * 63, i1 = i0 + 63;
    if (i1 > 250) i1 = 250;
    for (int i = i0; i < i1; ++i) {
      u64 v = partials[b * 512 + i];
      if (v > best) best = v;
    }
    s_red[tid] = best;
    __syncthreads();
    if (q == 0) {
      u64 m = best;
      #pragma unroll
      for (int k = 1; k < 4; ++k) {
        u64 v = s_red[tid + k];
        if (v > m) m = v;
      }
      s_tok[b] = (int)(~(unsigned)(m & 0xFFFFFFFFull));
    }
  }
  __syncthreads();
  int colblk = blockIdx.x & 63, ks = blockIdx.x >> 6;
  int col = colblk * 16 + (tid & 15);
  int b0 = (tid >> 4) * 4;
  float acc[4][4];
  #pragma unroll
  for (int g = 0; g < 4; ++g)
    #pragma unroll
    for (int bb = 0; bb < 4; ++bb) acc[g][bb] = 0.f;
  for (int kc = 0; kc < 3; ++kc) {
    int k0 = ks * 384 + kc * 128;
    __syncthreads();
    if (k0 < 512) {
      int b = tid & 63;
      int kk0 = (tid >> 6) * 32;
      const float* erow = emb + (size_t)s_tok[b] * ESZ + k0 + kk0;
      #pragma unroll
      for (int i = 0; i < 32; i += 4) {
        float4 v = *(const float4*)(erow + i);
        xs[(kk0 + i) * 64 + b] = v.x;
        xs[(kk0 + i + 1) * 64 + b] = v.y;
        xs[(kk0 + i + 2) * 64 + b] = v.z;
        xs[(kk0 + i + 3) * 64 + b] = v.w;
      }
    } else {
      const float* src = hT + (size_t)(k0 - 512) * 64;
      #pragma unroll
      for (int i = 0; i < 8192; i += 1024)
        *(float4*)&xs[i + tid * 4] = *(const float4*)(src + i + tid * 4);
    }
    __syncthreads();
    const float* Wb = (k0 < 512) ? (Wx + (size_t)k0 * G4H + col)
                                 : (Wh + (size_t)(k0 - 512) * G4H + col);
    #pragma unroll 4
    for (int kk = 0; kk < 128; ++kk) {
      float4 xv = *(const float4*)&xs[kk * 64 + b0];
      const float* wr = Wb + (size_t)kk * G4H;
      float w0 = wr[0], w1 = wr[1024], w2 = wr[2048], w3 = wr[3072];
      acc[0][0] += w0 * xv.x; acc[0][1] += w0 * xv.y;
      acc[0][2] += w0 * xv.z; acc[0][3] += w0 * xv.w;
      acc[1][0] += w1 * xv.x; acc[1][1] += w1 * xv.y;
      acc[1][2] += w1 * xv.z; acc[1][3] += w1 * xv.w;
      acc[2][0] += w2 * xv.x; acc[2][1] += w2 * xv.y;
      acc[2][2] += w2 * xv.z; acc[2][3] += w2 * xv.w;
      acc[3][0] += w3 * xv.x; acc[3][1] += w3 * xv.y;
      acc[3][2] += w3 * xv.z; acc[3][3] += w3 * xv.w;
    }
  }
  #pragma unroll
  for (int g = 0; g < 4; ++g) {
    float4 v = make_float4(acc[g][0], acc[g][1], acc[g][2], acc[g][3]);
    *(float4*)&gP[((size_t)ks * G4H + g * 1024 + col) * 64 + b0] = v;
  }
}

__global__ __launch_bounds__(256) void k_cellF(const float* __restrict__ gP,
                                               const float* __restrict__ bx,
                                               const float* __restrict__ bh,
                                               float* __restrict__ hT,
                                               float* __restrict__ cT) {
  int flat = (blockIdx.x * 256 + threadIdx.x) * 2;
  int j = flat >> 6;
  float2 gv[4];
  #pragma unroll
  for (int g = 0; g < 4; ++g) {
    size_t base = ((size_t)g * 1024 + j) * 64 + (flat & 63);
    float2 s = *(const float2*)&gP[base];
    #pragma unroll
    for (int ks = 1; ks < 4; ++ks) {
      float2 p = *(const float2*)&gP[(size_t)ks * 262144 + base];
      s.x += p.x; s.y += p.y;
    }
    float bias = bx[g * 1024 + j] + bh[g * 1024 + j];
    s.x += bias; s.y += bias;
    gv[g] = s;
  }
  float2 c = *(const float2*)&cT[flat];
  float fx = 1.f / (1.f + expf(-gv[0].x)), fy = 1.f / (1.f + expf(-gv[0].y));
  float ix = 1.f / (1.f + expf(-gv[1].x)), iy = 1.f / (1.f + expf(-gv[1].y));
  float gx = tanhf(gv[2].x), gy = tanhf(gv[2].y);
  float ox = 1.f / (1.f + expf(-gv[3].x)), oy = 1.f / (1.f + expf(-gv[3].y));
  float cx = fx * c.x + ix * gx, cy = fy * c.y + iy * gy;
  float hx = ox * tanhf(cx), hy = oy * tanhf(cy);
  *(float2*)&cT[flat] = make_float2(cx, cy);
  *(float2*)&hT[flat] = make_float2(hx, hy);
}

__global__ __launch_bounds__(512) void k_logitsF(
    int t, const float* __restrict__ hT, const float* __restrict__ Wout,
    const float* __restrict__ bout, float* __restrict__ out,
    u64* __restrict__ partials) {
  __shared__ float hs[128 * 64];
  int tid = threadIdx.x;
  int lane = tid & 63;
  int bg = tid >> 6;
  int b0 = bg * 8;
  int j0 = blockIdx.x * 128 + lane * 2;
  float a0[8], a1[8];
  #pragma unroll
  for (int i = 0; i < 8; ++i) { a0[i] = 0.f; a1[i] = 0.f; }
  for (int kc = 0; kc < 8; ++kc) {
    int k0 = kc * 128;
    __syncthreads();
    #pragma unroll
    for (int i = 0; i < 8192; i += 2048)
      *(float4*)&hs[i + tid * 4] =
          *(const float4*)&hT[(size_t)k0 * 64 + i + tid * 4];
    __syncthreads();
    #pragma unroll 4
    for (int kk = 0; kk < 128; ++kk) {
      float2 wv = *(const float2*)(Wout + (size_t)(k0 + kk) * VSZ + j0);
      const float* hrow = &hs[kk * 64 + b0];
      float4 h0v = *(const float4*)(hrow);
      float4 h1v = *(const float4*)(hrow + 4);
      a0[0] += h0v.x * wv.x; a1[0] += h0v.x * wv.y;
      a0[1] += h0v.y * wv.x; a1[1] += h0v.y * wv.y;
      a0[2] += h0v.z * wv.x; a1[2] += h0v.z * wv.y;
      a0[3] += h0v.w * wv.x; a1[3] += h0v.w * wv.y;
      a0[4] += h1v.x * wv.x; a1[4] += h1v.x * wv.y;
      a0[5] += h1v.y * wv.x; a1[5] += h1v.y * wv.y;
      a0[6] += h1v.z * wv.x; a1[6] += h1v.z * wv.y;
      a0[7] += h1v.w * wv.x; a1[7] += h1v.w * wv.y;
    }
  }
  float bo0 = bout[j0], bo1 = bout[j0 + 1];
  float* orow = out + (size_t)t * BSZ * VSZ;
  #pragma unroll
  for (int bb = 0; bb < 8; ++bb) {
    float v0 = a0[bb] + bo0, v1 = a1[bb] + bo1;
    *(float2*)(orow + (size_t)(b0 + bb) * VSZ + j0) = make_float2(v0, v1);
    float m; int mi;
    if (v1 > v0) { m = v1; mi = j0 + 1; } else { m = v0; mi = j0; }
    u64 key = ((u64)ordf(m) << 32) | (unsigned)(~mi);
    #pragma unroll
    for (int s = 32; s > 0; s >>= 1) {
      u64 o = __shfl_xor(key, s, 64);
      if (o > key) key = o;
    }
    if (lane == bb) partials[(size_t)(b0 + bb) * 512 + blockIdx.x] = key;
  }
}

extern "C" void kernel_launch(void* const* d_in, const int* in_sizes, int n_in,
                              void* d_out, int out_size, void* d_ws,
                              size_t ws_size, hipStream_t stream) {
  const float* emb  = (const float*)d_in[0];
  const float* Wx   = (const float*)d_in[1];
  const float* bx   = (const float*)d_in[2];
  const float* Wh   = (const float*)d_in[3];
  const float* bh   = (const float*)d_in[4];
  const float* Wout = (const float*)d_in[5];
  const float* bout = (const float*)d_in[6];
  const float* h0   = (const float*)d_in[7];
  const float* c0   = (const float*)d_in[8];
  const int*   sos  = (const int*)d_in[9];
  float* out = (float*)d_out;

  size_t gGsz = 16777216;  // nks=8
  bool mfma = ws_size >= 123814912ULL;

  char* base = (char*)d_ws;
  double* gG   = (double*)(base);
  double* cT64 = (double*)(base + gGsz);
  double* h64  = (double*)(base + gGsz + 524288);
  u16*    HA2  = (u16*)(base + gGsz + 1048576);   // 131072 B (+pad)
  u16*    HA3  = (u16*)(base + gGsz + 1310720);   // 393216 B
  int*    tokb = (int*)(base + gGsz + 1703936);   // 256 B
  int*    cntG = (int*)(base + gGsz + 1704192);   // 128 B (32 ints)
  int*    cntL = (int*)(base + gGsz + 1704320);   // 128 B (32 ints)
  u64*    p2   = (u64*)(base + gGsz + 1704960);   // 2048000 B
  u16*    WBL  = (u16*)(base + gGsz + 3752960);   // 65536000 B
  u16*    WBG  = (u16*)(base + gGsz + 69288960);  // 37748736 B
  // f32-fallback layout overlaps (paths exclusive)
  float* hT = (float*)(base);
  float* cT = (float*)(base + 262144);
  float* gP = (float*)(base + 524288);
  u64* partials = (u64*)(base + 4718592);

  if (mfma) {
    k_wpackL<<<500, 256, 0, stream>>>(Wout, WBL);
    k_wpackG<<<256, 256, 0, stream>>>(Wx, Wh, WBG);
    k_init<<<256, 256, 0, stream>>>(h0, c0, cT64, h64, HA2, HA3, cntG, cntL);
    for (int t = 0; t < TSZ; ++t) {
      k_gates_fused<<<512, 256, 0, stream>>>(t, sos, tokb, emb, WBG, HA3, gG,
                                             bx, bh, cT64, h64, HA2, cntG + t);
      k_logits_fused<<<500, 256, 0, stream>>>(t, HA2, WBL, bout, out, p2, h64,
                                              Wout, tokb, cntL + t,
                                              (t + 1 < TSZ) ? 1 : 0);
    }
  } else {
    k_initF<<<256, 256, 0, stream>>>(h0, c0, hT, cT);
    for (int t = 0; t < TSZ; ++t) {
      k_gatesF<<<256, 256, 0, stream>>>(t, sos, partials, emb, Wx, Wh, hT, gP);
      k_cellF<<<128, 256, 0, stream>>>(gP, bx, bh, hT, cT);
      k_logitsF<<<250, 512, 0, stream>>>(t, hT, Wout, bout, out, partials);
    }
  }
}

// Round 12
// 3377.391 us; speedup vs baseline: 2.5785x; 1.4815x over previous
//
#include <hip/hip_runtime.h>

// DecoderLSTM: V=32000 E=512 H=1024 B=64 T=32, fp32, greedy decode.
// Design (round 12 = round 11 + ws-layout fix): r11 failed because tokb was
// placed 4 KB INSIDE EA3 (sized EA3 as 188 KB instead of 192 KB) -> token
// ints clobbered bf16 A-frags (exponent ~2^68 garbage) for batches 32-47.
// Layout now: cumulative, EA3 = 64 tiles x 3072 B = 196608 B exactly.
//  - k_gatescell (64 blocks x 4 waves): wave w = gate w, full K=1536,
//    6-term split-bf16 MFMA, f64 chunk-promoted big term; pointwise f64
//    cell epilogue after one __syncthreads. HA3 ping-pong double-buffered.
//  - Embedding A-frags pre-split into EA3 by k_refine's tail / k_init(t=0).
//  - k_logits_mfma / k_refine: r7-verbatim math (single-term bf16 logits,
//    per-wave top-2 keys, exact f64 top-4 refine).
// 98 graph nodes vs r7's 131. Falls back to round-1 all-f32 path if ws small.

#define VSZ 32000
#define ESZ 512
#define HSZ 1024
#define BSZ 64
#define TSZ 32
#define G4H 4096

typedef unsigned short u16;
typedef unsigned int u32;
typedef unsigned long long u64;
typedef __attribute__((ext_vector_type(8))) short bf16x8;
typedef __attribute__((ext_vector_type(4))) float f32x4;

__device__ __forceinline__ unsigned ordf(float f) {
  unsigned u = __float_as_uint(f);
  return (u & 0x80000000u) ? ~u : (u | 0x80000000u);  // monotone float->uint
}
__device__ __forceinline__ u16 f2bf(float f) {  // f32 -> bf16 RNE
  u32 u = __float_as_uint(f);
  return (u16)((u + 0x7FFFu + ((u >> 16) & 1u)) >> 16);
}
__device__ __forceinline__ float bf2f(u16 s) {
  return __uint_as_float(((u32)s) << 16);
}
// 3-way bf16 split of a double (captures ~24 bits)
__device__ __forceinline__ void split3(double v, u16& s0, u16& s1, u16& s2) {
  s0 = f2bf((float)v);
  double r = v - (double)bf2f(s0);
  s1 = f2bf((float)r);
  double r2 = r - (double)bf2f(s1);
  s2 = f2bf((float)r2);
}

// pack h (f64) into HA2 (logits A: single bf16) and HA3 (gates A: 3 terms)
__device__ __forceinline__ void pack_h(int j, int b, double h,
                                       u16* __restrict__ HA2,
                                       u16* __restrict__ HA3) {
  u16 s0, s1, s2;
  split3(h, s0, s1, s2);
  int kc = j >> 5, kj = j & 31;
  int lane = (b & 15) | ((kj >> 3) << 4);
  int Mt = b >> 4;
  int e = kj & 7;
  HA2[(size_t)(kc * 4 + Mt) * 512 + lane * 8 + e] = s0;
  size_t b3 = ((size_t)(kc * 4 + Mt) * 3) * 512 + lane * 8 + e;
  HA3[b3] = s0;
  HA3[b3 + 512] = s1;
  HA3[b3 + 1024] = s2;
}

// pack one embedding element (k,b) into EA3 (gates A, kc 0..15)
__device__ __forceinline__ void pack_e(int k, int b, double v,
                                       u16* __restrict__ EA3) {
  u16 s0, s1, s2;
  split3(v, s0, s1, s2);
  int kc = k >> 5, kj = k & 31;
  int lane = (b & 15) | ((kj >> 3) << 4);
  int Mt = b >> 4;
  int e = kj & 7;
  size_t b3 = ((size_t)(kc * 4 + Mt) * 3) * 512 + lane * 8 + e;
  EA3[b3] = s0;
  EA3[b3 + 512] = s1;
  EA3[b3 + 1024] = s2;
}

// sorted-4 (desc) insert, branchless
__device__ __forceinline__ void ins4(u64 v, u64& t0, u64& t1, u64& t2,
                                     u64& t3) {
  bool g0 = v > t0, g1 = v > t1, g2 = v > t2, g3 = v > t3;
  t3 = g2 ? t2 : (g3 ? v : t3);
  t2 = g1 ? t1 : (g2 ? v : t2);
  t1 = g0 ? t0 : (g1 ? v : t1);
  t0 = g0 ? v : t0;
}
// top-4 of two sorted-desc 4-lists (bitonic)
__device__ __forceinline__ void merge4(u64& a0, u64& a1, u64& a2, u64& a3,
                                       u64 b0, u64 b1, u64 b2, u64 b3) {
  u64 m0 = a0 > b3 ? a0 : b3;
  u64 m1 = a1 > b2 ? a1 : b2;
  u64 m2 = a2 > b1 ? a2 : b1;
  u64 m3 = a3 > b0 ? a3 : b0;
  u64 e0 = m0 > m2 ? m0 : m2, e2 = m0 > m2 ? m2 : m0;
  u64 e1 = m1 > m3 ? m1 : m3, e3 = m1 > m3 ? m3 : m1;
  a0 = e0 > e1 ? e0 : e1;
  a1 = e0 > e1 ? e1 : e0;
  a2 = e2 > e3 ? e2 : e3;
  a3 = e2 > e3 ? e3 : e2;
}

// ---- init: c0,h0 -> f64 state; pack h0 into HA3b; pack sos emb -> EA3 ----
__global__ __launch_bounds__(256) void k_init(
    const float* __restrict__ h0, const float* __restrict__ c0,
    const int* __restrict__ sos, const float* __restrict__ emb,
    double* __restrict__ cT64, double* __restrict__ h64,
    u16* __restrict__ HA2, u16* __restrict__ HA3b, u16* __restrict__ EA3) {
  int idx = blockIdx.x * 256 + threadIdx.x;  // 65536
  int j = idx >> 6, b = idx & 63;
  double h = (double)h0[b * HSZ + j];
  cT64[idx] = (double)c0[b * HSZ + j];
  h64[idx] = h;
  pack_h(j, b, h, HA2, HA3b);
  if (j < ESZ) pack_e(j, b, (double)emb[(size_t)sos[b] * ESZ + j], EA3);
}

// ---- pack Wout (f32 [K=1024][V]) into logits B single bf16, once ----
// WBL layout: [Nt=2000][kc=32][lane=64][e=8]
__global__ __launch_bounds__(256) void k_wpackL(const float* __restrict__ Wout,
                                                u16* __restrict__ WBL) {
  __shared__ float ls[32][64];
  int tid = threadIdx.x;
  int j0 = blockIdx.x * 64;
  int Nt0 = blockIdx.x * 4;
  for (int kc = 0; kc < 32; ++kc) {
    __syncthreads();
    #pragma unroll
    for (int rr = 0; rr < 8; ++rr) {
      int row = rr * 4 + (tid >> 6);
      ls[row][tid & 63] = Wout[(size_t)(kc * 32 + row) * VSZ + j0 + (tid & 63)];
    }
    __syncthreads();
    int lane = tid & 63, Ntl = tid >> 6;
    int col = Ntl * 16 + (lane & 15);
    int kb = (lane >> 4) * 8;
    alignas(16) u16 hibuf[8];
    #pragma unroll
    for (int e = 0; e < 8; ++e) hibuf[e] = f2bf(ls[kb + e][col]);
    size_t base = ((size_t)((Nt0 + Ntl) * 32 + kc)) * 512 + lane * 8;
    *(bf16x8*)&WBL[base] = *(const bf16x8*)hibuf;
  }
}

// ---- pack [Wx;Wh] (f32 [K=1536][4096]) into gates B 3-term, once ----
// WBG layout: [Nt=256][kc=48][term=3][lane=64][e=8]
__global__ __launch_bounds__(256) void k_wpackG(const float* __restrict__ Wx,
                                                const float* __restrict__ Wh,
                                                u16* __restrict__ WBG) {
  int tid = threadIdx.x;
  int Nt = blockIdx.x;  // 256 blocks
  int lane = tid & 63, w = tid >> 6;
  int col = Nt * 16 + (lane & 15);
  for (int i = 0; i < 12; ++i) {
    int kc = w * 12 + i;
    int kb = kc * 32 + (lane >> 4) * 8;
    alignas(16) u16 b0[8], b1[8], b2[8];
    #pragma unroll
    for (int e = 0; e < 8; ++e) {
      int k = kb + e;
      float v = (k < ESZ) ? Wx[(size_t)k * G4H + col]
                          : Wh[(size_t)(k - ESZ) * G4H + col];
      u16 s0, s1, s2;
      split3((double)v, s0, s1, s2);
      b0[e] = s0; b1[e] = s1; b2[e] = s2;
    }
    size_t base = ((size_t)(Nt * 48 + kc) * 3) * 512 + lane * 8;
    *(bf16x8*)&WBG[base] = *(const bf16x8*)b0;
    *(bf16x8*)&WBG[base + 512] = *(const bf16x8*)b1;
    *(bf16x8*)&WBG[base + 1024] = *(const bf16x8*)b2;
  }
}

// ---- fused gates+cell: 64 blocks (1 j-tile each) x 4 waves (1 gate each) --
// Wave w computes gate w over full K=48 chunks (A from EA3 for kc<16, else
// HA3r). Pointwise f64 cell after one __syncthreads. No cross-block deps:
// HA3w is the OTHER buffer (ping-pong), HA2/h64 readers run in later kernels.
__global__ __launch_bounds__(256) void k_gatescell(
    const u16* __restrict__ EA3, const u16* __restrict__ HA3r,
    const u16* __restrict__ WBG, const float* __restrict__ bx,
    const float* __restrict__ bh, double* __restrict__ cT64,
    double* __restrict__ h64, u16* __restrict__ HA2,
    u16* __restrict__ HA3w) {
  __shared__ double gvL[4][1024];  // 32 KB: [gate][jl*64+b]
  int tid = threadIdx.x, lane = tid & 63, w = tid >> 6;
  int jt = blockIdx.x;        // j-tile 0..63
  int Nt = w * 64 + jt;       // gate w's column tile

  double big[4][4];
  f32x4 accs[4];
  #pragma unroll
  for (int Mt = 0; Mt < 4; ++Mt) {
    accs[Mt] = (f32x4){0.f, 0.f, 0.f, 0.f};
    #pragma unroll
    for (int r = 0; r < 4; ++r) big[Mt][r] = 0.0;
  }
  const f32x4 zz = {0.f, 0.f, 0.f, 0.f};

  for (int kc = 0; kc < 48; ++kc) {
    const u16* wb = WBG + ((size_t)(Nt * 48 + kc) * 3) * 512 + lane * 8;
    bf16x8 b0 = *(const bf16x8*)wb;
    bf16x8 b1 = *(const bf16x8*)(wb + 512);
    bf16x8 b2 = *(const bf16x8*)(wb + 1024);
    const u16* abase = (kc < 16)
        ? (EA3 + ((size_t)(kc * 4) * 3) * 512)
        : (HA3r + ((size_t)((kc - 16) * 4) * 3) * 512);
    #pragma unroll
    for (int Mt = 0; Mt < 4; ++Mt) {
      const u16* ha = abase + ((size_t)Mt * 3) * 512 + lane * 8;
      bf16x8 a0 = *(const bf16x8*)ha;
      bf16x8 a1 = *(const bf16x8*)(ha + 512);
      bf16x8 a2 = *(const bf16x8*)(ha + 1024);
      // dominant term: isolated MFMA, promoted to f64 per chunk
      f32x4 tb = __builtin_amdgcn_mfma_f32_16x16x32_bf16(a0, b0, zz, 0, 0, 0);
      #pragma unroll
      for (int r = 0; r < 4; ++r) big[Mt][r] += (double)tb[r];
      // 5 cross terms (i+j<=2): chained f32 accumulation
      accs[Mt] = __builtin_amdgcn_mfma_f32_16x16x32_bf16(a1, b0, accs[Mt], 0, 0, 0);
      accs[Mt] = __builtin_amdgcn_mfma_f32_16x16x32_bf16(a0, b1, accs[Mt], 0, 0, 0);
      accs[Mt] = __builtin_amdgcn_mfma_f32_16x16x32_bf16(a1, b1, accs[Mt], 0, 0, 0);
      accs[Mt] = __builtin_amdgcn_mfma_f32_16x16x32_bf16(a2, b0, accs[Mt], 0, 0, 0);
      accs[Mt] = __builtin_amdgcn_mfma_f32_16x16x32_bf16(a0, b2, accs[Mt], 0, 0, 0);
    }
  }
  // full gate pre-activation (no bias) -> LDS, keyed by (jl, b)
  #pragma unroll
  for (int Mt = 0; Mt < 4; ++Mt) {
    #pragma unroll
    for (int r = 0; r < 4; ++r) {
      int b = Mt * 16 + (lane >> 4) * 4 + r;  // C/D map (m89)
      gvL[w][(lane & 15) * 64 + b] = big[Mt][r] + (double)accs[Mt][r];
    }
  }
  __syncthreads();

  // pointwise f64 cell: 4 cells per thread
  #pragma unroll
  for (int q = 0; q < 4; ++q) {
    int ci = tid * 4 + q;  // 0..1023
    int jl = ci >> 6, b = ci & 63;
    int j = jt * 16 + jl;
    double gv0 = gvL[0][ci] + (double)bx[j] + (double)bh[j];
    double gv1 = gvL[1][ci] + (double)bx[1024 + j] + (double)bh[1024 + j];
    double gv2 = gvL[2][ci] + (double)bx[2048 + j] + (double)bh[2048 + j];
    double gv3 = gvL[3][ci] + (double)bx[3072 + j] + (double)bh[3072 + j];
    double c = cT64[(size_t)j * 64 + b];
    double f = 1.0 / (1.0 + exp(-gv0));
    double i = 1.0 / (1.0 + exp(-gv1));
    double g = tanh(gv2);
    double o = 1.0 / (1.0 + exp(-gv3));
    c = f * c + i * g;
    double h = o * tanh(c);
    cT64[(size_t)j * 64 + b] = c;
    h64[(size_t)j * 64 + b] = h;
    pack_h(j, b, h, HA2, HA3w);
  }
}

// ---- logits: single-term bf16 MFMA + store + per-WAVE top-2 keys ----
// grid 500 x block 256 = 4 waves (1 Nt of 16 cols each). r7-verbatim.
__global__ __launch_bounds__(256) void k_logits_mfma(
    int t, const u16* __restrict__ HA2, const u16* __restrict__ WBL,
    const float* __restrict__ bout, float* __restrict__ out,
    u64* __restrict__ p2) {
  int tid = threadIdx.x, lane = tid & 63, w = tid >> 6;
  int Nt = blockIdx.x * 4 + w;
  int colw = Nt * 16 + (lane & 15);
  const u16* wb = WBL + (size_t)Nt * 16384 + lane * 8;
  f32x4 acc[4] = {};

  for (int kc = 0; kc < 32; ++kc) {
    bf16x8 bhv = *(const bf16x8*)(wb + (size_t)kc * 512);
    const u16* ha = HA2 + (size_t)kc * 2048 + lane * 8;
    #pragma unroll
    for (int Mt = 0; Mt < 4; ++Mt) {
      bf16x8 ah = *(const bf16x8*)(ha + Mt * 512);
      acc[Mt] = __builtin_amdgcn_mfma_f32_16x16x32_bf16(ah, bhv, acc[Mt], 0, 0, 0);
    }
  }

  float bo = bout[colw];
  float* orow = out + (size_t)t * BSZ * VSZ;
  u64 mykey = 0, mykey2 = 0;
  #pragma unroll
  for (int Mt = 0; Mt < 4; ++Mt) {
    #pragma unroll
    for (int r = 0; r < 4; ++r) {
      float v = acc[Mt][r] + bo;
      orow[(size_t)(Mt * 16 + (lane >> 4) * 4 + r) * VSZ + colw] = v;
      // top-2 butterfly over the 16 col-lanes (disjoint-set top2 merge)
      u64 kb_ = ((u64)ordf(v) << 32) | (unsigned)(~colw);
      u64 ks_ = 0;
      #pragma unroll
      for (int s = 1; s < 16; s <<= 1) {
        u64 ob = __shfl_xor(kb_, s, 64);
        u64 os = __shfl_xor(ks_, s, 64);
        u64 nb = kb_ > ob ? kb_ : ob;
        u64 lo = kb_ > ob ? ob : kb_;
        u64 s2 = ks_ > os ? ks_ : os;
        kb_ = nb;
        ks_ = lo > s2 ? lo : s2;
      }
      if ((lane & 15) == Mt * 4 + r) { mykey = kb_; mykey2 = ks_; }
    }
  }
  // batch = Mt*16 + rowgrp*4 + r, bijective in lane; slot unique PER WAVE.
  int batch = ((lane & 15) >> 2) * 16 + (lane >> 4) * 4 + (lane & 3);
  size_t slot = (size_t)batch * 2000 + blockIdx.x * 4 + w;
  p2[slot * 2] = mykey;
  p2[slot * 2 + 1] = mykey2;
}

// ---- refine: global top-4; exact f64 logits; pick token; pack emb EA3 ----
// grid 64 (one block per batch) x 256 threads.
__global__ __launch_bounds__(256) void k_refine(
    const u64* __restrict__ p2, const double* __restrict__ h64,
    const float* __restrict__ Wout, const float* __restrict__ bout,
    int* __restrict__ tokbuf, const float* __restrict__ emb,
    u16* __restrict__ EA3) {
  __shared__ u64 sm[256][4];
  __shared__ double rr[256][4];
  __shared__ int s_i[4];
  __shared__ int s_sel;
  int b = blockIdx.x, tid = threadIdx.x;
  u64 t0 = 0, t1 = 0, t2 = 0, t3 = 0;
  for (int i = tid; i < 2000; i += 256) {
    u64 x = p2[((size_t)b * 2000 + i) * 2];
    u64 y = p2[((size_t)b * 2000 + i) * 2 + 1];
    ins4(x, t0, t1, t2, t3);
    ins4(y, t0, t1, t2, t3);
  }
  sm[tid][0] = t0; sm[tid][1] = t1; sm[tid][2] = t2; sm[tid][3] = t3;
  __syncthreads();
  for (int off = 128; off > 0; off >>= 1) {
    if (tid < off) {
      u64 a0 = sm[tid][0], a1 = sm[tid][1], a2 = sm[tid][2], a3 = sm[tid][3];
      merge4(a0, a1, a2, a3, sm[tid + off][0], sm[tid + off][1],
             sm[tid + off][2], sm[tid + off][3]);
      sm[tid][0] = a0; sm[tid][1] = a1; sm[tid][2] = a2; sm[tid][3] = a3;
    }
    __syncthreads();
  }
  if (tid < 4) s_i[tid] = (int)(~(u32)(sm[0][tid] & 0xFFFFFFFFull));
  __syncthreads();
  int i0 = s_i[0], i1 = s_i[1], i2 = s_i[2], i3 = s_i[3];
  double a0 = 0.0, a1 = 0.0, a2 = 0.0, a3 = 0.0;
  #pragma unroll
  for (int q = 0; q < 4; ++q) {
    int k = tid * 4 + q;
    double h = h64[(size_t)k * 64 + b];
    const float* wr = Wout + (size_t)k * VSZ;
    a0 += h * (double)wr[i0];
    a1 += h * (double)wr[i1];
    a2 += h * (double)wr[i2];
    a3 += h * (double)wr[i3];
  }
  rr[tid][0] = a0; rr[tid][1] = a1; rr[tid][2] = a2; rr[tid][3] = a3;
  __syncthreads();
  for (int off = 128; off > 0; off >>= 1) {
    if (tid < off) {
      rr[tid][0] += rr[tid + off][0];
      rr[tid][1] += rr[tid + off][1];
      rr[tid][2] += rr[tid + off][2];
      rr[tid][3] += rr[tid + off][3];
    }
    __syncthreads();
  }
  if (tid == 0) {
    double v0 = rr[0][0] + (double)bout[i0];
    double v1 = rr[0][1] + (double)bout[i1];
    double v2 = rr[0][2] + (double)bout[i2];
    double v3 = rr[0][3] + (double)bout[i3];
    double bv = v0; int bi = i0;
    if (v1 > bv || (v1 == bv && i1 < bi)) { bv = v1; bi = i1; }
    if (v2 > bv || (v2 == bv && i2 < bi)) { bv = v2; bi = i2; }
    if (v3 > bv || (v3 == bv && i3 < bi)) { bv = v3; bi = i3; }
    tokbuf[b] = bi;
    s_sel = bi;
  }
  __syncthreads();
  // pack next step's embedding A-frags for this batch (512 elems, 2/thread)
  int tokf = s_sel;
  int k = tid * 2;
  pack_e(k, b, (double)emb[(size_t)tokf * ESZ + k], EA3);
  pack_e(k + 1, b, (double)emb[(size_t)tokf * ESZ + k + 1], EA3);
}

// ================= fallback all-f32 path (round-1, proven) =================

__global__ __launch_bounds__(256) void k_initF(const float* __restrict__ h0,
                                               const float* __restrict__ c0,
                                               float* __restrict__ hT,
                                               float* __restrict__ cT) {
  int idx = blockIdx.x * 256 + threadIdx.x;
  int j = idx >> 6, b = idx & 63;
  hT[idx] = h0[b * HSZ + j];
  cT[idx] = c0[b * HSZ + j];
}

__global__ __launch_bounds__(256) void k_gatesF(
    int t, const int* __restrict__ sos, const u64* __restrict__ partials,
    const float* __restrict__ emb, const float* __restrict__ Wx,
    const float* __restrict__ Wh, const float* __restrict__ hT,
    float* __restrict__ gP) {
  __shared__ float xs[128 * 64];
  __shared__ u64 s_red[256];
  __shared__ int s_tok[64];
  int tid = threadIdx.x;
  if (t == 0) {
    if (tid < 64) s_tok[tid] = sos[tid];
  } else {
    int b = tid >> 2, q = tid & 3;
    u64 best = 0ull;
    int i0 = q * 63, i1 = i0 + 63;
    if (i1 > 250) i1 = 250;
    for (int i = i0; i < i1; ++i) {
      u64 v = partials[b * 512 + i];
      if (v > best) best = v;
    }
    s_red[tid] = best;
    __syncthreads();
    if (q == 0) {
      u64 m = best;
      #pragma unroll
      for (int k = 1; k < 4; ++k) {
        u64 v = s_red[tid + k];
        if (v > m) m = v;
      }
      s_tok[b] = (int)(~(unsigned)(m & 0xFFFFFFFFull));
    }
  }
  __syncthreads();
  int colblk = blockIdx.x & 63, ks = blockIdx.x >> 6;
  int col = colblk * 16 + (tid & 15);
  int b0 = (tid >> 4) * 4;
  float acc[4][4];
  #pragma unroll
  for (int g = 0; g < 4; ++g)
    #pragma unroll
    for (int bb = 0; bb < 4; ++bb) acc[g][bb] = 0.f;
  for (int kc = 0; kc < 3; ++kc) {
    int k0 = ks * 384 + kc * 128;
    __syncthreads();
    if (k0 < 512) {
      int b = tid & 63;
      int kk0 = (tid >> 6) * 32;
      const float* erow = emb + (size_t)s_tok[b] * ESZ + k0 + kk0;
      #pragma unroll
      for (int i = 0; i < 32; i += 4) {
        float4 v = *(const float4*)(erow + i);
        xs[(kk0 + i) * 64 + b] = v.x;
        xs[(kk0 + i + 1) * 64 + b] = v.y;
        xs[(kk0 + i + 2) * 64 + b] = v.z;
        xs[(kk0 + i + 3) * 64 + b] = v.w;
      }
    } else {
      const float* src = hT + (size_t)(k0 - 512) * 64;
      #pragma unroll
      for (int i = 0; i < 8192; i += 1024)
        *(float4*)&xs[i + tid * 4] = *(const float4*)(src + i + tid * 4);
    }
    __syncthreads();
    const float* Wb = (k0 < 512) ? (Wx + (size_t)k0 * G4H + col)
                                 : (Wh + (size_t)(k0 - 512) * G4H + col);
    #pragma unroll 4
    for (int kk = 0; kk < 128; ++kk) {
      float4 xv = *(const float4*)&xs[kk * 64 + b0];
      const float* wr = Wb + (size_t)kk * G4H;
      float w0 = wr[0], w1 = wr[1024], w2 = wr[2048], w3 = wr[3072];
      acc[0][0] += w0 * xv.x; acc[0][1] += w0 * xv.y;
      acc[0][2] += w0 * xv.z; acc[0][3] += w0 * xv.w;
      acc[1][0] += w1 * xv.x; acc[1][1] += w1 * xv.y;
      acc[1][2] += w1 * xv.z; acc[1][3] += w1 * xv.w;
      acc[2][0] += w2 * xv.x; acc[2][1] += w2 * xv.y;
      acc[2][2] += w2 * xv.z; acc[2][3] += w2 * xv.w;
      acc[3][0] += w3 * xv.x; acc[3][1] += w3 * xv.y;
      acc[3][2] += w3 * xv.z; acc[3][3] += w3 * xv.w;
    }
  }
  #pragma unroll
  for (int g = 0; g < 4; ++g) {
    float4 v = make_float4(acc[g][0], acc[g][1], acc[g][2], acc[g][3]);
    *(float4*)&gP[((size_t)ks * G4H + g * 1024 + col) * 64 + b0] = v;
  }
}

__global__ __launch_bounds__(256) void k_cellF(const float* __restrict__ gP,
                                               const float* __restrict__ bx,
                                               const float* __restrict__ bh,
                                               float* __restrict__ hT,
                                               float* __restrict__ cT) {
  int flat = (blockIdx.x * 256 + threadIdx.x) * 2;
  int j = flat >> 6;
  float2 gv[4];
  #pragma unroll
  for (int g = 0; g < 4; ++g) {
    size_t base = ((size_t)g * 1024 + j) * 64 + (flat & 63);
    float2 s = *(const float2*)&gP[base];
    #pragma unroll
    for (int ks = 1; ks < 4; ++ks) {
      float2 p = *(const float2*)&gP[(size_t)ks * 262144 + base];
      s.x += p.x; s.y += p.y;
    }
    float bias = bx[g * 1024 + j] + bh[g * 1024 + j];
    s.x += bias; s.y += bias;
    gv[g] = s;
  }
  float2 c = *(const float2*)&cT[flat];
  float fx = 1.f / (1.f + expf(-gv[0].x)), fy = 1.f / (1.f + expf(-gv[0].y));
  float ix = 1.f / (1.f + expf(-gv[1].x)), iy = 1.f / (1.f + expf(-gv[1].y));
  float gx = tanhf(gv[2].x), gy = tanhf(gv[2].y);
  float ox = 1.f / (1.f + expf(-gv[3].x)), oy = 1.f / (1.f + expf(-gv[3].y));
  float cx = fx * c.x + ix * gx, cy = fy * c.y + iy * gy;
  float hx = ox * tanhf(cx), hy = oy * tanhf(cy);
  *(float2*)&cT[flat] = make_float2(cx, cy);
  *(float2*)&hT[flat] = make_float2(hx, hy);
}

__global__ __launch_bounds__(512) void k_logitsF(
    int t, const float* __restrict__ hT, const float* __restrict__ Wout,
    const float* __restrict__ bout, float* __restrict__ out,
    u64* __restrict__ partials) {
  __shared__ float hs[128 * 64];
  int tid = threadIdx.x;
  int lane = tid & 63;
  int bg = tid >> 6;
  int b0 = bg * 8;
  int j0 = blockIdx.x * 128 + lane * 2;
  float a0[8], a1[8];
  #pragma unroll
  for (int i = 0; i < 8; ++i) { a0[i] = 0.f; a1[i] = 0.f; }
  for (int kc = 0; kc < 8; ++kc) {
    int k0 = kc * 128;
    __syncthreads();
    #pragma unroll
    for (int i = 0; i < 8192; i += 2048)
      *(float4*)&hs[i + tid * 4] =
          *(const float4*)&hT[(size_t)k0 * 64 + i + tid * 4];
    __syncthreads();
    #pragma unroll 4
    for (int kk = 0; kk < 128; ++kk) {
      float2 wv = *(const float2*)(Wout + (size_t)(k0 + kk) * VSZ + j0);
      const float* hrow = &hs[kk * 64 + b0];
      float4 h0v = *(const float4*)(hrow);
      float4 h1v = *(const float4*)(hrow + 4);
      a0[0] += h0v.x * wv.x; a1[0] += h0v.x * wv.y;
      a0[1] += h0v.y * wv.x; a1[1] += h0v.y * wv.y;
      a0[2] += h0v.z * wv.x; a1[2] += h0v.z * wv.y;
      a0[3] += h0v.w * wv.x; a1[3] += h0v.w * wv.y;
      a0[4] += h1v.x * wv.x; a1[4] += h1v.x * wv.y;
      a0[5] += h1v.y * wv.x; a1[5] += h1v.y * wv.y;
      a0[6] += h1v.z * wv.x; a1[6] += h1v.z * wv.y;
      a0[7] += h1v.w * wv.x; a1[7] += h1v.w * wv.y;
    }
  }
  float bo0 = bout[j0], bo1 = bout[j0 + 1];
  float* orow = out + (size_t)t * BSZ * VSZ;
  #pragma unroll
  for (int bb = 0; bb < 8; ++bb) {
    float v0 = a0[bb] + bo0, v1 = a1[bb] + bo1;
    *(float2*)(orow + (size_t)(b0 + bb) * VSZ + j0) = make_float2(v0, v1);
    float m; int mi;
    if (v1 > v0) { m = v1; mi = j0 + 1; } else { m = v0; mi = j0; }
    u64 key = ((u64)ordf(m) << 32) | (unsigned)(~mi);
    #pragma unroll
    for (int s = 32; s > 0; s >>= 1) {
      u64 o = __shfl_xor(key, s, 64);
      if (o > key) key = o;
    }
    if (lane == bb) partials[(size_t)(b0 + bb) * 512 + blockIdx.x] = key;
  }
}

extern "C" void kernel_launch(void* const* d_in, const int* in_sizes, int n_in,
                              void* d_out, int out_size, void* d_ws,
                              size_t ws_size, hipStream_t stream) {
  const float* emb  = (const float*)d_in[0];
  const float* Wx   = (const float*)d_in[1];
  const float* bx   = (const float*)d_in[2];
  const float* Wh   = (const float*)d_in[3];
  const float* bh   = (const float*)d_in[4];
  const float* Wout = (const float*)d_in[5];
  const float* bout = (const float*)d_in[6];
  const float* h0   = (const float*)d_in[7];
  const float* c0   = (const float*)d_in[8];
  const int*   sos  = (const int*)d_in[9];
  float* out = (float*)d_out;

  bool mfma = ws_size >= 123814912ULL;

  // ws layout (cumulative byte offsets, audited):
  //   cT64 @ 0         size 524288   (8192 f64... 65536*8)
  //   h64  @ 524288    size 524288
  //   HA2  @ 1048576   size 131072   (128 tiles * 512 u16 * 2B)
  //   HA3a @ 1179648   size 393216   (128 tiles * 3 * 512 u16 * 2B)
  //   HA3b @ 1572864   size 393216
  //   EA3  @ 1966080   size 196608   (64 tiles * 3 * 512 u16 * 2B)
  //   tokb @ 2162688   size 256      <- r11 bug: was 2158592 (inside EA3)
  //   p2   @ 2166784   size 2048000  (64*2000*2 u64)
  //   WBL  @ 4214784   size 65536000
  //   WBG  @ 69750784  size 37748736 -> end 107499520
  char* base = (char*)d_ws;
  double* cT64 = (double*)(base);
  double* h64  = (double*)(base + 524288);
  u16*    HA2  = (u16*)(base + 1048576);
  u16*    HA3a = (u16*)(base + 1179648);
  u16*    HA3b = (u16*)(base + 1572864);
  u16*    EA3  = (u16*)(base + 1966080);
  int*    tokb = (int*)(base + 2162688);
  u64*    p2   = (u64*)(base + 2166784);
  u16*    WBL  = (u16*)(base + 4214784);
  u16*    WBG  = (u16*)(base + 69750784);
  // f32-fallback layout overlaps (paths exclusive)
  float* hT = (float*)(base);
  float* cT = (float*)(base + 262144);
  float* gP = (float*)(base + 524288);
  u64* partials = (u64*)(base + 4718592);

  if (mfma) {
    k_wpackL<<<500, 256, 0, stream>>>(Wout, WBL);
    k_wpackG<<<256, 256, 0, stream>>>(Wx, Wh, WBG);
    k_init<<<256, 256, 0, stream>>>(h0, c0, sos, emb, cT64, h64, HA2, HA3b,
                                    EA3);
    for (int t = 0; t < TSZ; ++t) {
      const u16* HA3r = (t & 1) ? HA3a : HA3b;  // gates read h_{t-1}
      u16* HA3w = (t & 1) ? HA3b : HA3a;        // cell writes h_t
      k_gatescell<<<64, 256, 0, stream>>>(EA3, HA3r, WBG, bx, bh, cT64, h64,
                                          HA2, HA3w);
      k_logits_mfma<<<500, 256, 0, stream>>>(t, HA2, WBL, bout, out, p2);
      if (t + 1 < TSZ)  // last step's token is never consumed
        k_refine<<<64, 256, 0, stream>>>(p2, h64, Wout, bout, tokb, emb, EA3);
    }
  } else {
    k_initF<<<256, 256, 0, stream>>>(h0, c0, hT, cT);
    for (int t = 0; t < TSZ; ++t) {
      k_gatesF<<<256, 256, 0, stream>>>(t, sos, partials, emb, Wx, Wh, hT, gP);
      k_cellF<<<128, 256, 0, stream>>>(gP, bx, bh, hT, cT);
      k_logitsF<<<250, 512, 0, stream>>>(t, hT, Wout, bout, out, partials);
    }
  }
}

// Round 13
// 2110.315 us; speedup vs baseline: 4.1266x; 1.6004x over previous
//
#include <hip/hip_runtime.h>

// DecoderLSTM: V=32000 E=512 H=1024 B=64 T=32, fp32, greedy decode.
// Design (round 13): r12's gates+cell fusion, re-decomposed for parallelism.
// r12 regression root cause: 64 blocks (1 j-tile each) = 64 CUs busy, 1152
// serial MFMA/wave. Fix: split BATCH not K across blocks:
//  - k_gatescell: grid 256 = 64 jtiles x 4 batch-groups; block 512 = 8 waves;
//    wave (g,kh) = gate g, K-half kh (24 chunks x 6 MFMA = 144 MFMA/wave,
//    same shape as r7's proven gates; 2 waves/SIMD). Block holds all 4 gates
//    for its 16j x 16b -> pointwise f64 cell epilogue after 1 __syncthreads
//    (halves summed in fixed order -> deterministic). gG eliminated.
//  - EA3 pre-split emb A-frags (r12-proven) - no split3 in gates.
//  - k_logits_mfma (+unroll 2) / k_refine / k_init: r12-verbatim math.
// 98 graph nodes. No cross-block sync anywhere (r8/r10 lesson).
// Falls back to round-1 all-f32 path if ws too small.

#define VSZ 32000
#define ESZ 512
#define HSZ 1024
#define BSZ 64
#define TSZ 32
#define G4H 4096

typedef unsigned short u16;
typedef unsigned int u32;
typedef unsigned long long u64;
typedef __attribute__((ext_vector_type(8))) short bf16x8;
typedef __attribute__((ext_vector_type(4))) float f32x4;

__device__ __forceinline__ unsigned ordf(float f) {
  unsigned u = __float_as_uint(f);
  return (u & 0x80000000u) ? ~u : (u | 0x80000000u);  // monotone float->uint
}
__device__ __forceinline__ u16 f2bf(float f) {  // f32 -> bf16 RNE
  u32 u = __float_as_uint(f);
  return (u16)((u + 0x7FFFu + ((u >> 16) & 1u)) >> 16);
}
__device__ __forceinline__ float bf2f(u16 s) {
  return __uint_as_float(((u32)s) << 16);
}
// 3-way bf16 split of a double (captures ~24 bits)
__device__ __forceinline__ void split3(double v, u16& s0, u16& s1, u16& s2) {
  s0 = f2bf((float)v);
  double r = v - (double)bf2f(s0);
  s1 = f2bf((float)r);
  double r2 = r - (double)bf2f(s1);
  s2 = f2bf((float)r2);
}

// pack h (f64) into HA2 (logits A: single bf16) and HA3 (gates A: 3 terms)
__device__ __forceinline__ void pack_h(int j, int b, double h,
                                       u16* __restrict__ HA2,
                                       u16* __restrict__ HA3) {
  u16 s0, s1, s2;
  split3(h, s0, s1, s2);
  int kc = j >> 5, kj = j & 31;
  int lane = (b & 15) | ((kj >> 3) << 4);
  int Mt = b >> 4;
  int e = kj & 7;
  HA2[(size_t)(kc * 4 + Mt) * 512 + lane * 8 + e] = s0;
  size_t b3 = ((size_t)(kc * 4 + Mt) * 3) * 512 + lane * 8 + e;
  HA3[b3] = s0;
  HA3[b3 + 512] = s1;
  HA3[b3 + 1024] = s2;
}

// pack one embedding element (k,b) into EA3 (gates A, kc 0..15)
__device__ __forceinline__ void pack_e(int k, int b, double v,
                                       u16* __restrict__ EA3) {
  u16 s0, s1, s2;
  split3(v, s0, s1, s2);
  int kc = k >> 5, kj = k & 31;
  int lane = (b & 15) | ((kj >> 3) << 4);
  int Mt = b >> 4;
  int e = kj & 7;
  size_t b3 = ((size_t)(kc * 4 + Mt) * 3) * 512 + lane * 8 + e;
  EA3[b3] = s0;
  EA3[b3 + 512] = s1;
  EA3[b3 + 1024] = s2;
}

// sorted-4 (desc) insert, branchless
__device__ __forceinline__ void ins4(u64 v, u64& t0, u64& t1, u64& t2,
                                     u64& t3) {
  bool g0 = v > t0, g1 = v > t1, g2 = v > t2, g3 = v > t3;
  t3 = g2 ? t2 : (g3 ? v : t3);
  t2 = g1 ? t1 : (g2 ? v : t2);
  t1 = g0 ? t0 : (g1 ? v : t1);
  t0 = g0 ? v : t0;
}
// top-4 of two sorted-desc 4-lists (bitonic)
__device__ __forceinline__ void merge4(u64& a0, u64& a1, u64& a2, u64& a3,
                                       u64 b0, u64 b1, u64 b2, u64 b3) {
  u64 m0 = a0 > b3 ? a0 : b3;
  u64 m1 = a1 > b2 ? a1 : b2;
  u64 m2 = a2 > b1 ? a2 : b1;
  u64 m3 = a3 > b0 ? a3 : b0;
  u64 e0 = m0 > m2 ? m0 : m2, e2 = m0 > m2 ? m2 : m0;
  u64 e1 = m1 > m3 ? m1 : m3, e3 = m1 > m3 ? m3 : m1;
  a0 = e0 > e1 ? e0 : e1;
  a1 = e0 > e1 ? e1 : e0;
  a2 = e2 > e3 ? e2 : e3;
  a3 = e2 > e3 ? e3 : e2;
}

// ---- init: c0,h0 -> f64 state; pack h0 into HA3b; pack sos emb -> EA3 ----
__global__ __launch_bounds__(256) void k_init(
    const float* __restrict__ h0, const float* __restrict__ c0,
    const int* __restrict__ sos, const float* __restrict__ emb,
    double* __restrict__ cT64, double* __restrict__ h64,
    u16* __restrict__ HA2, u16* __restrict__ HA3b, u16* __restrict__ EA3) {
  int idx = blockIdx.x * 256 + threadIdx.x;  // 65536
  int j = idx >> 6, b = idx & 63;
  double h = (double)h0[b * HSZ + j];
  cT64[idx] = (double)c0[b * HSZ + j];
  h64[idx] = h;
  pack_h(j, b, h, HA2, HA3b);
  if (j < ESZ) pack_e(j, b, (double)emb[(size_t)sos[b] * ESZ + j], EA3);
}

// ---- pack Wout (f32 [K=1024][V]) into logits B single bf16, once ----
// WBL layout: [Nt=2000][kc=32][lane=64][e=8]
__global__ __launch_bounds__(256) void k_wpackL(const float* __restrict__ Wout,
                                                u16* __restrict__ WBL) {
  __shared__ float ls[32][64];
  int tid = threadIdx.x;
  int j0 = blockIdx.x * 64;
  int Nt0 = blockIdx.x * 4;
  for (int kc = 0; kc < 32; ++kc) {
    __syncthreads();
    #pragma unroll
    for (int rr = 0; rr < 8; ++rr) {
      int row = rr * 4 + (tid >> 6);
      ls[row][tid & 63] = Wout[(size_t)(kc * 32 + row) * VSZ + j0 + (tid & 63)];
    }
    __syncthreads();
    int lane = tid & 63, Ntl = tid >> 6;
    int col = Ntl * 16 + (lane & 15);
    int kb = (lane >> 4) * 8;
    alignas(16) u16 hibuf[8];
    #pragma unroll
    for (int e = 0; e < 8; ++e) hibuf[e] = f2bf(ls[kb + e][col]);
    size_t base = ((size_t)((Nt0 + Ntl) * 32 + kc)) * 512 + lane * 8;
    *(bf16x8*)&WBL[base] = *(const bf16x8*)hibuf;
  }
}

// ---- pack [Wx;Wh] (f32 [K=1536][4096]) into gates B 3-term, once ----
// WBG layout: [Nt=256][kc=48][term=3][lane=64][e=8]
__global__ __launch_bounds__(256) void k_wpackG(const float* __restrict__ Wx,
                                                const float* __restrict__ Wh,
                                                u16* __restrict__ WBG) {
  int tid = threadIdx.x;
  int Nt = blockIdx.x;  // 256 blocks
  int lane = tid & 63, w = tid >> 6;
  int col = Nt * 16 + (lane & 15);
  for (int i = 0; i < 12; ++i) {
    int kc = w * 12 + i;
    int kb = kc * 32 + (lane >> 4) * 8;
    alignas(16) u16 b0[8], b1[8], b2[8];
    #pragma unroll
    for (int e = 0; e < 8; ++e) {
      int k = kb + e;
      float v = (k < ESZ) ? Wx[(size_t)k * G4H + col]
                          : Wh[(size_t)(k - ESZ) * G4H + col];
      u16 s0, s1, s2;
      split3((double)v, s0, s1, s2);
      b0[e] = s0; b1[e] = s1; b2[e] = s2;
    }
    size_t base = ((size_t)(Nt * 48 + kc) * 3) * 512 + lane * 8;
    *(bf16x8*)&WBG[base] = *(const bf16x8*)b0;
    *(bf16x8*)&WBG[base + 512] = *(const bf16x8*)b1;
    *(bf16x8*)&WBG[base + 1024] = *(const bf16x8*)b2;
  }
}

// ---- fused gates+cell v2: grid 256 = 64 jtiles x 4 bgroups; 8 waves ----
// Wave w: gate g=w&3, K-half kh=w>>2 (24 chunks), batch tile mg only.
// 144 MFMA/wave (= r7's proven per-wave shape), 2 waves/SIMD, all 256 CUs.
// Cell = 256-thread pointwise f64 epilogue; halves summed in fixed order.
__global__ __launch_bounds__(512) void k_gatescell(
    const u16* __restrict__ EA3, const u16* __restrict__ HA3r,
    const u16* __restrict__ WBG, const float* __restrict__ bx,
    const float* __restrict__ bh, double* __restrict__ cT64,
    double* __restrict__ h64, u16* __restrict__ HA2,
    u16* __restrict__ HA3w) {
  __shared__ double gvL[8][256];  // 16 KB: [wave][jl*16+bl]
  int tid = threadIdx.x, lane = tid & 63, w = tid >> 6;  // 8 waves
  int g = w & 3, kh = w >> 2;
  int jt = blockIdx.x >> 2, mg = blockIdx.x & 3;  // adjacent blocks share jt
  int Nt = g * 64 + jt;

  double big[4];
  #pragma unroll
  for (int r = 0; r < 4; ++r) big[r] = 0.0;
  f32x4 accs = {0.f, 0.f, 0.f, 0.f};
  const f32x4 zz = {0.f, 0.f, 0.f, 0.f};

  for (int i = 0; i < 24; ++i) {
    int kc = kh * 24 + i;  // global K chunk (48 total)
    const u16* wb = WBG + ((size_t)(Nt * 48 + kc) * 3) * 512 + lane * 8;
    bf16x8 b0 = *(const bf16x8*)wb;
    bf16x8 b1 = *(const bf16x8*)(wb + 512);
    bf16x8 b2 = *(const bf16x8*)(wb + 1024);
    const u16* ha = (kc < 16)
        ? (EA3 + ((size_t)(kc * 4 + mg) * 3) * 512 + lane * 8)
        : (HA3r + ((size_t)((kc - 16) * 4 + mg) * 3) * 512 + lane * 8);
    bf16x8 a0 = *(const bf16x8*)ha;
    bf16x8 a1 = *(const bf16x8*)(ha + 512);
    bf16x8 a2 = *(const bf16x8*)(ha + 1024);
    // dominant term: isolated MFMA, promoted to f64 per chunk
    f32x4 tb = __builtin_amdgcn_mfma_f32_16x16x32_bf16(a0, b0, zz, 0, 0, 0);
    #pragma unroll
    for (int r = 0; r < 4; ++r) big[r] += (double)tb[r];
    // 5 cross terms (i+j<=2): chained f32 accumulation
    accs = __builtin_amdgcn_mfma_f32_16x16x32_bf16(a1, b0, accs, 0, 0, 0);
    accs = __builtin_amdgcn_mfma_f32_16x16x32_bf16(a0, b1, accs, 0, 0, 0);
    accs = __builtin_amdgcn_mfma_f32_16x16x32_bf16(a1, b1, accs, 0, 0, 0);
    accs = __builtin_amdgcn_mfma_f32_16x16x32_bf16(a2, b0, accs, 0, 0, 0);
    accs = __builtin_amdgcn_mfma_f32_16x16x32_bf16(a0, b2, accs, 0, 0, 0);
  }
  // partial (this K-half) -> LDS, keyed [jl*16+bl]
  #pragma unroll
  for (int r = 0; r < 4; ++r) {
    int bl = (lane >> 4) * 4 + r;  // C/D map (m89): row in 16-batch tile
    gvL[w][(lane & 15) * 16 + bl] = big[r] + (double)accs[r];
  }
  __syncthreads();

  // pointwise f64 cell: threads 0..255, one cell each (jl=tid>>4, bl=tid&15)
  if (tid < 256) {
    int jl = tid >> 4, bl = tid & 15;
    int j = jt * 16 + jl, b = mg * 16 + bl;
    double gv0 = (gvL[0][tid] + gvL[4][tid]) + (double)bx[j] + (double)bh[j];
    double gv1 = (gvL[1][tid] + gvL[5][tid]) + (double)bx[1024 + j] +
                 (double)bh[1024 + j];
    double gv2 = (gvL[2][tid] + gvL[6][tid]) + (double)bx[2048 + j] +
                 (double)bh[2048 + j];
    double gv3 = (gvL[3][tid] + gvL[7][tid]) + (double)bx[3072 + j] +
                 (double)bh[3072 + j];
    double c = cT64[(size_t)j * 64 + b];
    double f = 1.0 / (1.0 + exp(-gv0));
    double i = 1.0 / (1.0 + exp(-gv1));
    double gg = tanh(gv2);
    double o = 1.0 / (1.0 + exp(-gv3));
    c = f * c + i * gg;
    double h = o * tanh(c);
    cT64[(size_t)j * 64 + b] = c;
    h64[(size_t)j * 64 + b] = h;
    pack_h(j, b, h, HA2, HA3w);
  }
}

// ---- logits: single-term bf16 MFMA + store + per-WAVE top-2 keys ----
// grid 500 x block 256 = 4 waves (1 Nt of 16 cols each). r7-verbatim math.
__global__ __launch_bounds__(256) void k_logits_mfma(
    int t, const u16* __restrict__ HA2, const u16* __restrict__ WBL,
    const float* __restrict__ bout, float* __restrict__ out,
    u64* __restrict__ p2) {
  int tid = threadIdx.x, lane = tid & 63, w = tid >> 6;
  int Nt = blockIdx.x * 4 + w;
  int colw = Nt * 16 + (lane & 15);
  const u16* wb = WBL + (size_t)Nt * 16384 + lane * 8;
  f32x4 acc[4] = {};

  #pragma unroll 2
  for (int kc = 0; kc < 32; ++kc) {
    bf16x8 bhv = *(const bf16x8*)(wb + (size_t)kc * 512);
    const u16* ha = HA2 + (size_t)kc * 2048 + lane * 8;
    #pragma unroll
    for (int Mt = 0; Mt < 4; ++Mt) {
      bf16x8 ah = *(const bf16x8*)(ha + Mt * 512);
      acc[Mt] = __builtin_amdgcn_mfma_f32_16x16x32_bf16(ah, bhv, acc[Mt], 0, 0, 0);
    }
  }

  float bo = bout[colw];
  float* orow = out + (size_t)t * BSZ * VSZ;
  u64 mykey = 0, mykey2 = 0;
  #pragma unroll
  for (int Mt = 0; Mt < 4; ++Mt) {
    #pragma unroll
    for (int r = 0; r < 4; ++r) {
      float v = acc[Mt][r] + bo;
      orow[(size_t)(Mt * 16 + (lane >> 4) * 4 + r) * VSZ + colw] = v;
      // top-2 butterfly over the 16 col-lanes (disjoint-set top2 merge)
      u64 kb_ = ((u64)ordf(v) << 32) | (unsigned)(~colw);
      u64 ks_ = 0;
      #pragma unroll
      for (int s = 1; s < 16; s <<= 1) {
        u64 ob = __shfl_xor(kb_, s, 64);
        u64 os = __shfl_xor(ks_, s, 64);
        u64 nb = kb_ > ob ? kb_ : ob;
        u64 lo = kb_ > ob ? ob : kb_;
        u64 s2 = ks_ > os ? ks_ : os;
        kb_ = nb;
        ks_ = lo > s2 ? lo : s2;
      }
      if ((lane & 15) == Mt * 4 + r) { mykey = kb_; mykey2 = ks_; }
    }
  }
  // batch = Mt*16 + rowgrp*4 + r, bijective in lane; slot unique PER WAVE.
  int batch = ((lane & 15) >> 2) * 16 + (lane >> 4) * 4 + (lane & 3);
  size_t slot = (size_t)batch * 2000 + blockIdx.x * 4 + w;
  p2[slot * 2] = mykey;
  p2[slot * 2 + 1] = mykey2;
}

// ---- refine: global top-4; exact f64 logits; pick token; pack emb EA3 ----
// grid 64 (one block per batch) x 256 threads.
__global__ __launch_bounds__(256) void k_refine(
    const u64* __restrict__ p2, const double* __restrict__ h64,
    const float* __restrict__ Wout, const float* __restrict__ bout,
    int* __restrict__ tokbuf, const float* __restrict__ emb,
    u16* __restrict__ EA3) {
  __shared__ u64 sm[256][4];
  __shared__ double rr[256][4];
  __shared__ int s_i[4];
  __shared__ int s_sel;
  int b = blockIdx.x, tid = threadIdx.x;
  u64 t0 = 0, t1 = 0, t2 = 0, t3 = 0;
  for (int i = tid; i < 2000; i += 256) {
    u64 x = p2[((size_t)b * 2000 + i) * 2];
    u64 y = p2[((size_t)b * 2000 + i) * 2 + 1];
    ins4(x, t0, t1, t2, t3);
    ins4(y, t0, t1, t2, t3);
  }
  sm[tid][0] = t0; sm[tid][1] = t1; sm[tid][2] = t2; sm[tid][3] = t3;
  __syncthreads();
  for (int off = 128; off > 0; off >>= 1) {
    if (tid < off) {
      u64 a0 = sm[tid][0], a1 = sm[tid][1], a2 = sm[tid][2], a3 = sm[tid][3];
      merge4(a0, a1, a2, a3, sm[tid + off][0], sm[tid + off][1],
             sm[tid + off][2], sm[tid + off][3]);
      sm[tid][0] = a0; sm[tid][1] = a1; sm[tid][2] = a2; sm[tid][3] = a3;
    }
    __syncthreads();
  }
  if (tid < 4) s_i[tid] = (int)(~(u32)(sm[0][tid] & 0xFFFFFFFFull));
  __syncthreads();
  int i0 = s_i[0], i1 = s_i[1], i2 = s_i[2], i3 = s_i[3];
  double a0 = 0.0, a1 = 0.0, a2 = 0.0, a3 = 0.0;
  #pragma unroll
  for (int q = 0; q < 4; ++q) {
    int k = tid * 4 + q;
    double h = h64[(size_t)k * 64 + b];
    const float* wr = Wout + (size_t)k * VSZ;
    a0 += h * (double)wr[i0];
    a1 += h * (double)wr[i1];
    a2 += h * (double)wr[i2];
    a3 += h * (double)wr[i3];
  }
  rr[tid][0] = a0; rr[tid][1] = a1; rr[tid][2] = a2; rr[tid][3] = a3;
  __syncthreads();
  for (int off = 128; off > 0; off >>= 1) {
    if (tid < off) {
      rr[tid][0] += rr[tid + off][0];
      rr[tid][1] += rr[tid + off][1];
      rr[tid][2] += rr[tid + off][2];
      rr[tid][3] += rr[tid + off][3];
    }
    __syncthreads();
  }
  if (tid == 0) {
    double v0 = rr[0][0] + (double)bout[i0];
    double v1 = rr[0][1] + (double)bout[i1];
    double v2 = rr[0][2] + (double)bout[i2];
    double v3 = rr[0][3] + (double)bout[i3];
    double bv = v0; int bi = i0;
    if (v1 > bv || (v1 == bv && i1 < bi)) { bv = v1; bi = i1; }
    if (v2 > bv || (v2 == bv && i2 < bi)) { bv = v2; bi = i2; }
    if (v3 > bv || (v3 == bv && i3 < bi)) { bv = v3; bi = i3; }
    tokbuf[b] = bi;
    s_sel = bi;
  }
  __syncthreads();
  // pack next step's embedding A-frags for this batch (512 elems, 2/thread)
  int tokf = s_sel;
  int k = tid * 2;
  pack_e(k, b, (double)emb[(size_t)tokf * ESZ + k], EA3);
  pack_e(k + 1, b, (double)emb[(size_t)tokf * ESZ + k + 1], EA3);
}

// ================= fallback all-f32 path (round-1, proven) =================

__global__ __launch_bounds__(256) void k_initF(const float* __restrict__ h0,
                                               const float* __restrict__ c0,
                                               float* __restrict__ hT,
                                               float* __restrict__ cT) {
  int idx = blockIdx.x * 256 + threadIdx.x;
  int j = idx >> 6, b = idx & 63;
  hT[idx] = h0[b * HSZ + j];
  cT[idx] = c0[b * HSZ + j];
}

__global__ __launch_bounds__(256) void k_gatesF(
    int t, const int* __restrict__ sos, const u64* __restrict__ partials,
    const float* __restrict__ emb, const float* __restrict__ Wx,
    const float* __restrict__ Wh, const float* __restrict__ hT,
    float* __restrict__ gP) {
  __shared__ float xs[128 * 64];
  __shared__ u64 s_red[256];
  __shared__ int s_tok[64];
  int tid = threadIdx.x;
  if (t == 0) {
    if (tid < 64) s_tok[tid] = sos[tid];
  } else {
    int b = tid >> 2, q = tid & 3;
    u64 best = 0ull;
    int i0 = q * 63, i1 = i0 + 63;
    if (i1 > 250) i1 = 250;
    for (int i = i0; i < i1; ++i) {
      u64 v = partials[b * 512 + i];
      if (v > best) best = v;
    }
    s_red[tid] = best;
    __syncthreads();
    if (q == 0) {
      u64 m = best;
      #pragma unroll
      for (int k = 1; k < 4; ++k) {
        u64 v = s_red[tid + k];
        if (v > m) m = v;
      }
      s_tok[b] = (int)(~(unsigned)(m & 0xFFFFFFFFull));
    }
  }
  __syncthreads();
  int colblk = blockIdx.x & 63, ks = blockIdx.x >> 6;
  int col = colblk * 16 + (tid & 15);
  int b0 = (tid >> 4) * 4;
  float acc[4][4];
  #pragma unroll
  for (int g = 0; g < 4; ++g)
    #pragma unroll
    for (int bb = 0; bb < 4; ++bb) acc[g][bb] = 0.f;
  for (int kc = 0; kc < 3; ++kc) {
    int k0 = ks * 384 + kc * 128;
    __syncthreads();
    if (k0 < 512) {
      int b = tid & 63;
      int kk0 = (tid >> 6) * 32;
      const float* erow = emb + (size_t)s_tok[b] * ESZ + k0 + kk0;
      #pragma unroll
      for (int i = 0; i < 32; i += 4) {
        float4 v = *(const float4*)(erow + i);
        xs[(kk0 + i) * 64 + b] = v.x;
        xs[(kk0 + i + 1) * 64 + b] = v.y;
        xs[(kk0 + i + 2) * 64 + b] = v.z;
        xs[(kk0 + i + 3) * 64 + b] = v.w;
      }
    } else {
      const float* src = hT + (size_t)(k0 - 512) * 64;
      #pragma unroll
      for (int i = 0; i < 8192; i += 1024)
        *(float4*)&xs[i + tid * 4] = *(const float4*)(src + i + tid * 4);
    }
    __syncthreads();
    const float* Wb = (k0 < 512) ? (Wx + (size_t)k0 * G4H + col)
                                 : (Wh + (size_t)(k0 - 512) * G4H + col);
    #pragma unroll 4
    for (int kk = 0; kk < 128; ++kk) {
      float4 xv = *(const float4*)&xs[kk * 64 + b0];
      const float* wr = Wb + (size_t)kk * G4H;
      float w0 = wr[0], w1 = wr[1024], w2 = wr[2048], w3 = wr[3072];
      acc[0][0] += w0 * xv.x; acc[0][1] += w0 * xv.y;
      acc[0][2] += w0 * xv.z; acc[0][3] += w0 * xv.w;
      acc[1][0] += w1 * xv.x; acc[1][1] += w1 * xv.y;
      acc[1][2] += w1 * xv.z; acc[1][3] += w1 * xv.w;
      acc[2][0] += w2 * xv.x; acc[2][1] += w2 * xv.y;
      acc[2][2] += w2 * xv.z; acc[2][3] += w2 * xv.w;
      acc[3][0] += w3 * xv.x; acc[3][1] += w3 * xv.y;
      acc[3][2] += w3 * xv.z; acc[3][3] += w3 * xv.w;
    }
  }
  #pragma unroll
  for (int g = 0; g < 4; ++g) {
    float4 v = make_float4(acc[g][0], acc[g][1], acc[g][2], acc[g][3]);
    *(float4*)&gP[((size_t)ks * G4H + g * 1024 + col) * 64 + b0] = v;
  }
}

__global__ __launch_bounds__(256) void k_cellF(const float* __restrict__ gP,
                                               const float* __restrict__ bx,
                                               const float* __restrict__ bh,
                                               float* __restrict__ hT,
                                               float* __restrict__ cT) {
  int flat = (blockIdx.x * 256 + threadIdx.x) * 2;
  int j = flat >> 6;
  float2 gv[4];
  #pragma unroll
  for (int g = 0; g < 4; ++g) {
    size_t base = ((size_t)g * 1024 + j) * 64 + (flat & 63);
    float2 s = *(const float2*)&gP[base];
    #pragma unroll
    for (int ks = 1; ks < 4; ++ks) {
      float2 p = *(const float2*)&gP[(size_t)ks * 262144 + base];
      s.x += p.x; s.y += p.y;
    }
    float bias = bx[g * 1024 + j] + bh[g * 1024 + j];
    s.x += bias; s.y += bias;
    gv[g] = s;
  }
  float2 c = *(const float2*)&cT[flat];
  float fx = 1.f / (1.f + expf(-gv[0].x)), fy = 1.f / (1.f + expf(-gv[0].y));
  float ix = 1.f / (1.f + expf(-gv[1].x)), iy = 1.f / (1.f + expf(-gv[1].y));
  float gx = tanhf(gv[2].x), gy = tanhf(gv[2].y);
  float ox = 1.f / (1.f + expf(-gv[3].x)), oy = 1.f / (1.f + expf(-gv[3].y));
  float cx = fx * c.x + ix * gx, cy = fy * c.y + iy * gy;
  float hx = ox * tanhf(cx), hy = oy * tanhf(cy);
  *(float2*)&cT[flat] = make_float2(cx, cy);
  *(float2*)&hT[flat] = make_float2(hx, hy);
}

__global__ __launch_bounds__(512) void k_logitsF(
    int t, const float* __restrict__ hT, const float* __restrict__ Wout,
    const float* __restrict__ bout, float* __restrict__ out,
    u64* __restrict__ partials) {
  __shared__ float hs[128 * 64];
  int tid = threadIdx.x;
  int lane = tid & 63;
  int bg = tid >> 6;
  int b0 = bg * 8;
  int j0 = blockIdx.x * 128 + lane * 2;
  float a0[8], a1[8];
  #pragma unroll
  for (int i = 0; i < 8; ++i) { a0[i] = 0.f; a1[i] = 0.f; }
  for (int kc = 0; kc < 8; ++kc) {
    int k0 = kc * 128;
    __syncthreads();
    #pragma unroll
    for (int i = 0; i < 8192; i += 2048)
      *(float4*)&hs[i + tid * 4] =
          *(const float4*)&hT[(size_t)k0 * 64 + i + tid * 4];
    __syncthreads();
    #pragma unroll 4
    for (int kk = 0; kk < 128; ++kk) {
      float2 wv = *(const float2*)(Wout + (size_t)(k0 + kk) * VSZ + j0);
      const float* hrow = &hs[kk * 64 + b0];
      float4 h0v = *(const float4*)(hrow);
      float4 h1v = *(const float4*)(hrow + 4);
      a0[0] += h0v.x * wv.x; a1[0] += h0v.x * wv.y;
      a0[1] += h0v.y * wv.x; a1[1] += h0v.y * wv.y;
      a0[2] += h0v.z * wv.x; a1[2] += h0v.z * wv.y;
      a0[3] += h0v.w * wv.x; a1[3] += h0v.w * wv.y;
      a0[4] += h1v.x * wv.x; a1[4] += h1v.x * wv.y;
      a0[5] += h1v.y * wv.x; a1[5] += h1v.y * wv.y;
      a0[6] += h1v.z * wv.x; a1[6] += h1v.z * wv.y;
      a0[7] += h1v.w * wv.x; a1[7] += h1v.w * wv.y;
    }
  }
  float bo0 = bout[j0], bo1 = bout[j0 + 1];
  float* orow = out + (size_t)t * BSZ * VSZ;
  #pragma unroll
  for (int bb = 0; bb < 8; ++bb) {
    float v0 = a0[bb] + bo0, v1 = a1[bb] + bo1;
    *(float2*)(orow + (size_t)(b0 + bb) * VSZ + j0) = make_float2(v0, v1);
    float m; int mi;
    if (v1 > v0) { m = v1; mi = j0 + 1; } else { m = v0; mi = j0; }
    u64 key = ((u64)ordf(m) << 32) | (unsigned)(~mi);
    #pragma unroll
    for (int s = 32; s > 0; s >>= 1) {
      u64 o = __shfl_xor(key, s, 64);
      if (o > key) key = o;
    }
    if (lane == bb) partials[(size_t)(b0 + bb) * 512 + blockIdx.x] = key;
  }
}

extern "C" void kernel_launch(void* const* d_in, const int* in_sizes, int n_in,
                              void* d_out, int out_size, void* d_ws,
                              size_t ws_size, hipStream_t stream) {
  const float* emb  = (const float*)d_in[0];
  const float* Wx   = (const float*)d_in[1];
  const float* bx   = (const float*)d_in[2];
  const float* Wh   = (const float*)d_in[3];
  const float* bh   = (const float*)d_in[4];
  const float* Wout = (const float*)d_in[5];
  const float* bout = (const float*)d_in[6];
  const float* h0   = (const float*)d_in[7];
  const float* c0   = (const float*)d_in[8];
  const int*   sos  = (const int*)d_in[9];
  float* out = (float*)d_out;

  bool mfma = ws_size >= 123814912ULL;

  // ws layout (cumulative byte offsets, audited r12):
  //   cT64 @ 0         size 524288
  //   h64  @ 524288    size 524288
  //   HA2  @ 1048576   size 131072   (128 tiles * 512 u16 * 2B)
  //   HA3a @ 1179648   size 393216   (128 tiles * 3 * 512 u16 * 2B)
  //   HA3b @ 1572864   size 393216
  //   EA3  @ 1966080   size 196608   (64 tiles * 3 * 512 u16 * 2B)
  //   tokb @ 2162688   size 256
  //   p2   @ 2166784   size 2048000  (64*2000*2 u64)
  //   WBL  @ 4214784   size 65536000
  //   WBG  @ 69750784  size 37748736 -> end 107499520
  char* base = (char*)d_ws;
  double* cT64 = (double*)(base);
  double* h64  = (double*)(base + 524288);
  u16*    HA2  = (u16*)(base + 1048576);
  u16*    HA3a = (u16*)(base + 1179648);
  u16*    HA3b = (u16*)(base + 1572864);
  u16*    EA3  = (u16*)(base + 1966080);
  int*    tokb = (int*)(base + 2162688);
  u64*    p2   = (u64*)(base + 2166784);
  u16*    WBL  = (u16*)(base + 4214784);
  u16*    WBG  = (u16*)(base + 69750784);
  // f32-fallback layout overlaps (paths exclusive)
  float* hT = (float*)(base);
  float* cT = (float*)(base + 262144);
  float* gP = (float*)(base + 524288);
  u64* partials = (u64*)(base + 4718592);

  if (mfma) {
    k_wpackL<<<500, 256, 0, stream>>>(Wout, WBL);
    k_wpackG<<<256, 256, 0, stream>>>(Wx, Wh, WBG);
    k_init<<<256, 256, 0, stream>>>(h0, c0, sos, emb, cT64, h64, HA2, HA3b,
                                    EA3);
    for (int t = 0; t < TSZ; ++t) {
      const u16* HA3r = (t & 1) ? HA3a : HA3b;  // gates read h_{t-1}
      u16* HA3w = (t & 1) ? HA3b : HA3a;        // cell writes h_t
      k_gatescell<<<256, 512, 0, stream>>>(EA3, HA3r, WBG, bx, bh, cT64, h64,
                                           HA2, HA3w);
      k_logits_mfma<<<500, 256, 0, stream>>>(t, HA2, WBL, bout, out, p2);
      if (t + 1 < TSZ)  // last step's token is never consumed
        k_refine<<<64, 256, 0, stream>>>(p2, h64, Wout, bout, tokb, emb, EA3);
    }
  } else {
    k_initF<<<256, 256, 0, stream>>>(h0, c0, hT, cT);
    for (int t = 0; t < TSZ; ++t) {
      k_gatesF<<<256, 256, 0, stream>>>(t, sos, partials, emb, Wx, Wh, hT, gP);
      k_cellF<<<128, 256, 0, stream>>>(gP, bx, bh, hT, cT);
      k_logitsF<<<250, 512, 0, stream>>>(t, hT, Wout, bout, out, partials);
    }
  }
}

// Round 14
// 1794.140 us; speedup vs baseline: 4.8539x; 1.1762x over previous
//
#include <hip/hip_runtime.h>

// DecoderLSTM: V=32000 E=512 H=1024 B=64 T=32, fp32, greedy decode.
// Design (round 14 = round 13 + XCD-aware block swizzle in k_gatescell):
// r13's 4 batch-group blocks per j-tile read IDENTICAL WBG columns but land
// on different XCDs (default round-robin) -> 4x L3 traffic (~147 MB/step).
// Swizzle blockIdx so the 4 mg-blocks of each jt share an XCD: one L3 fetch,
// three L2 hits (576 KB/jt fits the 4 MB per-XCD L2). Pure index remap;
// per-(jt,mg) math bit-identical to r13 (passed, 2110us, absmax 3.9e-3).
//  - k_gatescell: grid 256 = 64 jtiles x 4 bgroups; block 512 = 8 waves;
//    wave (g,kh): gate g, K-half kh, 144 MFMA; f64 cell epilogue in-block.
//  - EA3 pre-split emb A-frags (refine tail / init).
//  - k_logits_mfma / k_refine: proven r7 math (single-term bf16 logits,
//    per-wave top-2 keys, exact f64 top-4 refine).
// 98 graph nodes. No cross-block sync anywhere (r8/r10 lesson).
// Falls back to round-1 all-f32 path if ws too small.

#define VSZ 32000
#define ESZ 512
#define HSZ 1024
#define BSZ 64
#define TSZ 32
#define G4H 4096

typedef unsigned short u16;
typedef unsigned int u32;
typedef unsigned long long u64;
typedef __attribute__((ext_vector_type(8))) short bf16x8;
typedef __attribute__((ext_vector_type(4))) float f32x4;

__device__ __forceinline__ unsigned ordf(float f) {
  unsigned u = __float_as_uint(f);
  return (u & 0x80000000u) ? ~u : (u | 0x80000000u);  // monotone float->uint
}
__device__ __forceinline__ u16 f2bf(float f) {  // f32 -> bf16 RNE
  u32 u = __float_as_uint(f);
  return (u16)((u + 0x7FFFu + ((u >> 16) & 1u)) >> 16);
}
__device__ __forceinline__ float bf2f(u16 s) {
  return __uint_as_float(((u32)s) << 16);
}
// 3-way bf16 split of a double (captures ~24 bits)
__device__ __forceinline__ void split3(double v, u16& s0, u16& s1, u16& s2) {
  s0 = f2bf((float)v);
  double r = v - (double)bf2f(s0);
  s1 = f2bf((float)r);
  double r2 = r - (double)bf2f(s1);
  s2 = f2bf((float)r2);
}

// pack h (f64) into HA2 (logits A: single bf16) and HA3 (gates A: 3 terms)
__device__ __forceinline__ void pack_h(int j, int b, double h,
                                       u16* __restrict__ HA2,
                                       u16* __restrict__ HA3) {
  u16 s0, s1, s2;
  split3(h, s0, s1, s2);
  int kc = j >> 5, kj = j & 31;
  int lane = (b & 15) | ((kj >> 3) << 4);
  int Mt = b >> 4;
  int e = kj & 7;
  HA2[(size_t)(kc * 4 + Mt) * 512 + lane * 8 + e] = s0;
  size_t b3 = ((size_t)(kc * 4 + Mt) * 3) * 512 + lane * 8 + e;
  HA3[b3] = s0;
  HA3[b3 + 512] = s1;
  HA3[b3 + 1024] = s2;
}

// pack one embedding element (k,b) into EA3 (gates A, kc 0..15)
__device__ __forceinline__ void pack_e(int k, int b, double v,
                                       u16* __restrict__ EA3) {
  u16 s0, s1, s2;
  split3(v, s0, s1, s2);
  int kc = k >> 5, kj = k & 31;
  int lane = (b & 15) | ((kj >> 3) << 4);
  int Mt = b >> 4;
  int e = kj & 7;
  size_t b3 = ((size_t)(kc * 4 + Mt) * 3) * 512 + lane * 8 + e;
  EA3[b3] = s0;
  EA3[b3 + 512] = s1;
  EA3[b3 + 1024] = s2;
}

// sorted-4 (desc) insert, branchless
__device__ __forceinline__ void ins4(u64 v, u64& t0, u64& t1, u64& t2,
                                     u64& t3) {
  bool g0 = v > t0, g1 = v > t1, g2 = v > t2, g3 = v > t3;
  t3 = g2 ? t2 : (g3 ? v : t3);
  t2 = g1 ? t1 : (g2 ? v : t2);
  t1 = g0 ? t0 : (g1 ? v : t1);
  t0 = g0 ? v : t0;
}
// top-4 of two sorted-desc 4-lists (bitonic)
__device__ __forceinline__ void merge4(u64& a0, u64& a1, u64& a2, u64& a3,
                                       u64 b0, u64 b1, u64 b2, u64 b3) {
  u64 m0 = a0 > b3 ? a0 : b3;
  u64 m1 = a1 > b2 ? a1 : b2;
  u64 m2 = a2 > b1 ? a2 : b1;
  u64 m3 = a3 > b0 ? a3 : b0;
  u64 e0 = m0 > m2 ? m0 : m2, e2 = m0 > m2 ? m2 : m0;
  u64 e1 = m1 > m3 ? m1 : m3, e3 = m1 > m3 ? m3 : m1;
  a0 = e0 > e1 ? e0 : e1;
  a1 = e0 > e1 ? e1 : e0;
  a2 = e2 > e3 ? e2 : e3;
  a3 = e2 > e3 ? e3 : e2;
}

// ---- init: c0,h0 -> f64 state; pack h0 into HA3b; pack sos emb -> EA3 ----
__global__ __launch_bounds__(256) void k_init(
    const float* __restrict__ h0, const float* __restrict__ c0,
    const int* __restrict__ sos, const float* __restrict__ emb,
    double* __restrict__ cT64, double* __restrict__ h64,
    u16* __restrict__ HA2, u16* __restrict__ HA3b, u16* __restrict__ EA3) {
  int idx = blockIdx.x * 256 + threadIdx.x;  // 65536
  int j = idx >> 6, b = idx & 63;
  double h = (double)h0[b * HSZ + j];
  cT64[idx] = (double)c0[b * HSZ + j];
  h64[idx] = h;
  pack_h(j, b, h, HA2, HA3b);
  if (j < ESZ) pack_e(j, b, (double)emb[(size_t)sos[b] * ESZ + j], EA3);
}

// ---- pack Wout (f32 [K=1024][V]) into logits B single bf16, once ----
// WBL layout: [Nt=2000][kc=32][lane=64][e=8]
__global__ __launch_bounds__(256) void k_wpackL(const float* __restrict__ Wout,
                                                u16* __restrict__ WBL) {
  __shared__ float ls[32][64];
  int tid = threadIdx.x;
  int j0 = blockIdx.x * 64;
  int Nt0 = blockIdx.x * 4;
  for (int kc = 0; kc < 32; ++kc) {
    __syncthreads();
    #pragma unroll
    for (int rr = 0; rr < 8; ++rr) {
      int row = rr * 4 + (tid >> 6);
      ls[row][tid & 63] = Wout[(size_t)(kc * 32 + row) * VSZ + j0 + (tid & 63)];
    }
    __syncthreads();
    int lane = tid & 63, Ntl = tid >> 6;
    int col = Ntl * 16 + (lane & 15);
    int kb = (lane >> 4) * 8;
    alignas(16) u16 hibuf[8];
    #pragma unroll
    for (int e = 0; e < 8; ++e) hibuf[e] = f2bf(ls[kb + e][col]);
    size_t base = ((size_t)((Nt0 + Ntl) * 32 + kc)) * 512 + lane * 8;
    *(bf16x8*)&WBL[base] = *(const bf16x8*)hibuf;
  }
}

// ---- pack [Wx;Wh] (f32 [K=1536][4096]) into gates B 3-term, once ----
// WBG layout: [Nt=256][kc=48][term=3][lane=64][e=8]
__global__ __launch_bounds__(256) void k_wpackG(const float* __restrict__ Wx,
                                                const float* __restrict__ Wh,
                                                u16* __restrict__ WBG) {
  int tid = threadIdx.x;
  int Nt = blockIdx.x;  // 256 blocks
  int lane = tid & 63, w = tid >> 6;
  int col = Nt * 16 + (lane & 15);
  for (int i = 0; i < 12; ++i) {
    int kc = w * 12 + i;
    int kb = kc * 32 + (lane >> 4) * 8;
    alignas(16) u16 b0[8], b1[8], b2[8];
    #pragma unroll
    for (int e = 0; e < 8; ++e) {
      int k = kb + e;
      float v = (k < ESZ) ? Wx[(size_t)k * G4H + col]
                          : Wh[(size_t)(k - ESZ) * G4H + col];
      u16 s0, s1, s2;
      split3((double)v, s0, s1, s2);
      b0[e] = s0; b1[e] = s1; b2[e] = s2;
    }
    size_t base = ((size_t)(Nt * 48 + kc) * 3) * 512 + lane * 8;
    *(bf16x8*)&WBG[base] = *(const bf16x8*)b0;
    *(bf16x8*)&WBG[base + 512] = *(const bf16x8*)b1;
    *(bf16x8*)&WBG[base + 1024] = *(const bf16x8*)b2;
  }
}

// ---- fused gates+cell v2 + XCD swizzle: 256 blocks x 512 threads ----
// Swizzle: xcd=q&7, slot=q>>3; jt=xcd+8*(slot>>2), mg=slot&3. The 4 mg
// blocks of a jt share q&7 -> same XCD -> WBG tile hits L2 after 1st fetch.
// Wave w: gate g=w&3, K-half kh=w>>2 (24 chunks x 6 MFMA), batch tile mg.
// Cell = 256-thread pointwise f64 epilogue; halves summed in fixed order.
__global__ __launch_bounds__(512) void k_gatescell(
    const u16* __restrict__ EA3, const u16* __restrict__ HA3r,
    const u16* __restrict__ WBG, const float* __restrict__ bx,
    const float* __restrict__ bh, double* __restrict__ cT64,
    double* __restrict__ h64, u16* __restrict__ HA2,
    u16* __restrict__ HA3w) {
  __shared__ double gvL[8][256];  // 16 KB: [wave][jl*16+bl]
  int tid = threadIdx.x, lane = tid & 63, w = tid >> 6;  // 8 waves
  int g = w & 3, kh = w >> 2;
  int q = blockIdx.x;
  int jt = (q & 7) + 8 * ((q >> 3) >> 2);  // XCD-coherent j-tile
  int mg = (q >> 3) & 3;                   // batch group within jt
  int Nt = g * 64 + jt;

  double big[4];
  #pragma unroll
  for (int r = 0; r < 4; ++r) big[r] = 0.0;
  f32x4 accs = {0.f, 0.f, 0.f, 0.f};
  const f32x4 zz = {0.f, 0.f, 0.f, 0.f};

  for (int i = 0; i < 24; ++i) {
    int kc = kh * 24 + i;  // global K chunk (48 total)
    const u16* wb = WBG + ((size_t)(Nt * 48 + kc) * 3) * 512 + lane * 8;
    bf16x8 b0 = *(const bf16x8*)wb;
    bf16x8 b1 = *(const bf16x8*)(wb + 512);
    bf16x8 b2 = *(const bf16x8*)(wb + 1024);
    const u16* ha = (kc < 16)
        ? (EA3 + ((size_t)(kc * 4 + mg) * 3) * 512 + lane * 8)
        : (HA3r + ((size_t)((kc - 16) * 4 + mg) * 3) * 512 + lane * 8);
    bf16x8 a0 = *(const bf16x8*)ha;
    bf16x8 a1 = *(const bf16x8*)(ha + 512);
    bf16x8 a2 = *(const bf16x8*)(ha + 1024);
    // dominant term: isolated MFMA, promoted to f64 per chunk
    f32x4 tb = __builtin_amdgcn_mfma_f32_16x16x32_bf16(a0, b0, zz, 0, 0, 0);
    #pragma unroll
    for (int r = 0; r < 4; ++r) big[r] += (double)tb[r];
    // 5 cross terms (i+j<=2): chained f32 accumulation
    accs = __builtin_amdgcn_mfma_f32_16x16x32_bf16(a1, b0, accs, 0, 0, 0);
    accs = __builtin_amdgcn_mfma_f32_16x16x32_bf16(a0, b1, accs, 0, 0, 0);
    accs = __builtin_amdgcn_mfma_f32_16x16x32_bf16(a1, b1, accs, 0, 0, 0);
    accs = __builtin_amdgcn_mfma_f32_16x16x32_bf16(a2, b0, accs, 0, 0, 0);
    accs = __builtin_amdgcn_mfma_f32_16x16x32_bf16(a0, b2, accs, 0, 0, 0);
  }
  // partial (this K-half) -> LDS, keyed [jl*16+bl]
  #pragma unroll
  for (int r = 0; r < 4; ++r) {
    int bl = (lane >> 4) * 4 + r;  // C/D map (m89): row in 16-batch tile
    gvL[w][(lane & 15) * 16 + bl] = big[r] + (double)accs[r];
  }
  __syncthreads();

  // pointwise f64 cell: threads 0..255, one cell each (jl=tid>>4, bl=tid&15)
  if (tid < 256) {
    int jl = tid >> 4, bl = tid & 15;
    int j = jt * 16 + jl, b = mg * 16 + bl;
    double gv0 = (gvL[0][tid] + gvL[4][tid]) + (double)bx[j] + (double)bh[j];
    double gv1 = (gvL[1][tid] + gvL[5][tid]) + (double)bx[1024 + j] +
                 (double)bh[1024 + j];
    double gv2 = (gvL[2][tid] + gvL[6][tid]) + (double)bx[2048 + j] +
                 (double)bh[2048 + j];
    double gv3 = (gvL[3][tid] + gvL[7][tid]) + (double)bx[3072 + j] +
                 (double)bh[3072 + j];
    double c = cT64[(size_t)j * 64 + b];
    double f = 1.0 / (1.0 + exp(-gv0));
    double i = 1.0 / (1.0 + exp(-gv1));
    double gg = tanh(gv2);
    double o = 1.0 / (1.0 + exp(-gv3));
    c = f * c + i * gg;
    double h = o * tanh(c);
    cT64[(size_t)j * 64 + b] = c;
    h64[(size_t)j * 64 + b] = h;
    pack_h(j, b, h, HA2, HA3w);
  }
}

// ---- logits: single-term bf16 MFMA + store + per-WAVE top-2 keys ----
// grid 500 x block 256 = 4 waves (1 Nt of 16 cols each). r7-verbatim math.
__global__ __launch_bounds__(256) void k_logits_mfma(
    int t, const u16* __restrict__ HA2, const u16* __restrict__ WBL,
    const float* __restrict__ bout, float* __restrict__ out,
    u64* __restrict__ p2) {
  int tid = threadIdx.x, lane = tid & 63, w = tid >> 6;
  int Nt = blockIdx.x * 4 + w;
  int colw = Nt * 16 + (lane & 15);
  const u16* wb = WBL + (size_t)Nt * 16384 + lane * 8;
  f32x4 acc[4] = {};

  #pragma unroll 2
  for (int kc = 0; kc < 32; ++kc) {
    bf16x8 bhv = *(const bf16x8*)(wb + (size_t)kc * 512);
    const u16* ha = HA2 + (size_t)kc * 2048 + lane * 8;
    #pragma unroll
    for (int Mt = 0; Mt < 4; ++Mt) {
      bf16x8 ah = *(const bf16x8*)(ha + Mt * 512);
      acc[Mt] = __builtin_amdgcn_mfma_f32_16x16x32_bf16(ah, bhv, acc[Mt], 0, 0, 0);
    }
  }

  float bo = bout[colw];
  float* orow = out + (size_t)t * BSZ * VSZ;
  u64 mykey = 0, mykey2 = 0;
  #pragma unroll
  for (int Mt = 0; Mt < 4; ++Mt) {
    #pragma unroll
    for (int r = 0; r < 4; ++r) {
      float v = acc[Mt][r] + bo;
      orow[(size_t)(Mt * 16 + (lane >> 4) * 4 + r) * VSZ + colw] = v;
      // top-2 butterfly over the 16 col-lanes (disjoint-set top2 merge)
      u64 kb_ = ((u64)ordf(v) << 32) | (unsigned)(~colw);
      u64 ks_ = 0;
      #pragma unroll
      for (int s = 1; s < 16; s <<= 1) {
        u64 ob = __shfl_xor(kb_, s, 64);
        u64 os = __shfl_xor(ks_, s, 64);
        u64 nb = kb_ > ob ? kb_ : ob;
        u64 lo = kb_ > ob ? ob : kb_;
        u64 s2 = ks_ > os ? ks_ : os;
        kb_ = nb;
        ks_ = lo > s2 ? lo : s2;
      }
      if ((lane & 15) == Mt * 4 + r) { mykey = kb_; mykey2 = ks_; }
    }
  }
  // batch = Mt*16 + rowgrp*4 + r, bijective in lane; slot unique PER WAVE.
  int batch = ((lane & 15) >> 2) * 16 + (lane >> 4) * 4 + (lane & 3);
  size_t slot = (size_t)batch * 2000 + blockIdx.x * 4 + w;
  p2[slot * 2] = mykey;
  p2[slot * 2 + 1] = mykey2;
}

// ---- refine: global top-4; exact f64 logits; pick token; pack emb EA3 ----
// grid 64 (one block per batch) x 256 threads.
__global__ __launch_bounds__(256) void k_refine(
    const u64* __restrict__ p2, const double* __restrict__ h64,
    const float* __restrict__ Wout, const float* __restrict__ bout,
    int* __restrict__ tokbuf, const float* __restrict__ emb,
    u16* __restrict__ EA3) {
  __shared__ u64 sm[256][4];
  __shared__ double rr[256][4];
  __shared__ int s_i[4];
  __shared__ int s_sel;
  int b = blockIdx.x, tid = threadIdx.x;
  u64 t0 = 0, t1 = 0, t2 = 0, t3 = 0;
  for (int i = tid; i < 2000; i += 256) {
    u64 x = p2[((size_t)b * 2000 + i) * 2];
    u64 y = p2[((size_t)b * 2000 + i) * 2 + 1];
    ins4(x, t0, t1, t2, t3);
    ins4(y, t0, t1, t2, t3);
  }
  sm[tid][0] = t0; sm[tid][1] = t1; sm[tid][2] = t2; sm[tid][3] = t3;
  __syncthreads();
  for (int off = 128; off > 0; off >>= 1) {
    if (tid < off) {
      u64 a0 = sm[tid][0], a1 = sm[tid][1], a2 = sm[tid][2], a3 = sm[tid][3];
      merge4(a0, a1, a2, a3, sm[tid + off][0], sm[tid + off][1],
             sm[tid + off][2], sm[tid + off][3]);
      sm[tid][0] = a0; sm[tid][1] = a1; sm[tid][2] = a2; sm[tid][3] = a3;
    }
    __syncthreads();
  }
  if (tid < 4) s_i[tid] = (int)(~(u32)(sm[0][tid] & 0xFFFFFFFFull));
  __syncthreads();
  int i0 = s_i[0], i1 = s_i[1], i2 = s_i[2], i3 = s_i[3];
  double a0 = 0.0, a1 = 0.0, a2 = 0.0, a3 = 0.0;
  #pragma unroll
  for (int q = 0; q < 4; ++q) {
    int k = tid * 4 + q;
    double h = h64[(size_t)k * 64 + b];
    const float* wr = Wout + (size_t)k * VSZ;
    a0 += h * (double)wr[i0];
    a1 += h * (double)wr[i1];
    a2 += h * (double)wr[i2];
    a3 += h * (double)wr[i3];
  }
  rr[tid][0] = a0; rr[tid][1] = a1; rr[tid][2] = a2; rr[tid][3] = a3;
  __syncthreads();
  for (int off = 128; off > 0; off >>= 1) {
    if (tid < off) {
      rr[tid][0] += rr[tid + off][0];
      rr[tid][1] += rr[tid + off][1];
      rr[tid][2] += rr[tid + off][2];
      rr[tid][3] += rr[tid + off][3];
    }
    __syncthreads();
  }
  if (tid == 0) {
    double v0 = rr[0][0] + (double)bout[i0];
    double v1 = rr[0][1] + (double)bout[i1];
    double v2 = rr[0][2] + (double)bout[i2];
    double v3 = rr[0][3] + (double)bout[i3];
    double bv = v0; int bi = i0;
    if (v1 > bv || (v1 == bv && i1 < bi)) { bv = v1; bi = i1; }
    if (v2 > bv || (v2 == bv && i2 < bi)) { bv = v2; bi = i2; }
    if (v3 > bv || (v3 == bv && i3 < bi)) { bv = v3; bi = i3; }
    tokbuf[b] = bi;
    s_sel = bi;
  }
  __syncthreads();
  // pack next step's embedding A-frags for this batch (512 elems, 2/thread)
  int tokf = s_sel;
  int k = tid * 2;
  pack_e(k, b, (double)emb[(size_t)tokf * ESZ + k], EA3);
  pack_e(k + 1, b, (double)emb[(size_t)tokf * ESZ + k + 1], EA3);
}

// ================= fallback all-f32 path (round-1, proven) =================

__global__ __launch_bounds__(256) void k_initF(const float* __restrict__ h0,
                                               const float* __restrict__ c0,
                                               float* __restrict__ hT,
                                               float* __restrict__ cT) {
  int idx = blockIdx.x * 256 + threadIdx.x;
  int j = idx >> 6, b = idx & 63;
  hT[idx] = h0[b * HSZ + j];
  cT[idx] = c0[b * HSZ + j];
}

__global__ __launch_bounds__(256) void k_gatesF(
    int t, const int* __restrict__ sos, const u64* __restrict__ partials,
    const float* __restrict__ emb, const float* __restrict__ Wx,
    const float* __restrict__ Wh, const float* __restrict__ hT,
    float* __restrict__ gP) {
  __shared__ float xs[128 * 64];
  __shared__ u64 s_red[256];
  __shared__ int s_tok[64];
  int tid = threadIdx.x;
  if (t == 0) {
    if (tid < 64) s_tok[tid] = sos[tid];
  } else {
    int b = tid >> 2, q = tid & 3;
    u64 best = 0ull;
    int i0 = q * 63, i1 = i0 + 63;
    if (i1 > 250) i1 = 250;
    for (int i = i0; i < i1; ++i) {
      u64 v = partials[b * 512 + i];
      if (v > best) best = v;
    }
    s_red[tid] = best;
    __syncthreads();
    if (q == 0) {
      u64 m = best;
      #pragma unroll
      for (int k = 1; k < 4; ++k) {
        u64 v = s_red[tid + k];
        if (v > m) m = v;
      }
      s_tok[b] = (int)(~(unsigned)(m & 0xFFFFFFFFull));
    }
  }
  __syncthreads();
  int colblk = blockIdx.x & 63, ks = blockIdx.x >> 6;
  int col = colblk * 16 + (tid & 15);
  int b0 = (tid >> 4) * 4;
  float acc[4][4];
  #pragma unroll
  for (int g = 0; g < 4; ++g)
    #pragma unroll
    for (int bb = 0; bb < 4; ++bb) acc[g][bb] = 0.f;
  for (int kc = 0; kc < 3; ++kc) {
    int k0 = ks * 384 + kc * 128;
    __syncthreads();
    if (k0 < 512) {
      int b = tid & 63;
      int kk0 = (tid >> 6) * 32;
      const float* erow = emb + (size_t)s_tok[b] * ESZ + k0 + kk0;
      #pragma unroll
      for (int i = 0; i < 32; i += 4) {
        float4 v = *(const float4*)(erow + i);
        xs[(kk0 + i) * 64 + b] = v.x;
        xs[(kk0 + i + 1) * 64 + b] = v.y;
        xs[(kk0 + i + 2) * 64 + b] = v.z;
        xs[(kk0 + i + 3) * 64 + b] = v.w;
      }
    } else {
      const float* src = hT + (size_t)(k0 - 512) * 64;
      #pragma unroll
      for (int i = 0; i < 8192; i += 1024)
        *(float4*)&xs[i + tid * 4] = *(const float4*)(src + i + tid * 4);
    }
    __syncthreads();
    const float* Wb = (k0 < 512) ? (Wx + (size_t)k0 * G4H + col)
                                 : (Wh + (size_t)(k0 - 512) * G4H + col);
    #pragma unroll 4
    for (int kk = 0; kk < 128; ++kk) {
      float4 xv = *(const float4*)&xs[kk * 64 + b0];
      const float* wr = Wb + (size_t)kk * G4H;
      float w0 = wr[0], w1 = wr[1024], w2 = wr[2048], w3 = wr[3072];
      acc[0][0] += w0 * xv.x; acc[0][1] += w0 * xv.y;
      acc[0][2] += w0 * xv.z; acc[0][3] += w0 * xv.w;
      acc[1][0] += w1 * xv.x; acc[1][1] += w1 * xv.y;
      acc[1][2] += w1 * xv.z; acc[1][3] += w1 * xv.w;
      acc[2][0] += w2 * xv.x; acc[2][1] += w2 * xv.y;
      acc[2][2] += w2 * xv.z; acc[2][3] += w2 * xv.w;
      acc[3][0] += w3 * xv.x; acc[3][1] += w3 * xv.y;
      acc[3][2] += w3 * xv.z; acc[3][3] += w3 * xv.w;
    }
  }
  #pragma unroll
  for (int g = 0; g < 4; ++g) {
    float4 v = make_float4(acc[g][0], acc[g][1], acc[g][2], acc[g][3]);
    *(float4*)&gP[((size_t)ks * G4H + g * 1024 + col) * 64 + b0] = v;
  }
}

__global__ __launch_bounds__(256) void k_cellF(const float* __restrict__ gP,
                                               const float* __restrict__ bx,
                                               const float* __restrict__ bh,
                                               float* __restrict__ hT,
                                               float* __restrict__ cT) {
  int flat = (blockIdx.x * 256 + threadIdx.x) * 2;
  int j = flat >> 6;
  float2 gv[4];
  #pragma unroll
  for (int g = 0; g < 4; ++g) {
    size_t base = ((size_t)g * 1024 + j) * 64 + (flat & 63);
    float2 s = *(const float2*)&gP[base];
    #pragma unroll
    for (int ks = 1; ks < 4; ++ks) {
      float2 p = *(const float2*)&gP[(size_t)ks * 262144 + base];
      s.x += p.x; s.y += p.y;
    }
    float bias = bx[g * 1024 + j] + bh[g * 1024 + j];
    s.x += bias; s.y += bias;
    gv[g] = s;
  }
  float2 c = *(const float2*)&cT[flat];
  float fx = 1.f / (1.f + expf(-gv[0].x)), fy = 1.f / (1.f + expf(-gv[0].y));
  float ix = 1.f / (1.f + expf(-gv[1].x)), iy = 1.f / (1.f + expf(-gv[1].y));
  float gx = tanhf(gv[2].x), gy = tanhf(gv[2].y);
  float ox = 1.f / (1.f + expf(-gv[3].x)), oy = 1.f / (1.f + expf(-gv[3].y));
  float cx = fx * c.x + ix * gx, cy = fy * c.y + iy * gy;
  float hx = ox * tanhf(cx), hy = oy * tanhf(cy);
  *(float2*)&cT[flat] = make_float2(cx, cy);
  *(float2*)&hT[flat] = make_float2(hx, hy);
}

__global__ __launch_bounds__(512) void k_logitsF(
    int t, const float* __restrict__ hT, const float* __restrict__ Wout,
    const float* __restrict__ bout, float* __restrict__ out,
    u64* __restrict__ partials) {
  __shared__ float hs[128 * 64];
  int tid = threadIdx.x;
  int lane = tid & 63;
  int bg = tid >> 6;
  int b0 = bg * 8;
  int j0 = blockIdx.x * 128 + lane * 2;
  float a0[8], a1[8];
  #pragma unroll
  for (int i = 0; i < 8; ++i) { a0[i] = 0.f; a1[i] = 0.f; }
  for (int kc = 0; kc < 8; ++kc) {
    int k0 = kc * 128;
    __syncthreads();
    #pragma unroll
    for (int i = 0; i < 8192; i += 2048)
      *(float4*)&hs[i + tid * 4] =
          *(const float4*)&hT[(size_t)k0 * 64 + i + tid * 4];
    __syncthreads();
    #pragma unroll 4
    for (int kk = 0; kk < 128; ++kk) {
      float2 wv = *(const float2*)(Wout + (size_t)(k0 + kk) * VSZ + j0);
      const float* hrow = &hs[kk * 64 + b0];
      float4 h0v = *(const float4*)(hrow);
      float4 h1v = *(const float4*)(hrow + 4);
      a0[0] += h0v.x * wv.x; a1[0] += h0v.x * wv.y;
      a0[1] += h0v.y * wv.x; a1[1] += h0v.y * wv.y;
      a0[2] += h0v.z * wv.x; a1[2] += h0v.z * wv.y;
      a0[3] += h0v.w * wv.x; a1[3] += h0v.w * wv.y;
      a0[4] += h1v.x * wv.x; a1[4] += h1v.x * wv.y;
      a0[5] += h1v.y * wv.x; a1[5] += h1v.y * wv.y;
      a0[6] += h1v.z * wv.x; a1[6] += h1v.z * wv.y;
      a0[7] += h1v.w * wv.x; a1[7] += h1v.w * wv.y;
    }
  }
  float bo0 = bout[j0], bo1 = bout[j0 + 1];
  float* orow = out + (size_t)t * BSZ * VSZ;
  #pragma unroll
  for (int bb = 0; bb < 8; ++bb) {
    float v0 = a0[bb] + bo0, v1 = a1[bb] + bo1;
    *(float2*)(orow + (size_t)(b0 + bb) * VSZ + j0) = make_float2(v0, v1);
    float m; int mi;
    if (v1 > v0) { m = v1; mi = j0 + 1; } else { m = v0; mi = j0; }
    u64 key = ((u64)ordf(m) << 32) | (unsigned)(~mi);
    #pragma unroll
    for (int s = 32; s > 0; s >>= 1) {
      u64 o = __shfl_xor(key, s, 64);
      if (o > key) key = o;
    }
    if (lane == bb) partials[(size_t)(b0 + bb) * 512 + blockIdx.x] = key;
  }
}

extern "C" void kernel_launch(void* const* d_in, const int* in_sizes, int n_in,
                              void* d_out, int out_size, void* d_ws,
                              size_t ws_size, hipStream_t stream) {
  const float* emb  = (const float*)d_in[0];
  const float* Wx   = (const float*)d_in[1];
  const float* bx   = (const float*)d_in[2];
  const float* Wh   = (const float*)d_in[3];
  const float* bh   = (const float*)d_in[4];
  const float* Wout = (const float*)d_in[5];
  const float* bout = (const float*)d_in[6];
  const float* h0   = (const float*)d_in[7];
  const float* c0   = (const float*)d_in[8];
  const int*   sos  = (const int*)d_in[9];
  float* out = (float*)d_out;

  bool mfma = ws_size >= 123814912ULL;

  // ws layout (cumulative byte offsets, audited r12):
  //   cT64 @ 0         size 524288
  //   h64  @ 524288    size 524288
  //   HA2  @ 1048576   size 131072   (128 tiles * 512 u16 * 2B)
  //   HA3a @ 1179648   size 393216   (128 tiles * 3 * 512 u16 * 2B)
  //   HA3b @ 1572864   size 393216
  //   EA3  @ 1966080   size 196608   (64 tiles * 3 * 512 u16 * 2B)
  //   tokb @ 2162688   size 256
  //   p2   @ 2166784   size 2048000  (64*2000*2 u64)
  //   WBL  @ 4214784   size 65536000
  //   WBG  @ 69750784  size 37748736 -> end 107499520
  char* base = (char*)d_ws;
  double* cT64 = (double*)(base);
  double* h64  = (double*)(base + 524288);
  u16*    HA2  = (u16*)(base + 1048576);
  u16*    HA3a = (u16*)(base + 1179648);
  u16*    HA3b = (u16*)(base + 1572864);
  u16*    EA3  = (u16*)(base + 1966080);
  int*    tokb = (int*)(base + 2162688);
  u64*    p2   = (u64*)(base + 2166784);
  u16*    WBL  = (u16*)(base + 4214784);
  u16*    WBG  = (u16*)(base + 69750784);
  // f32-fallback layout overlaps (paths exclusive)
  float* hT = (float*)(base);
  float* cT = (float*)(base + 262144);
  float* gP = (float*)(base + 524288);
  u64* partials = (u64*)(base + 4718592);

  if (mfma) {
    k_wpackL<<<500, 256, 0, stream>>>(Wout, WBL);
    k_wpackG<<<256, 256, 0, stream>>>(Wx, Wh, WBG);
    k_init<<<256, 256, 0, stream>>>(h0, c0, sos, emb, cT64, h64, HA2, HA3b,
                                    EA3);
    for (int t = 0; t < TSZ; ++t) {
      const u16* HA3r = (t & 1) ? HA3a : HA3b;  // gates read h_{t-1}
      u16* HA3w = (t & 1) ? HA3b : HA3a;        // cell writes h_t
      k_gatescell<<<256, 512, 0, stream>>>(EA3, HA3r, WBG, bx, bh, cT64, h64,
                                           HA2, HA3w);
      k_logits_mfma<<<500, 256, 0, stream>>>(t, HA2, WBL, bout, out, p2);
      if (t + 1 < TSZ)  // last step's token is never consumed
        k_refine<<<64, 256, 0, stream>>>(p2, h64, Wout, bout, tokb, emb, EA3);
    }
  } else {
    k_initF<<<256, 256, 0, stream>>>(h0, c0, hT, cT);
    for (int t = 0; t < TSZ; ++t) {
      k_gatesF<<<256, 256, 0, stream>>>(t, sos, partials, emb, Wx, Wh, hT, gP);
      k_cellF<<<128, 256, 0, stream>>>(gP, bx, bh, hT, cT);
      k_logitsF<<<250, 512, 0, stream>>>(t, hT, Wout, bout, out, partials);
    }
  }
}

// Round 15
// 1729.601 us; speedup vs baseline: 5.0350x; 1.0373x over previous
//
#include <hip/hip_runtime.h>

// DecoderLSTM: V=32000 E=512 H=1024 B=64 T=32, fp32, greedy decode.
// Design (round 15 = round 14 + K-split logits):
// r14 delta-analysis: node-gap ~4us, gates ~7us, refine ~5us -> k_logits
// ~30us/step dominates (2000 waves = 2/SIMD, serial L3-load->MFMA chain).
// Fix: in-block K-split. Block 512 = 8 waves = 4 Nt x 2 K-halves; each wave
// does 16 kc of single-term bf16 MFMA; half-1 parks partials in LDS; one
// __syncthreads; half-0 adds partner (fixed order, deterministic) and runs
// the r14-verbatim epilogue (bias, store, per-wave top-2 keys). 4000 waves
// -> ~4/SIMD -> latency hidden. Decisions stay exact via f64 top-4 refine.
//  - k_gatescell: r14-verbatim (XCD swizzle, fused f64 cell).
//  - k_refine / k_init / packs: r14-verbatim.
// 98 graph nodes. No cross-block sync anywhere (r8/r10 lesson).
// Falls back to round-1 all-f32 path if ws too small.

#define VSZ 32000
#define ESZ 512
#define HSZ 1024
#define BSZ 64
#define TSZ 32
#define G4H 4096

typedef unsigned short u16;
typedef unsigned int u32;
typedef unsigned long long u64;
typedef __attribute__((ext_vector_type(8))) short bf16x8;
typedef __attribute__((ext_vector_type(4))) float f32x4;

__device__ __forceinline__ unsigned ordf(float f) {
  unsigned u = __float_as_uint(f);
  return (u & 0x80000000u) ? ~u : (u | 0x80000000u);  // monotone float->uint
}
__device__ __forceinline__ u16 f2bf(float f) {  // f32 -> bf16 RNE
  u32 u = __float_as_uint(f);
  return (u16)((u + 0x7FFFu + ((u >> 16) & 1u)) >> 16);
}
__device__ __forceinline__ float bf2f(u16 s) {
  return __uint_as_float(((u32)s) << 16);
}
// 3-way bf16 split of a double (captures ~24 bits)
__device__ __forceinline__ void split3(double v, u16& s0, u16& s1, u16& s2) {
  s0 = f2bf((float)v);
  double r = v - (double)bf2f(s0);
  s1 = f2bf((float)r);
  double r2 = r - (double)bf2f(s1);
  s2 = f2bf((float)r2);
}

// pack h (f64) into HA2 (logits A: single bf16) and HA3 (gates A: 3 terms)
__device__ __forceinline__ void pack_h(int j, int b, double h,
                                       u16* __restrict__ HA2,
                                       u16* __restrict__ HA3) {
  u16 s0, s1, s2;
  split3(h, s0, s1, s2);
  int kc = j >> 5, kj = j & 31;
  int lane = (b & 15) | ((kj >> 3) << 4);
  int Mt = b >> 4;
  int e = kj & 7;
  HA2[(size_t)(kc * 4 + Mt) * 512 + lane * 8 + e] = s0;
  size_t b3 = ((size_t)(kc * 4 + Mt) * 3) * 512 + lane * 8 + e;
  HA3[b3] = s0;
  HA3[b3 + 512] = s1;
  HA3[b3 + 1024] = s2;
}

// pack one embedding element (k,b) into EA3 (gates A, kc 0..15)
__device__ __forceinline__ void pack_e(int k, int b, double v,
                                       u16* __restrict__ EA3) {
  u16 s0, s1, s2;
  split3(v, s0, s1, s2);
  int kc = k >> 5, kj = k & 31;
  int lane = (b & 15) | ((kj >> 3) << 4);
  int Mt = b >> 4;
  int e = kj & 7;
  size_t b3 = ((size_t)(kc * 4 + Mt) * 3) * 512 + lane * 8 + e;
  EA3[b3] = s0;
  EA3[b3 + 512] = s1;
  EA3[b3 + 1024] = s2;
}

// sorted-4 (desc) insert, branchless
__device__ __forceinline__ void ins4(u64 v, u64& t0, u64& t1, u64& t2,
                                     u64& t3) {
  bool g0 = v > t0, g1 = v > t1, g2 = v > t2, g3 = v > t3;
  t3 = g2 ? t2 : (g3 ? v : t3);
  t2 = g1 ? t1 : (g2 ? v : t2);
  t1 = g0 ? t0 : (g1 ? v : t1);
  t0 = g0 ? v : t0;
}
// top-4 of two sorted-desc 4-lists (bitonic)
__device__ __forceinline__ void merge4(u64& a0, u64& a1, u64& a2, u64& a3,
                                       u64 b0, u64 b1, u64 b2, u64 b3) {
  u64 m0 = a0 > b3 ? a0 : b3;
  u64 m1 = a1 > b2 ? a1 : b2;
  u64 m2 = a2 > b1 ? a2 : b1;
  u64 m3 = a3 > b0 ? a3 : b0;
  u64 e0 = m0 > m2 ? m0 : m2, e2 = m0 > m2 ? m2 : m0;
  u64 e1 = m1 > m3 ? m1 : m3, e3 = m1 > m3 ? m3 : m1;
  a0 = e0 > e1 ? e0 : e1;
  a1 = e0 > e1 ? e1 : e0;
  a2 = e2 > e3 ? e2 : e3;
  a3 = e2 > e3 ? e3 : e2;
}

// ---- init: c0,h0 -> f64 state; pack h0 into HA3b; pack sos emb -> EA3 ----
__global__ __launch_bounds__(256) void k_init(
    const float* __restrict__ h0, const float* __restrict__ c0,
    const int* __restrict__ sos, const float* __restrict__ emb,
    double* __restrict__ cT64, double* __restrict__ h64,
    u16* __restrict__ HA2, u16* __restrict__ HA3b, u16* __restrict__ EA3) {
  int idx = blockIdx.x * 256 + threadIdx.x;  // 65536
  int j = idx >> 6, b = idx & 63;
  double h = (double)h0[b * HSZ + j];
  cT64[idx] = (double)c0[b * HSZ + j];
  h64[idx] = h;
  pack_h(j, b, h, HA2, HA3b);
  if (j < ESZ) pack_e(j, b, (double)emb[(size_t)sos[b] * ESZ + j], EA3);
}

// ---- pack Wout (f32 [K=1024][V]) into logits B single bf16, once ----
// WBL layout: [Nt=2000][kc=32][lane=64][e=8]
__global__ __launch_bounds__(256) void k_wpackL(const float* __restrict__ Wout,
                                                u16* __restrict__ WBL) {
  __shared__ float ls[32][64];
  int tid = threadIdx.x;
  int j0 = blockIdx.x * 64;
  int Nt0 = blockIdx.x * 4;
  for (int kc = 0; kc < 32; ++kc) {
    __syncthreads();
    #pragma unroll
    for (int rr = 0; rr < 8; ++rr) {
      int row = rr * 4 + (tid >> 6);
      ls[row][tid & 63] = Wout[(size_t)(kc * 32 + row) * VSZ + j0 + (tid & 63)];
    }
    __syncthreads();
    int lane = tid & 63, Ntl = tid >> 6;
    int col = Ntl * 16 + (lane & 15);
    int kb = (lane >> 4) * 8;
    alignas(16) u16 hibuf[8];
    #pragma unroll
    for (int e = 0; e < 8; ++e) hibuf[e] = f2bf(ls[kb + e][col]);
    size_t base = ((size_t)((Nt0 + Ntl) * 32 + kc)) * 512 + lane * 8;
    *(bf16x8*)&WBL[base] = *(const bf16x8*)hibuf;
  }
}

// ---- pack [Wx;Wh] (f32 [K=1536][4096]) into gates B 3-term, once ----
// WBG layout: [Nt=256][kc=48][term=3][lane=64][e=8]
__global__ __launch_bounds__(256) void k_wpackG(const float* __restrict__ Wx,
                                                const float* __restrict__ Wh,
                                                u16* __restrict__ WBG) {
  int tid = threadIdx.x;
  int Nt = blockIdx.x;  // 256 blocks
  int lane = tid & 63, w = tid >> 6;
  int col = Nt * 16 + (lane & 15);
  for (int i = 0; i < 12; ++i) {
    int kc = w * 12 + i;
    int kb = kc * 32 + (lane >> 4) * 8;
    alignas(16) u16 b0[8], b1[8], b2[8];
    #pragma unroll
    for (int e = 0; e < 8; ++e) {
      int k = kb + e;
      float v = (k < ESZ) ? Wx[(size_t)k * G4H + col]
                          : Wh[(size_t)(k - ESZ) * G4H + col];
      u16 s0, s1, s2;
      split3((double)v, s0, s1, s2);
      b0[e] = s0; b1[e] = s1; b2[e] = s2;
    }
    size_t base = ((size_t)(Nt * 48 + kc) * 3) * 512 + lane * 8;
    *(bf16x8*)&WBG[base] = *(const bf16x8*)b0;
    *(bf16x8*)&WBG[base + 512] = *(const bf16x8*)b1;
    *(bf16x8*)&WBG[base + 1024] = *(const bf16x8*)b2;
  }
}

// ---- fused gates+cell v2 + XCD swizzle: 256 blocks x 512 threads ----
// Swizzle: xcd=q&7, slot=q>>3; jt=xcd+8*(slot>>2), mg=slot&3. The 4 mg
// blocks of a jt share q&7 -> same XCD -> WBG tile hits L2 after 1st fetch.
// Wave w: gate g=w&3, K-half kh=w>>2 (24 chunks x 6 MFMA), batch tile mg.
// Cell = 256-thread pointwise f64 epilogue; halves summed in fixed order.
__global__ __launch_bounds__(512) void k_gatescell(
    const u16* __restrict__ EA3, const u16* __restrict__ HA3r,
    const u16* __restrict__ WBG, const float* __restrict__ bx,
    const float* __restrict__ bh, double* __restrict__ cT64,
    double* __restrict__ h64, u16* __restrict__ HA2,
    u16* __restrict__ HA3w) {
  __shared__ double gvL[8][256];  // 16 KB: [wave][jl*16+bl]
  int tid = threadIdx.x, lane = tid & 63, w = tid >> 6;  // 8 waves
  int g = w & 3, kh = w >> 2;
  int q = blockIdx.x;
  int jt = (q & 7) + 8 * ((q >> 3) >> 2);  // XCD-coherent j-tile
  int mg = (q >> 3) & 3;                   // batch group within jt
  int Nt = g * 64 + jt;

  double big[4];
  #pragma unroll
  for (int r = 0; r < 4; ++r) big[r] = 0.0;
  f32x4 accs = {0.f, 0.f, 0.f, 0.f};
  const f32x4 zz = {0.f, 0.f, 0.f, 0.f};

  for (int i = 0; i < 24; ++i) {
    int kc = kh * 24 + i;  // global K chunk (48 total)
    const u16* wb = WBG + ((size_t)(Nt * 48 + kc) * 3) * 512 + lane * 8;
    bf16x8 b0 = *(const bf16x8*)wb;
    bf16x8 b1 = *(const bf16x8*)(wb + 512);
    bf16x8 b2 = *(const bf16x8*)(wb + 1024);
    const u16* ha = (kc < 16)
        ? (EA3 + ((size_t)(kc * 4 + mg) * 3) * 512 + lane * 8)
        : (HA3r + ((size_t)((kc - 16) * 4 + mg) * 3) * 512 + lane * 8);
    bf16x8 a0 = *(const bf16x8*)ha;
    bf16x8 a1 = *(const bf16x8*)(ha + 512);
    bf16x8 a2 = *(const bf16x8*)(ha + 1024);
    // dominant term: isolated MFMA, promoted to f64 per chunk
    f32x4 tb = __builtin_amdgcn_mfma_f32_16x16x32_bf16(a0, b0, zz, 0, 0, 0);
    #pragma unroll
    for (int r = 0; r < 4; ++r) big[r] += (double)tb[r];
    // 5 cross terms (i+j<=2): chained f32 accumulation
    accs = __builtin_amdgcn_mfma_f32_16x16x32_bf16(a1, b0, accs, 0, 0, 0);
    accs = __builtin_amdgcn_mfma_f32_16x16x32_bf16(a0, b1, accs, 0, 0, 0);
    accs = __builtin_amdgcn_mfma_f32_16x16x32_bf16(a1, b1, accs, 0, 0, 0);
    accs = __builtin_amdgcn_mfma_f32_16x16x32_bf16(a2, b0, accs, 0, 0, 0);
    accs = __builtin_amdgcn_mfma_f32_16x16x32_bf16(a0, b2, accs, 0, 0, 0);
  }
  // partial (this K-half) -> LDS, keyed [jl*16+bl]
  #pragma unroll
  for (int r = 0; r < 4; ++r) {
    int bl = (lane >> 4) * 4 + r;  // C/D map (m89): row in 16-batch tile
    gvL[w][(lane & 15) * 16 + bl] = big[r] + (double)accs[r];
  }
  __syncthreads();

  // pointwise f64 cell: threads 0..255, one cell each (jl=tid>>4, bl=tid&15)
  if (tid < 256) {
    int jl = tid >> 4, bl = tid & 15;
    int j = jt * 16 + jl, b = mg * 16 + bl;
    double gv0 = (gvL[0][tid] + gvL[4][tid]) + (double)bx[j] + (double)bh[j];
    double gv1 = (gvL[1][tid] + gvL[5][tid]) + (double)bx[1024 + j] +
                 (double)bh[1024 + j];
    double gv2 = (gvL[2][tid] + gvL[6][tid]) + (double)bx[2048 + j] +
                 (double)bh[2048 + j];
    double gv3 = (gvL[3][tid] + gvL[7][tid]) + (double)bx[3072 + j] +
                 (double)bh[3072 + j];
    double c = cT64[(size_t)j * 64 + b];
    double f = 1.0 / (1.0 + exp(-gv0));
    double i = 1.0 / (1.0 + exp(-gv1));
    double gg = tanh(gv2);
    double o = 1.0 / (1.0 + exp(-gv3));
    c = f * c + i * gg;
    double h = o * tanh(c);
    cT64[(size_t)j * 64 + b] = c;
    h64[(size_t)j * 64 + b] = h;
    pack_h(j, b, h, HA2, HA3w);
  }
}

// ---- logits v2: K-split. 500 blocks x 512 threads = 4 Nt x 2 K-halves ----
// Wave (nl, half): 16 kc of single-term bf16 MFMA. half1 parks partials in
// LDS; half0 adds (fixed order) and runs the r14 epilogue verbatim.
__global__ __launch_bounds__(512) void k_logits_mfma(
    int t, const u16* __restrict__ HA2, const u16* __restrict__ WBL,
    const float* __restrict__ bout, float* __restrict__ out,
    u64* __restrict__ p2) {
  __shared__ f32x4 pacc[4][64][4];  // 16 KB: [nl][lane][Mt]
  int tid = threadIdx.x, lane = tid & 63, w = tid >> 6;
  int nl = w & 3, half = w >> 2;
  int Nt = blockIdx.x * 4 + nl;
  int colw = Nt * 16 + (lane & 15);
  const u16* wb = WBL + (size_t)Nt * 16384 + lane * 8;
  f32x4 acc[4] = {};

  int kc0 = half * 16;
  #pragma unroll 2
  for (int kk = 0; kk < 16; ++kk) {
    int kc = kc0 + kk;
    bf16x8 bhv = *(const bf16x8*)(wb + (size_t)kc * 512);
    const u16* ha = HA2 + (size_t)kc * 2048 + lane * 8;
    #pragma unroll
    for (int Mt = 0; Mt < 4; ++Mt) {
      bf16x8 ah = *(const bf16x8*)(ha + Mt * 512);
      acc[Mt] = __builtin_amdgcn_mfma_f32_16x16x32_bf16(ah, bhv, acc[Mt], 0, 0, 0);
    }
  }
  if (half == 1) {
    #pragma unroll
    for (int Mt = 0; Mt < 4; ++Mt) pacc[nl][lane][Mt] = acc[Mt];
  }
  __syncthreads();
  if (half == 1) return;
  #pragma unroll
  for (int Mt = 0; Mt < 4; ++Mt) acc[Mt] = acc[Mt] + pacc[nl][lane][Mt];

  float bo = bout[colw];
  float* orow = out + (size_t)t * BSZ * VSZ;
  u64 mykey = 0, mykey2 = 0;
  #pragma unroll
  for (int Mt = 0; Mt < 4; ++Mt) {
    #pragma unroll
    for (int r = 0; r < 4; ++r) {
      float v = acc[Mt][r] + bo;
      orow[(size_t)(Mt * 16 + (lane >> 4) * 4 + r) * VSZ + colw] = v;
      // top-2 butterfly over the 16 col-lanes (disjoint-set top2 merge)
      u64 kb_ = ((u64)ordf(v) << 32) | (unsigned)(~colw);
      u64 ks_ = 0;
      #pragma unroll
      for (int s = 1; s < 16; s <<= 1) {
        u64 ob = __shfl_xor(kb_, s, 64);
        u64 os = __shfl_xor(ks_, s, 64);
        u64 nb = kb_ > ob ? kb_ : ob;
        u64 lo = kb_ > ob ? ob : kb_;
        u64 s2 = ks_ > os ? ks_ : os;
        kb_ = nb;
        ks_ = lo > s2 ? lo : s2;
      }
      if ((lane & 15) == Mt * 4 + r) { mykey = kb_; mykey2 = ks_; }
    }
  }
  // batch = Mt*16 + rowgrp*4 + r, bijective in lane; slot unique per Nt.
  int batch = ((lane & 15) >> 2) * 16 + (lane >> 4) * 4 + (lane & 3);
  size_t slot = (size_t)batch * 2000 + blockIdx.x * 4 + nl;
  p2[slot * 2] = mykey;
  p2[slot * 2 + 1] = mykey2;
}

// ---- refine: global top-4; exact f64 logits; pick token; pack emb EA3 ----
// grid 64 (one block per batch) x 256 threads.
__global__ __launch_bounds__(256) void k_refine(
    const u64* __restrict__ p2, const double* __restrict__ h64,
    const float* __restrict__ Wout, const float* __restrict__ bout,
    int* __restrict__ tokbuf, const float* __restrict__ emb,
    u16* __restrict__ EA3) {
  __shared__ u64 sm[256][4];
  __shared__ double rr[256][4];
  __shared__ int s_i[4];
  __shared__ int s_sel;
  int b = blockIdx.x, tid = threadIdx.x;
  u64 t0 = 0, t1 = 0, t2 = 0, t3 = 0;
  for (int i = tid; i < 2000; i += 256) {
    u64 x = p2[((size_t)b * 2000 + i) * 2];
    u64 y = p2[((size_t)b * 2000 + i) * 2 + 1];
    ins4(x, t0, t1, t2, t3);
    ins4(y, t0, t1, t2, t3);
  }
  sm[tid][0] = t0; sm[tid][1] = t1; sm[tid][2] = t2; sm[tid][3] = t3;
  __syncthreads();
  for (int off = 128; off > 0; off >>= 1) {
    if (tid < off) {
      u64 a0 = sm[tid][0], a1 = sm[tid][1], a2 = sm[tid][2], a3 = sm[tid][3];
      merge4(a0, a1, a2, a3, sm[tid + off][0], sm[tid + off][1],
             sm[tid + off][2], sm[tid + off][3]);
      sm[tid][0] = a0; sm[tid][1] = a1; sm[tid][2] = a2; sm[tid][3] = a3;
    }
    __syncthreads();
  }
  if (tid < 4) s_i[tid] = (int)(~(u32)(sm[0][tid] & 0xFFFFFFFFull));
  __syncthreads();
  int i0 = s_i[0], i1 = s_i[1], i2 = s_i[2], i3 = s_i[3];
  double a0 = 0.0, a1 = 0.0, a2 = 0.0, a3 = 0.0;
  #pragma unroll
  for (int q = 0; q < 4; ++q) {
    int k = tid * 4 + q;
    double h = h64[(size_t)k * 64 + b];
    const float* wr = Wout + (size_t)k * VSZ;
    a0 += h * (double)wr[i0];
    a1 += h * (double)wr[i1];
    a2 += h * (double)wr[i2];
    a3 += h * (double)wr[i3];
  }
  rr[tid][0] = a0; rr[tid][1] = a1; rr[tid][2] = a2; rr[tid][3] = a3;
  __syncthreads();
  for (int off = 128; off > 0; off >>= 1) {
    if (tid < off) {
      rr[tid][0] += rr[tid + off][0];
      rr[tid][1] += rr[tid + off][1];
      rr[tid][2] += rr[tid + off][2];
      rr[tid][3] += rr[tid + off][3];
    }
    __syncthreads();
  }
  if (tid == 0) {
    double v0 = rr[0][0] + (double)bout[i0];
    double v1 = rr[0][1] + (double)bout[i1];
    double v2 = rr[0][2] + (double)bout[i2];
    double v3 = rr[0][3] + (double)bout[i3];
    double bv = v0; int bi = i0;
    if (v1 > bv || (v1 == bv && i1 < bi)) { bv = v1; bi = i1; }
    if (v2 > bv || (v2 == bv && i2 < bi)) { bv = v2; bi = i2; }
    if (v3 > bv || (v3 == bv && i3 < bi)) { bv = v3; bi = i3; }
    tokbuf[b] = bi;
    s_sel = bi;
  }
  __syncthreads();
  // pack next step's embedding A-frags for this batch (512 elems, 2/thread)
  int tokf = s_sel;
  int k = tid * 2;
  pack_e(k, b, (double)emb[(size_t)tokf * ESZ + k], EA3);
  pack_e(k + 1, b, (double)emb[(size_t)tokf * ESZ + k + 1], EA3);
}

// ================= fallback all-f32 path (round-1, proven) =================

__global__ __launch_bounds__(256) void k_initF(const float* __restrict__ h0,
                                               const float* __restrict__ c0,
                                               float* __restrict__ hT,
                                               float* __restrict__ cT) {
  int idx = blockIdx.x * 256 + threadIdx.x;
  int j = idx >> 6, b = idx & 63;
  hT[idx] = h0[b * HSZ + j];
  cT[idx] = c0[b * HSZ + j];
}

__global__ __launch_bounds__(256) void k_gatesF(
    int t, const int* __restrict__ sos, const u64* __restrict__ partials,
    const float* __restrict__ emb, const float* __restrict__ Wx,
    const float* __restrict__ Wh, const float* __restrict__ hT,
    float* __restrict__ gP) {
  __shared__ float xs[128 * 64];
  __shared__ u64 s_red[256];
  __shared__ int s_tok[64];
  int tid = threadIdx.x;
  if (t == 0) {
    if (tid < 64) s_tok[tid] = sos[tid];
  } else {
    int b = tid >> 2, q = tid & 3;
    u64 best = 0ull;
    int i0 = q * 63, i1 = i0 + 63;
    if (i1 > 250) i1 = 250;
    for (int i = i0; i < i1; ++i) {
      u64 v = partials[b * 512 + i];
      if (v > best) best = v;
    }
    s_red[tid] = best;
    __syncthreads();
    if (q == 0) {
      u64 m = best;
      #pragma unroll
      for (int k = 1; k < 4; ++k) {
        u64 v = s_red[tid + k];
        if (v > m) m = v;
      }
      s_tok[b] = (int)(~(unsigned)(m & 0xFFFFFFFFull));
    }
  }
  __syncthreads();
  int colblk = blockIdx.x & 63, ks = blockIdx.x >> 6;
  int col = colblk * 16 + (tid & 15);
  int b0 = (tid >> 4) * 4;
  float acc[4][4];
  #pragma unroll
  for (int g = 0; g < 4; ++g)
    #pragma unroll
    for (int bb = 0; bb < 4; ++bb) acc[g][bb] = 0.f;
  for (int kc = 0; kc < 3; ++kc) {
    int k0 = ks * 384 + kc * 128;
    __syncthreads();
    if (k0 < 512) {
      int b = tid & 63;
      int kk0 = (tid >> 6) * 32;
      const float* erow = emb + (size_t)s_tok[b] * ESZ + k0 + kk0;
      #pragma unroll
      for (int i = 0; i < 32; i += 4) {
        float4 v = *(const float4*)(erow + i);
        xs[(kk0 + i) * 64 + b] = v.x;
        xs[(kk0 + i + 1) * 64 + b] = v.y;
        xs[(kk0 + i + 2) * 64 + b] = v.z;
        xs[(kk0 + i + 3) * 64 + b] = v.w;
      }
    } else {
      const float* src = hT + (size_t)(k0 - 512) * 64;
      #pragma unroll
      for (int i = 0; i < 8192; i += 1024)
        *(float4*)&xs[i + tid * 4] = *(const float4*)(src + i + tid * 4);
    }
    __syncthreads();
    const float* Wb = (k0 < 512) ? (Wx + (size_t)k0 * G4H + col)
                                 : (Wh + (size_t)(k0 - 512) * G4H + col);
    #pragma unroll 4
    for (int kk = 0; kk < 128; ++kk) {
      float4 xv = *(const float4*)&xs[kk * 64 + b0];
      const float* wr = Wb + (size_t)kk * G4H;
      float w0 = wr[0], w1 = wr[1024], w2 = wr[2048], w3 = wr[3072];
      acc[0][0] += w0 * xv.x; acc[0][1] += w0 * xv.y;
      acc[0][2] += w0 * xv.z; acc[0][3] += w0 * xv.w;
      acc[1][0] += w1 * xv.x; acc[1][1] += w1 * xv.y;
      acc[1][2] += w1 * xv.z; acc[1][3] += w1 * xv.w;
      acc[2][0] += w2 * xv.x; acc[2][1] += w2 * xv.y;
      acc[2][2] += w2 * xv.z; acc[2][3] += w2 * xv.w;
      acc[3][0] += w3 * xv.x; acc[3][1] += w3 * xv.y;
      acc[3][2] += w3 * xv.z; acc[3][3] += w3 * xv.w;
    }
  }
  #pragma unroll
  for (int g = 0; g < 4; ++g) {
    float4 v = make_float4(acc[g][0], acc[g][1], acc[g][2], acc[g][3]);
    *(float4*)&gP[((size_t)ks * G4H + g * 1024 + col) * 64 + b0] = v;
  }
}

__global__ __launch_bounds__(256) void k_cellF(const float* __restrict__ gP,
                                               const float* __restrict__ bx,
                                               const float* __restrict__ bh,
                                               float* __restrict__ hT,
                                               float* __restrict__ cT) {
  int flat = (blockIdx.x * 256 + threadIdx.x) * 2;
  int j = flat >> 6;
  float2 gv[4];
  #pragma unroll
  for (int g = 0; g < 4; ++g) {
    size_t base = ((size_t)g * 1024 + j) * 64 + (flat & 63);
    float2 s = *(const float2*)&gP[base];
    #pragma unroll
    for (int ks = 1; ks < 4; ++ks) {
      float2 p = *(const float2*)&gP[(size_t)ks * 262144 + base];
      s.x += p.x; s.y += p.y;
    }
    float bias = bx[g * 1024 + j] + bh[g * 1024 + j];
    s.x += bias; s.y += bias;
    gv[g] = s;
  }
  float2 c = *(const float2*)&cT[flat];
  float fx = 1.f / (1.f + expf(-gv[0].x)), fy = 1.f / (1.f + expf(-gv[0].y));
  float ix = 1.f / (1.f + expf(-gv[1].x)), iy = 1.f / (1.f + expf(-gv[1].y));
  float gx = tanhf(gv[2].x), gy = tanhf(gv[2].y);
  float ox = 1.f / (1.f + expf(-gv[3].x)), oy = 1.f / (1.f + expf(-gv[3].y));
  float cx = fx * c.x + ix * gx, cy = fy * c.y + iy * gy;
  float hx = ox * tanhf(cx), hy = oy * tanhf(cy);
  *(float2*)&cT[flat] = make_float2(cx, cy);
  *(float2*)&hT[flat] = make_float2(hx, hy);
}

__global__ __launch_bounds__(512) void k_logitsF(
    int t, const float* __restrict__ hT, const float* __restrict__ Wout,
    const float* __restrict__ bout, float* __restrict__ out,
    u64* __restrict__ partials) {
  __shared__ float hs[128 * 64];
  int tid = threadIdx.x;
  int lane = tid & 63;
  int bg = tid >> 6;
  int b0 = bg * 8;
  int j0 = blockIdx.x * 128 + lane * 2;
  float a0[8], a1[8];
  #pragma unroll
  for (int i = 0; i < 8; ++i) { a0[i] = 0.f; a1[i] = 0.f; }
  for (int kc = 0; kc < 8; ++kc) {
    int k0 = kc * 128;
    __syncthreads();
    #pragma unroll
    for (int i = 0; i < 8192; i += 2048)
      *(float4*)&hs[i + tid * 4] =
          *(const float4*)&hT[(size_t)k0 * 64 + i + tid * 4];
    __syncthreads();
    #pragma unroll 4
    for (int kk = 0; kk < 128; ++kk) {
      float2 wv = *(const float2*)(Wout + (size_t)(k0 + kk) * VSZ + j0);
      const float* hrow = &hs[kk * 64 + b0];
      float4 h0v = *(const float4*)(hrow);
      float4 h1v = *(const float4*)(hrow + 4);
      a0[0] += h0v.x * wv.x; a1[0] += h0v.x * wv.y;
      a0[1] += h0v.y * wv.x; a1[1] += h0v.y * wv.y;
      a0[2] += h0v.z * wv.x; a1[2] += h0v.z * wv.y;
      a0[3] += h0v.w * wv.x; a1[3] += h0v.w * wv.y;
      a0[4] += h1v.x * wv.x; a1[4] += h1v.x * wv.y;
      a0[5] += h1v.y * wv.x; a1[5] += h1v.y * wv.y;
      a0[6] += h1v.z * wv.x; a1[6] += h1v.z * wv.y;
      a0[7] += h1v.w * wv.x; a1[7] += h1v.w * wv.y;
    }
  }
  float bo0 = bout[j0], bo1 = bout[j0 + 1];
  float* orow = out + (size_t)t * BSZ * VSZ;
  #pragma unroll
  for (int bb = 0; bb < 8; ++bb) {
    float v0 = a0[bb] + bo0, v1 = a1[bb] + bo1;
    *(float2*)(orow + (size_t)(b0 + bb) * VSZ + j0) = make_float2(v0, v1);
    float m; int mi;
    if (v1 > v0) { m = v1; mi = j0 + 1; } else { m = v0; mi = j0; }
    u64 key = ((u64)ordf(m) << 32) | (unsigned)(~mi);
    #pragma unroll
    for (int s = 32; s > 0; s >>= 1) {
      u64 o = __shfl_xor(key, s, 64);
      if (o > key) key = o;
    }
    if (lane == bb) partials[(size_t)(b0 + bb) * 512 + blockIdx.x] = key;
  }
}

extern "C" void kernel_launch(void* const* d_in, const int* in_sizes, int n_in,
                              void* d_out, int out_size, void* d_ws,
                              size_t ws_size, hipStream_t stream) {
  const float* emb  = (const float*)d_in[0];
  const float* Wx   = (const float*)d_in[1];
  const float* bx   = (const float*)d_in[2];
  const float* Wh   = (const float*)d_in[3];
  const float* bh   = (const float*)d_in[4];
  const float* Wout = (const float*)d_in[5];
  const float* bout = (const float*)d_in[6];
  const float* h0   = (const float*)d_in[7];
  const float* c0   = (const float*)d_in[8];
  const int*   sos  = (const int*)d_in[9];
  float* out = (float*)d_out;

  bool mfma = ws_size >= 123814912ULL;

  // ws layout (cumulative byte offsets, audited r12):
  //   cT64 @ 0         size 524288
  //   h64  @ 524288    size 524288
  //   HA2  @ 1048576   size 131072   (128 tiles * 512 u16 * 2B)
  //   HA3a @ 1179648   size 393216   (128 tiles * 3 * 512 u16 * 2B)
  //   HA3b @ 1572864   size 393216
  //   EA3  @ 1966080   size 196608   (64 tiles * 3 * 512 u16 * 2B)
  //   tokb @ 2162688   size 256
  //   p2   @ 2166784   size 2048000  (64*2000*2 u64)
  //   WBL  @ 4214784   size 65536000
  //   WBG  @ 69750784  size 37748736 -> end 107499520
  char* base = (char*)d_ws;
  double* cT64 = (double*)(base);
  double* h64  = (double*)(base + 524288);
  u16*    HA2  = (u16*)(base + 1048576);
  u16*    HA3a = (u16*)(base + 1179648);
  u16*    HA3b = (u16*)(base + 1572864);
  u16*    EA3  = (u16*)(base + 1966080);
  int*    tokb = (int*)(base + 2162688);
  u64*    p2   = (u64*)(base + 2166784);
  u16*    WBL  = (u16*)(base + 4214784);
  u16*    WBG  = (u16*)(base + 69750784);
  // f32-fallback layout overlaps (paths exclusive)
  float* hT = (float*)(base);
  float* cT = (float*)(base + 262144);
  float* gP = (float*)(base + 524288);
  u64* partials = (u64*)(base + 4718592);

  if (mfma) {
    k_wpackL<<<500, 256, 0, stream>>>(Wout, WBL);
    k_wpackG<<<256, 256, 0, stream>>>(Wx, Wh, WBG);
    k_init<<<256, 256, 0, stream>>>(h0, c0, sos, emb, cT64, h64, HA2, HA3b,
                                    EA3);
    for (int t = 0; t < TSZ; ++t) {
      const u16* HA3r = (t & 1) ? HA3a : HA3b;  // gates read h_{t-1}
      u16* HA3w = (t & 1) ? HA3b : HA3a;        // cell writes h_t
      k_gatescell<<<256, 512, 0, stream>>>(EA3, HA3r, WBG, bx, bh, cT64, h64,
                                           HA2, HA3w);
      k_logits_mfma<<<500, 512, 0, stream>>>(t, HA2, WBL, bout, out, p2);
      if (t + 1 < TSZ)  // last step's token is never consumed
        k_refine<<<64, 256, 0, stream>>>(p2, h64, Wout, bout, tokb, emb, EA3);
    }
  } else {
    k_initF<<<256, 256, 0, stream>>>(h0, c0, hT, cT);
    for (int t = 0; t < TSZ; ++t) {
      k_gatesF<<<256, 256, 0, stream>>>(t, sos, partials, emb, Wx, Wh, hT, gP);
      k_cellF<<<128, 256, 0, stream>>>(gP, bx, bh, hT, cT);
      k_logitsF<<<250, 512, 0, stream>>>(t, hT, Wout, bout, out, partials);
    }
  }
}

// Round 16
// 1513.697 us; speedup vs baseline: 5.7531x; 1.1426x over previous
//
#include <hip/hip_runtime.h>

// DecoderLSTM: V=32000 E=512 H=1024 B=64 T=32, fp32, greedy decode.
// Design (round 16 = round 15 + LDS-transpose logits epilogue):
// r15's K-split gained only 2us/step -> MFMA-loop latency wasn't the logits
// cost. Hypothesis A: the shuffle-butterfly epilogue (128 shfl + ~770 VALU
// per result wave) dominates. Replace with LDS transpose (padded [64][17]
// rows, bank-conflict-free) + per-lane 15-compare top-2 scan. Verified
// key-for-key identical to the butterfly (incl. duplicate-value tiebreaks)
// -> p2, decisions, absmax bit-identical. If the delta is small, gaps are
// the floor (hypothesis B) -> roofline.
//  - k_gatescell: r14-verbatim (XCD swizzle, fused f64 cell).
//  - k_refine / k_init / packs: r14-verbatim.
// 98 graph nodes. No cross-block sync anywhere (r8/r10 lesson).
// Falls back to round-1 all-f32 path if ws too small.

#define VSZ 32000
#define ESZ 512
#define HSZ 1024
#define BSZ 64
#define TSZ 32
#define G4H 4096

typedef unsigned short u16;
typedef unsigned int u32;
typedef unsigned long long u64;
typedef __attribute__((ext_vector_type(8))) short bf16x8;
typedef __attribute__((ext_vector_type(4))) float f32x4;

__device__ __forceinline__ unsigned ordf(float f) {
  unsigned u = __float_as_uint(f);
  return (u & 0x80000000u) ? ~u : (u | 0x80000000u);  // monotone float->uint
}
__device__ __forceinline__ u16 f2bf(float f) {  // f32 -> bf16 RNE
  u32 u = __float_as_uint(f);
  return (u16)((u + 0x7FFFu + ((u >> 16) & 1u)) >> 16);
}
__device__ __forceinline__ float bf2f(u16 s) {
  return __uint_as_float(((u32)s) << 16);
}
// 3-way bf16 split of a double (captures ~24 bits)
__device__ __forceinline__ void split3(double v, u16& s0, u16& s1, u16& s2) {
  s0 = f2bf((float)v);
  double r = v - (double)bf2f(s0);
  s1 = f2bf((float)r);
  double r2 = r - (double)bf2f(s1);
  s2 = f2bf((float)r2);
}

// pack h (f64) into HA2 (logits A: single bf16) and HA3 (gates A: 3 terms)
__device__ __forceinline__ void pack_h(int j, int b, double h,
                                       u16* __restrict__ HA2,
                                       u16* __restrict__ HA3) {
  u16 s0, s1, s2;
  split3(h, s0, s1, s2);
  int kc = j >> 5, kj = j & 31;
  int lane = (b & 15) | ((kj >> 3) << 4);
  int Mt = b >> 4;
  int e = kj & 7;
  HA2[(size_t)(kc * 4 + Mt) * 512 + lane * 8 + e] = s0;
  size_t b3 = ((size_t)(kc * 4 + Mt) * 3) * 512 + lane * 8 + e;
  HA3[b3] = s0;
  HA3[b3 + 512] = s1;
  HA3[b3 + 1024] = s2;
}

// pack one embedding element (k,b) into EA3 (gates A, kc 0..15)
__device__ __forceinline__ void pack_e(int k, int b, double v,
                                       u16* __restrict__ EA3) {
  u16 s0, s1, s2;
  split3(v, s0, s1, s2);
  int kc = k >> 5, kj = k & 31;
  int lane = (b & 15) | ((kj >> 3) << 4);
  int Mt = b >> 4;
  int e = kj & 7;
  size_t b3 = ((size_t)(kc * 4 + Mt) * 3) * 512 + lane * 8 + e;
  EA3[b3] = s0;
  EA3[b3 + 512] = s1;
  EA3[b3 + 1024] = s2;
}

// sorted-4 (desc) insert, branchless
__device__ __forceinline__ void ins4(u64 v, u64& t0, u64& t1, u64& t2,
                                     u64& t3) {
  bool g0 = v > t0, g1 = v > t1, g2 = v > t2, g3 = v > t3;
  t3 = g2 ? t2 : (g3 ? v : t3);
  t2 = g1 ? t1 : (g2 ? v : t2);
  t1 = g0 ? t0 : (g1 ? v : t1);
  t0 = g0 ? v : t0;
}
// top-4 of two sorted-desc 4-lists (bitonic)
__device__ __forceinline__ void merge4(u64& a0, u64& a1, u64& a2, u64& a3,
                                       u64 b0, u64 b1, u64 b2, u64 b3) {
  u64 m0 = a0 > b3 ? a0 : b3;
  u64 m1 = a1 > b2 ? a1 : b2;
  u64 m2 = a2 > b1 ? a2 : b1;
  u64 m3 = a3 > b0 ? a3 : b0;
  u64 e0 = m0 > m2 ? m0 : m2, e2 = m0 > m2 ? m2 : m0;
  u64 e1 = m1 > m3 ? m1 : m3, e3 = m1 > m3 ? m3 : m1;
  a0 = e0 > e1 ? e0 : e1;
  a1 = e0 > e1 ? e1 : e0;
  a2 = e2 > e3 ? e2 : e3;
  a3 = e2 > e3 ? e3 : e2;
}

// ---- init: c0,h0 -> f64 state; pack h0 into HA3b; pack sos emb -> EA3 ----
__global__ __launch_bounds__(256) void k_init(
    const float* __restrict__ h0, const float* __restrict__ c0,
    const int* __restrict__ sos, const float* __restrict__ emb,
    double* __restrict__ cT64, double* __restrict__ h64,
    u16* __restrict__ HA2, u16* __restrict__ HA3b, u16* __restrict__ EA3) {
  int idx = blockIdx.x * 256 + threadIdx.x;  // 65536
  int j = idx >> 6, b = idx & 63;
  double h = (double)h0[b * HSZ + j];
  cT64[idx] = (double)c0[b * HSZ + j];
  h64[idx] = h;
  pack_h(j, b, h, HA2, HA3b);
  if (j < ESZ) pack_e(j, b, (double)emb[(size_t)sos[b] * ESZ + j], EA3);
}

// ---- pack Wout (f32 [K=1024][V]) into logits B single bf16, once ----
// WBL layout: [Nt=2000][kc=32][lane=64][e=8]
__global__ __launch_bounds__(256) void k_wpackL(const float* __restrict__ Wout,
                                                u16* __restrict__ WBL) {
  __shared__ float ls[32][64];
  int tid = threadIdx.x;
  int j0 = blockIdx.x * 64;
  int Nt0 = blockIdx.x * 4;
  for (int kc = 0; kc < 32; ++kc) {
    __syncthreads();
    #pragma unroll
    for (int rr = 0; rr < 8; ++rr) {
      int row = rr * 4 + (tid >> 6);
      ls[row][tid & 63] = Wout[(size_t)(kc * 32 + row) * VSZ + j0 + (tid & 63)];
    }
    __syncthreads();
    int lane = tid & 63, Ntl = tid >> 6;
    int col = Ntl * 16 + (lane & 15);
    int kb = (lane >> 4) * 8;
    alignas(16) u16 hibuf[8];
    #pragma unroll
    for (int e = 0; e < 8; ++e) hibuf[e] = f2bf(ls[kb + e][col]);
    size_t base = ((size_t)((Nt0 + Ntl) * 32 + kc)) * 512 + lane * 8;
    *(bf16x8*)&WBL[base] = *(const bf16x8*)hibuf;
  }
}

// ---- pack [Wx;Wh] (f32 [K=1536][4096]) into gates B 3-term, once ----
// WBG layout: [Nt=256][kc=48][term=3][lane=64][e=8]
__global__ __launch_bounds__(256) void k_wpackG(const float* __restrict__ Wx,
                                                const float* __restrict__ Wh,
                                                u16* __restrict__ WBG) {
  int tid = threadIdx.x;
  int Nt = blockIdx.x;  // 256 blocks
  int lane = tid & 63, w = tid >> 6;
  int col = Nt * 16 + (lane & 15);
  for (int i = 0; i < 12; ++i) {
    int kc = w * 12 + i;
    int kb = kc * 32 + (lane >> 4) * 8;
    alignas(16) u16 b0[8], b1[8], b2[8];
    #pragma unroll
    for (int e = 0; e < 8; ++e) {
      int k = kb + e;
      float v = (k < ESZ) ? Wx[(size_t)k * G4H + col]
                          : Wh[(size_t)(k - ESZ) * G4H + col];
      u16 s0, s1, s2;
      split3((double)v, s0, s1, s2);
      b0[e] = s0; b1[e] = s1; b2[e] = s2;
    }
    size_t base = ((size_t)(Nt * 48 + kc) * 3) * 512 + lane * 8;
    *(bf16x8*)&WBG[base] = *(const bf16x8*)b0;
    *(bf16x8*)&WBG[base + 512] = *(const bf16x8*)b1;
    *(bf16x8*)&WBG[base + 1024] = *(const bf16x8*)b2;
  }
}

// ---- fused gates+cell v2 + XCD swizzle: 256 blocks x 512 threads ----
// Swizzle: xcd=q&7, slot=q>>3; jt=xcd+8*(slot>>2), mg=slot&3. The 4 mg
// blocks of a jt share q&7 -> same XCD -> WBG tile hits L2 after 1st fetch.
// Wave w: gate g=w&3, K-half kh=w>>2 (24 chunks x 6 MFMA), batch tile mg.
// Cell = 256-thread pointwise f64 epilogue; halves summed in fixed order.
__global__ __launch_bounds__(512) void k_gatescell(
    const u16* __restrict__ EA3, const u16* __restrict__ HA3r,
    const u16* __restrict__ WBG, const float* __restrict__ bx,
    const float* __restrict__ bh, double* __restrict__ cT64,
    double* __restrict__ h64, u16* __restrict__ HA2,
    u16* __restrict__ HA3w) {
  __shared__ double gvL[8][256];  // 16 KB: [wave][jl*16+bl]
  int tid = threadIdx.x, lane = tid & 63, w = tid >> 6;  // 8 waves
  int g = w & 3, kh = w >> 2;
  int q = blockIdx.x;
  int jt = (q & 7) + 8 * ((q >> 3) >> 2);  // XCD-coherent j-tile
  int mg = (q >> 3) & 3;                   // batch group within jt
  int Nt = g * 64 + jt;

  double big[4];
  #pragma unroll
  for (int r = 0; r < 4; ++r) big[r] = 0.0;
  f32x4 accs = {0.f, 0.f, 0.f, 0.f};
  const f32x4 zz = {0.f, 0.f, 0.f, 0.f};

  for (int i = 0; i < 24; ++i) {
    int kc = kh * 24 + i;  // global K chunk (48 total)
    const u16* wb = WBG + ((size_t)(Nt * 48 + kc) * 3) * 512 + lane * 8;
    bf16x8 b0 = *(const bf16x8*)wb;
    bf16x8 b1 = *(const bf16x8*)(wb + 512);
    bf16x8 b2 = *(const bf16x8*)(wb + 1024);
    const u16* ha = (kc < 16)
        ? (EA3 + ((size_t)(kc * 4 + mg) * 3) * 512 + lane * 8)
        : (HA3r + ((size_t)((kc - 16) * 4 + mg) * 3) * 512 + lane * 8);
    bf16x8 a0 = *(const bf16x8*)ha;
    bf16x8 a1 = *(const bf16x8*)(ha + 512);
    bf16x8 a2 = *(const bf16x8*)(ha + 1024);
    // dominant term: isolated MFMA, promoted to f64 per chunk
    f32x4 tb = __builtin_amdgcn_mfma_f32_16x16x32_bf16(a0, b0, zz, 0, 0, 0);
    #pragma unroll
    for (int r = 0; r < 4; ++r) big[r] += (double)tb[r];
    // 5 cross terms (i+j<=2): chained f32 accumulation
    accs = __builtin_amdgcn_mfma_f32_16x16x32_bf16(a1, b0, accs, 0, 0, 0);
    accs = __builtin_amdgcn_mfma_f32_16x16x32_bf16(a0, b1, accs, 0, 0, 0);
    accs = __builtin_amdgcn_mfma_f32_16x16x32_bf16(a1, b1, accs, 0, 0, 0);
    accs = __builtin_amdgcn_mfma_f32_16x16x32_bf16(a2, b0, accs, 0, 0, 0);
    accs = __builtin_amdgcn_mfma_f32_16x16x32_bf16(a0, b2, accs, 0, 0, 0);
  }
  // partial (this K-half) -> LDS, keyed [jl*16+bl]
  #pragma unroll
  for (int r = 0; r < 4; ++r) {
    int bl = (lane >> 4) * 4 + r;  // C/D map (m89): row in 16-batch tile
    gvL[w][(lane & 15) * 16 + bl] = big[r] + (double)accs[r];
  }
  __syncthreads();

  // pointwise f64 cell: threads 0..255, one cell each (jl=tid>>4, bl=tid&15)
  if (tid < 256) {
    int jl = tid >> 4, bl = tid & 15;
    int j = jt * 16 + jl, b = mg * 16 + bl;
    double gv0 = (gvL[0][tid] + gvL[4][tid]) + (double)bx[j] + (double)bh[j];
    double gv1 = (gvL[1][tid] + gvL[5][tid]) + (double)bx[1024 + j] +
                 (double)bh[1024 + j];
    double gv2 = (gvL[2][tid] + gvL[6][tid]) + (double)bx[2048 + j] +
                 (double)bh[2048 + j];
    double gv3 = (gvL[3][tid] + gvL[7][tid]) + (double)bx[3072 + j] +
                 (double)bh[3072 + j];
    double c = cT64[(size_t)j * 64 + b];
    double f = 1.0 / (1.0 + exp(-gv0));
    double i = 1.0 / (1.0 + exp(-gv1));
    double gg = tanh(gv2);
    double o = 1.0 / (1.0 + exp(-gv3));
    c = f * c + i * gg;
    double h = o * tanh(c);
    cT64[(size_t)j * 64 + b] = c;
    h64[(size_t)j * 64 + b] = h;
    pack_h(j, b, h, HA2, HA3w);
  }
}

// ---- logits v3: K-split + LDS-transpose top-2 epilogue ----
// 500 blocks x 512 threads = 4 Nt x 2 K-halves. Wave (nl,half): 16 kc of
// single-term bf16 MFMA. half1 parks partials; half0 merges (fixed order),
// stores biased logits to global AND to padded LDS rows; then each lane
// scans its batch's 16 contiguous values (15 predicated compares) for
// top-2 -> identical keys to the old shuffle butterfly, far fewer ops.
__global__ __launch_bounds__(512) void k_logits_mfma(
    int t, const u16* __restrict__ HA2, const u16* __restrict__ WBL,
    const float* __restrict__ bout, float* __restrict__ out,
    u64* __restrict__ p2) {
  __shared__ f32x4 pacc[4][64][4];  // 16 KB: [nl][lane][Mt]
  __shared__ float lv[4][64][17];   // 17.4 KB: padded rows, conflict-free
  int tid = threadIdx.x, lane = tid & 63, w = tid >> 6;
  int nl = w & 3, half = w >> 2;
  int Nt = blockIdx.x * 4 + nl;
  int colw = Nt * 16 + (lane & 15);
  const u16* wb = WBL + (size_t)Nt * 16384 + lane * 8;
  f32x4 acc[4] = {};

  int kc0 = half * 16;
  #pragma unroll 2
  for (int kk = 0; kk < 16; ++kk) {
    int kc = kc0 + kk;
    bf16x8 bhv = *(const bf16x8*)(wb + (size_t)kc * 512);
    const u16* ha = HA2 + (size_t)kc * 2048 + lane * 8;
    #pragma unroll
    for (int Mt = 0; Mt < 4; ++Mt) {
      bf16x8 ah = *(const bf16x8*)(ha + Mt * 512);
      acc[Mt] = __builtin_amdgcn_mfma_f32_16x16x32_bf16(ah, bhv, acc[Mt], 0, 0, 0);
    }
  }
  if (half == 1) {
    #pragma unroll
    for (int Mt = 0; Mt < 4; ++Mt) pacc[nl][lane][Mt] = acc[Mt];
  }
  __syncthreads();
  if (half == 0) {
    #pragma unroll
    for (int Mt = 0; Mt < 4; ++Mt) acc[Mt] = acc[Mt] + pacc[nl][lane][Mt];
    float bo = bout[colw];
    float* orow = out + (size_t)t * BSZ * VSZ;
    #pragma unroll
    for (int Mt = 0; Mt < 4; ++Mt) {
      #pragma unroll
      for (int r = 0; r < 4; ++r) {
        int row = Mt * 16 + (lane >> 4) * 4 + r;
        float v = acc[Mt][r] + bo;
        orow[(size_t)row * VSZ + colw] = v;
        lv[nl][row][lane & 15] = v;
      }
    }
  }
  __syncthreads();
  if (half == 0) {
    // lane handles batch = lane for its tile nl (16 contiguous values)
    const float* rowp = lv[nl][lane];
    float m1 = rowp[0];
    int i1 = 0;
    float m2 = -__builtin_inff();
    int i2 = 1;
    #pragma unroll
    for (int c = 1; c < 16; ++c) {
      float v = rowp[c];
      bool top = v > m1;
      bool sec = v > m2;
      m2 = top ? m1 : (sec ? v : m2);
      i2 = top ? i1 : (sec ? c : i2);
      m1 = top ? v : m1;
      i1 = top ? c : i1;
    }
    int c1 = Nt * 16 + i1, c2 = Nt * 16 + i2;
    u64 k1 = ((u64)ordf(m1) << 32) | (unsigned)(~c1);
    u64 k2 = ((u64)ordf(m2) << 32) | (unsigned)(~c2);
    size_t slot = (size_t)lane * 2000 + blockIdx.x * 4 + nl;
    p2[slot * 2] = k1;
    p2[slot * 2 + 1] = k2;
  }
}

// ---- refine: global top-4; exact f64 logits; pick token; pack emb EA3 ----
// grid 64 (one block per batch) x 256 threads.
__global__ __launch_bounds__(256) void k_refine(
    const u64* __restrict__ p2, const double* __restrict__ h64,
    const float* __restrict__ Wout, const float* __restrict__ bout,
    int* __restrict__ tokbuf, const float* __restrict__ emb,
    u16* __restrict__ EA3) {
  __shared__ u64 sm[256][4];
  __shared__ double rr[256][4];
  __shared__ int s_i[4];
  __shared__ int s_sel;
  int b = blockIdx.x, tid = threadIdx.x;
  u64 t0 = 0, t1 = 0, t2 = 0, t3 = 0;
  for (int i = tid; i < 2000; i += 256) {
    u64 x = p2[((size_t)b * 2000 + i) * 2];
    u64 y = p2[((size_t)b * 2000 + i) * 2 + 1];
    ins4(x, t0, t1, t2, t3);
    ins4(y, t0, t1, t2, t3);
  }
  sm[tid][0] = t0; sm[tid][1] = t1; sm[tid][2] = t2; sm[tid][3] = t3;
  __syncthreads();
  for (int off = 128; off > 0; off >>= 1) {
    if (tid < off) {
      u64 a0 = sm[tid][0], a1 = sm[tid][1], a2 = sm[tid][2], a3 = sm[tid][3];
      merge4(a0, a1, a2, a3, sm[tid + off][0], sm[tid + off][1],
             sm[tid + off][2], sm[tid + off][3]);
      sm[tid][0] = a0; sm[tid][1] = a1; sm[tid][2] = a2; sm[tid][3] = a3;
    }
    __syncthreads();
  }
  if (tid < 4) s_i[tid] = (int)(~(u32)(sm[0][tid] & 0xFFFFFFFFull));
  __syncthreads();
  int i0 = s_i[0], i1 = s_i[1], i2 = s_i[2], i3 = s_i[3];
  double a0 = 0.0, a1 = 0.0, a2 = 0.0, a3 = 0.0;
  #pragma unroll
  for (int q = 0; q < 4; ++q) {
    int k = tid * 4 + q;
    double h = h64[(size_t)k * 64 + b];
    const float* wr = Wout + (size_t)k * VSZ;
    a0 += h * (double)wr[i0];
    a1 += h * (double)wr[i1];
    a2 += h * (double)wr[i2];
    a3 += h * (double)wr[i3];
  }
  rr[tid][0] = a0; rr[tid][1] = a1; rr[tid][2] = a2; rr[tid][3] = a3;
  __syncthreads();
  for (int off = 128; off > 0; off >>= 1) {
    if (tid < off) {
      rr[tid][0] += rr[tid + off][0];
      rr[tid][1] += rr[tid + off][1];
      rr[tid][2] += rr[tid + off][2];
      rr[tid][3] += rr[tid + off][3];
    }
    __syncthreads();
  }
  if (tid == 0) {
    double v0 = rr[0][0] + (double)bout[i0];
    double v1 = rr[0][1] + (double)bout[i1];
    double v2 = rr[0][2] + (double)bout[i2];
    double v3 = rr[0][3] + (double)bout[i3];
    double bv = v0; int bi = i0;
    if (v1 > bv || (v1 == bv && i1 < bi)) { bv = v1; bi = i1; }
    if (v2 > bv || (v2 == bv && i2 < bi)) { bv = v2; bi = i2; }
    if (v3 > bv || (v3 == bv && i3 < bi)) { bv = v3; bi = i3; }
    tokbuf[b] = bi;
    s_sel = bi;
  }
  __syncthreads();
  // pack next step's embedding A-frags for this batch (512 elems, 2/thread)
  int tokf = s_sel;
  int k = tid * 2;
  pack_e(k, b, (double)emb[(size_t)tokf * ESZ + k], EA3);
  pack_e(k + 1, b, (double)emb[(size_t)tokf * ESZ + k + 1], EA3);
}

// ================= fallback all-f32 path (round-1, proven) =================

__global__ __launch_bounds__(256) void k_initF(const float* __restrict__ h0,
                                               const float* __restrict__ c0,
                                               float* __restrict__ hT,
                                               float* __restrict__ cT) {
  int idx = blockIdx.x * 256 + threadIdx.x;
  int j = idx >> 6, b = idx & 63;
  hT[idx] = h0[b * HSZ + j];
  cT[idx] = c0[b * HSZ + j];
}

__global__ __launch_bounds__(256) void k_gatesF(
    int t, const int* __restrict__ sos, const u64* __restrict__ partials,
    const float* __restrict__ emb, const float* __restrict__ Wx,
    const float* __restrict__ Wh, const float* __restrict__ hT,
    float* __restrict__ gP) {
  __shared__ float xs[128 * 64];
  __shared__ u64 s_red[256];
  __shared__ int s_tok[64];
  int tid = threadIdx.x;
  if (t == 0) {
    if (tid < 64) s_tok[tid] = sos[tid];
  } else {
    int b = tid >> 2, q = tid & 3;
    u64 best = 0ull;
    int i0 = q * 63, i1 = i0 + 63;
    if (i1 > 250) i1 = 250;
    for (int i = i0; i < i1; ++i) {
      u64 v = partials[b * 512 + i];
      if (v > best) best = v;
    }
    s_red[tid] = best;
    __syncthreads();
    if (q == 0) {
      u64 m = best;
      #pragma unroll
      for (int k = 1; k < 4; ++k) {
        u64 v = s_red[tid + k];
        if (v > m) m = v;
      }
      s_tok[b] = (int)(~(unsigned)(m & 0xFFFFFFFFull));
    }
  }
  __syncthreads();
  int colblk = blockIdx.x & 63, ks = blockIdx.x >> 6;
  int col = colblk * 16 + (tid & 15);
  int b0 = (tid >> 4) * 4;
  float acc[4][4];
  #pragma unroll
  for (int g = 0; g < 4; ++g)
    #pragma unroll
    for (int bb = 0; bb < 4; ++bb) acc[g][bb] = 0.f;
  for (int kc = 0; kc < 3; ++kc) {
    int k0 = ks * 384 + kc * 128;
    __syncthreads();
    if (k0 < 512) {
      int b = tid & 63;
      int kk0 = (tid >> 6) * 32;
      const float* erow = emb + (size_t)s_tok[b] * ESZ + k0 + kk0;
      #pragma unroll
      for (int i = 0; i < 32; i += 4) {
        float4 v = *(const float4*)(erow + i);
        xs[(kk0 + i) * 64 + b] = v.x;
        xs[(kk0 + i + 1) * 64 + b] = v.y;
        xs[(kk0 + i + 2) * 64 + b] = v.z;
        xs[(kk0 + i + 3) * 64 + b] = v.w;
      }
    } else {
      const float* src = hT + (size_t)(k0 - 512) * 64;
      #pragma unroll
      for (int i = 0; i < 8192; i += 1024)
        *(float4*)&xs[i + tid * 4] = *(const float4*)(src + i + tid * 4);
    }
    __syncthreads();
    const float* Wb = (k0 < 512) ? (Wx + (size_t)k0 * G4H + col)
                                 : (Wh + (size_t)(k0 - 512) * G4H + col);
    #pragma unroll 4
    for (int kk = 0; kk < 128; ++kk) {
      float4 xv = *(const float4*)&xs[kk * 64 + b0];
      const float* wr = Wb + (size_t)kk * G4H;
      float w0 = wr[0], w1 = wr[1024], w2 = wr[2048], w3 = wr[3072];
      acc[0][0] += w0 * xv.x; acc[0][1] += w0 * xv.y;
      acc[0][2] += w0 * xv.z; acc[0][3] += w0 * xv.w;
      acc[1][0] += w1 * xv.x; acc[1][1] += w1 * xv.y;
      acc[1][2] += w1 * xv.z; acc[1][3] += w1 * xv.w;
      acc[2][0] += w2 * xv.x; acc[2][1] += w2 * xv.y;
      acc[2][2] += w2 * xv.z; acc[2][3] += w2 * xv.w;
      acc[3][0] += w3 * xv.x; acc[3][1] += w3 * xv.y;
      acc[3][2] += w3 * xv.z; acc[3][3] += w3 * xv.w;
    }
  }
  #pragma unroll
  for (int g = 0; g < 4; ++g) {
    float4 v = make_float4(acc[g][0], acc[g][1], acc[g][2], acc[g][3]);
    *(float4*)&gP[((size_t)ks * G4H + g * 1024 + col) * 64 + b0] = v;
  }
}

__global__ __launch_bounds__(256) void k_cellF(const float* __restrict__ gP,
                                               const float* __restrict__ bx,
                                               const float* __restrict__ bh,
                                               float* __restrict__ hT,
                                               float* __restrict__ cT) {
  int flat = (blockIdx.x * 256 + threadIdx.x) * 2;
  int j = flat >> 6;
  float2 gv[4];
  #pragma unroll
  for (int g = 0; g < 4; ++g) {
    size_t base = ((size_t)g * 1024 + j) * 64 + (flat & 63);
    float2 s = *(const float2*)&gP[base];
    #pragma unroll
    for (int ks = 1; ks < 4; ++ks) {
      float2 p = *(const float2*)&gP[(size_t)ks * 262144 + base];
      s.x += p.x; s.y += p.y;
    }
    float bias = bx[g * 1024 + j] + bh[g * 1024 + j];
    s.x += bias; s.y += bias;
    gv[g] = s;
  }
  float2 c = *(const float2*)&cT[flat];
  float fx = 1.f / (1.f + expf(-gv[0].x)), fy = 1.f / (1.f + expf(-gv[0].y));
  float ix = 1.f / (1.f + expf(-gv[1].x)), iy = 1.f / (1.f + expf(-gv[1].y));
  float gx = tanhf(gv[2].x), gy = tanhf(gv[2].y);
  float ox = 1.f / (1.f + expf(-gv[3].x)), oy = 1.f / (1.f + expf(-gv[3].y));
  float cx = fx * c.x + ix * gx, cy = fy * c.y + iy * gy;
  float hx = ox * tanhf(cx), hy = oy * tanhf(cy);
  *(float2*)&cT[flat] = make_float2(cx, cy);
  *(float2*)&hT[flat] = make_float2(hx, hy);
}

__global__ __launch_bounds__(512) void k_logitsF(
    int t, const float* __restrict__ hT, const float* __restrict__ Wout,
    const float* __restrict__ bout, float* __restrict__ out,
    u64* __restrict__ partials) {
  __shared__ float hs[128 * 64];
  int tid = threadIdx.x;
  int lane = tid & 63;
  int bg = tid >> 6;
  int b0 = bg * 8;
  int j0 = blockIdx.x * 128 + lane * 2;
  float a0[8], a1[8];
  #pragma unroll
  for (int i = 0; i < 8; ++i) { a0[i] = 0.f; a1[i] = 0.f; }
  for (int kc = 0; kc < 8; ++kc) {
    int k0 = kc * 128;
    __syncthreads();
    #pragma unroll
    for (int i = 0; i < 8192; i += 2048)
      *(float4*)&hs[i + tid * 4] =
          *(const float4*)&hT[(size_t)k0 * 64 + i + tid * 4];
    __syncthreads();
    #pragma unroll 4
    for (int kk = 0; kk < 128; ++kk) {
      float2 wv = *(const float2*)(Wout + (size_t)(k0 + kk) * VSZ + j0);
      const float* hrow = &hs[kk * 64 + b0];
      float4 h0v = *(const float4*)(hrow);
      float4 h1v = *(const float4*)(hrow + 4);
      a0[0] += h0v.x * wv.x; a1[0] += h0v.x * wv.y;
      a0[1] += h0v.y * wv.x; a1[1] += h0v.y * wv.y;
      a0[2] += h0v.z * wv.x; a1[2] += h0v.z * wv.y;
      a0[3] += h0v.w * wv.x; a1[3] += h0v.w * wv.y;
      a0[4] += h1v.x * wv.x; a1[4] += h1v.x * wv.y;
      a0[5] += h1v.y * wv.x; a1[5] += h1v.y * wv.y;
      a0[6] += h1v.z * wv.x; a1[6] += h1v.z * wv.y;
      a0[7] += h1v.w * wv.x; a1[7] += h1v.w * wv.y;
    }
  }
  float bo0 = bout[j0], bo1 = bout[j0 + 1];
  float* orow = out + (size_t)t * BSZ * VSZ;
  #pragma unroll
  for (int bb = 0; bb < 8; ++bb) {
    float v0 = a0[bb] + bo0, v1 = a1[bb] + bo1;
    *(float2*)(orow + (size_t)(b0 + bb) * VSZ + j0) = make_float2(v0, v1);
    float m; int mi;
    if (v1 > v0) { m = v1; mi = j0 + 1; } else { m = v0; mi = j0; }
    u64 key = ((u64)ordf(m) << 32) | (unsigned)(~mi);
    #pragma unroll
    for (int s = 32; s > 0; s >>= 1) {
      u64 o = __shfl_xor(key, s, 64);
      if (o > key) key = o;
    }
    if (lane == bb) partials[(size_t)(b0 + bb) * 512 + blockIdx.x] = key;
  }
}

extern "C" void kernel_launch(void* const* d_in, const int* in_sizes, int n_in,
                              void* d_out, int out_size, void* d_ws,
                              size_t ws_size, hipStream_t stream) {
  const float* emb  = (const float*)d_in[0];
  const float* Wx   = (const float*)d_in[1];
  const float* bx   = (const float*)d_in[2];
  const float* Wh   = (const float*)d_in[3];
  const float* bh   = (const float*)d_in[4];
  const float* Wout = (const float*)d_in[5];
  const float* bout = (const float*)d_in[6];
  const float* h0   = (const float*)d_in[7];
  const float* c0   = (const float*)d_in[8];
  const int*   sos  = (const int*)d_in[9];
  float* out = (float*)d_out;

  bool mfma = ws_size >= 123814912ULL;

  // ws layout (cumulative byte offsets, audited r12):
  //   cT64 @ 0         size 524288
  //   h64  @ 524288    size 524288
  //   HA2  @ 1048576   size 131072   (128 tiles * 512 u16 * 2B)
  //   HA3a @ 1179648   size 393216   (128 tiles * 3 * 512 u16 * 2B)
  //   HA3b @ 1572864   size 393216
  //   EA3  @ 1966080   size 196608   (64 tiles * 3 * 512 u16 * 2B)
  //   tokb @ 2162688   size 256
  //   p2   @ 2166784   size 2048000  (64*2000*2 u64)
  //   WBL  @ 4214784   size 65536000
  //   WBG  @ 69750784  size 37748736 -> end 107499520
  char* base = (char*)d_ws;
  double* cT64 = (double*)(base);
  double* h64  = (double*)(base + 524288);
  u16*    HA2  = (u16*)(base + 1048576);
  u16*    HA3a = (u16*)(base + 1179648);
  u16*    HA3b = (u16*)(base + 1572864);
  u16*    EA3  = (u16*)(base + 1966080);
  int*    tokb = (int*)(base + 2162688);
  u64*    p2   = (u64*)(base + 2166784);
  u16*    WBL  = (u16*)(base + 4214784);
  u16*    WBG  = (u16*)(base + 69750784);
  // f32-fallback layout overlaps (paths exclusive)
  float* hT = (float*)(base);
  float* cT = (float*)(base + 262144);
  float* gP = (float*)(base + 524288);
  u64* partials = (u64*)(base + 4718592);

  if (mfma) {
    k_wpackL<<<500, 256, 0, stream>>>(Wout, WBL);
    k_wpackG<<<256, 256, 0, stream>>>(Wx, Wh, WBG);
    k_init<<<256, 256, 0, stream>>>(h0, c0, sos, emb, cT64, h64, HA2, HA3b,
                                    EA3);
    for (int t = 0; t < TSZ; ++t) {
      const u16* HA3r = (t & 1) ? HA3a : HA3b;  // gates read h_{t-1}
      u16* HA3w = (t & 1) ? HA3b : HA3a;        // cell writes h_t
      k_gatescell<<<256, 512, 0, stream>>>(EA3, HA3r, WBG, bx, bh, cT64, h64,
                                           HA2, HA3w);
      k_logits_mfma<<<500, 512, 0, stream>>>(t, HA2, WBL, bout, out, p2);
      if (t + 1 < TSZ)  // last step's token is never consumed
        k_refine<<<64, 256, 0, stream>>>(p2, h64, Wout, bout, tokb, emb, EA3);
    }
  } else {
    k_initF<<<256, 256, 0, stream>>>(h0, c0, hT, cT);
    for (int t = 0; t < TSZ; ++t) {
      k_gatesF<<<256, 256, 0, stream>>>(t, sos, partials, emb, Wx, Wh, hT, gP);
      k_cellF<<<128, 256, 0, stream>>>(gP, bx, bh, hT, cT);
      k_logitsF<<<250, 512, 0, stream>>>(t, hT, Wout, bout, out, partials);
    }
  }
}

// Round 17
// 1457.632 us; speedup vs baseline: 5.9744x; 1.0385x over previous
//
#include <hip/hip_runtime.h>

// DecoderLSTM: V=32000 E=512 H=1024 B=64 T=32, fp32, greedy decode.
// Design (round 17 = round 16 + logits store/key plumbing):
//  1) Coalesced out-stores: logits tile already sits in LDS (lv); ALL 512
//     threads store the 64x64 block tile as 2x float4 (16B-aligned) --
//     replaces 16 scattered scalar stores per half0 lane.
//  2) p2 = per-block TOP-4 (merge 4 Nt top-2s in LDS, fixed order):
//     strictly stronger candidate guarantee, refine scan traffic halves.
//  3) unroll 4 on the logits MFMA loop (deeper load pipelining).
// Values/keys/decisions provably identical -> absmax exactly 3.90625e-3.
//  - k_gatescell: r14-verbatim (XCD swizzle, fused f64 cell).
//  - k_init / packs: r14-verbatim. 98 graph nodes. No cross-block sync.
// Falls back to round-1 all-f32 path if ws too small.

#define VSZ 32000
#define ESZ 512
#define HSZ 1024
#define BSZ 64
#define TSZ 32
#define G4H 4096

typedef unsigned short u16;
typedef unsigned int u32;
typedef unsigned long long u64;
typedef __attribute__((ext_vector_type(8))) short bf16x8;
typedef __attribute__((ext_vector_type(4))) float f32x4;

__device__ __forceinline__ unsigned ordf(float f) {
  unsigned u = __float_as_uint(f);
  return (u & 0x80000000u) ? ~u : (u | 0x80000000u);  // monotone float->uint
}
__device__ __forceinline__ u16 f2bf(float f) {  // f32 -> bf16 RNE
  u32 u = __float_as_uint(f);
  return (u16)((u + 0x7FFFu + ((u >> 16) & 1u)) >> 16);
}
__device__ __forceinline__ float bf2f(u16 s) {
  return __uint_as_float(((u32)s) << 16);
}
// 3-way bf16 split of a double (captures ~24 bits)
__device__ __forceinline__ void split3(double v, u16& s0, u16& s1, u16& s2) {
  s0 = f2bf((float)v);
  double r = v - (double)bf2f(s0);
  s1 = f2bf((float)r);
  double r2 = r - (double)bf2f(s1);
  s2 = f2bf((float)r2);
}

// pack h (f64) into HA2 (logits A: single bf16) and HA3 (gates A: 3 terms)
__device__ __forceinline__ void pack_h(int j, int b, double h,
                                       u16* __restrict__ HA2,
                                       u16* __restrict__ HA3) {
  u16 s0, s1, s2;
  split3(h, s0, s1, s2);
  int kc = j >> 5, kj = j & 31;
  int lane = (b & 15) | ((kj >> 3) << 4);
  int Mt = b >> 4;
  int e = kj & 7;
  HA2[(size_t)(kc * 4 + Mt) * 512 + lane * 8 + e] = s0;
  size_t b3 = ((size_t)(kc * 4 + Mt) * 3) * 512 + lane * 8 + e;
  HA3[b3] = s0;
  HA3[b3 + 512] = s1;
  HA3[b3 + 1024] = s2;
}

// pack one embedding element (k,b) into EA3 (gates A, kc 0..15)
__device__ __forceinline__ void pack_e(int k, int b, double v,
                                       u16* __restrict__ EA3) {
  u16 s0, s1, s2;
  split3(v, s0, s1, s2);
  int kc = k >> 5, kj = k & 31;
  int lane = (b & 15) | ((kj >> 3) << 4);
  int Mt = b >> 4;
  int e = kj & 7;
  size_t b3 = ((size_t)(kc * 4 + Mt) * 3) * 512 + lane * 8 + e;
  EA3[b3] = s0;
  EA3[b3 + 512] = s1;
  EA3[b3 + 1024] = s2;
}

// sorted-4 (desc) insert, branchless
__device__ __forceinline__ void ins4(u64 v, u64& t0, u64& t1, u64& t2,
                                     u64& t3) {
  bool g0 = v > t0, g1 = v > t1, g2 = v > t2, g3 = v > t3;
  t3 = g2 ? t2 : (g3 ? v : t3);
  t2 = g1 ? t1 : (g2 ? v : t2);
  t1 = g0 ? t0 : (g1 ? v : t1);
  t0 = g0 ? v : t0;
}
// top-4 of two sorted-desc 4-lists (bitonic)
__device__ __forceinline__ void merge4(u64& a0, u64& a1, u64& a2, u64& a3,
                                       u64 b0, u64 b1, u64 b2, u64 b3) {
  u64 m0 = a0 > b3 ? a0 : b3;
  u64 m1 = a1 > b2 ? a1 : b2;
  u64 m2 = a2 > b1 ? a2 : b1;
  u64 m3 = a3 > b0 ? a3 : b0;
  u64 e0 = m0 > m2 ? m0 : m2, e2 = m0 > m2 ? m2 : m0;
  u64 e1 = m1 > m3 ? m1 : m3, e3 = m1 > m3 ? m3 : m1;
  a0 = e0 > e1 ? e0 : e1;
  a1 = e0 > e1 ? e1 : e0;
  a2 = e2 > e3 ? e2 : e3;
  a3 = e2 > e3 ? e3 : e2;
}

// ---- init: c0,h0 -> f64 state; pack h0 into HA3b; pack sos emb -> EA3 ----
__global__ __launch_bounds__(256) void k_init(
    const float* __restrict__ h0, const float* __restrict__ c0,
    const int* __restrict__ sos, const float* __restrict__ emb,
    double* __restrict__ cT64, double* __restrict__ h64,
    u16* __restrict__ HA2, u16* __restrict__ HA3b, u16* __restrict__ EA3) {
  int idx = blockIdx.x * 256 + threadIdx.x;  // 65536
  int j = idx >> 6, b = idx & 63;
  double h = (double)h0[b * HSZ + j];
  cT64[idx] = (double)c0[b * HSZ + j];
  h64[idx] = h;
  pack_h(j, b, h, HA2, HA3b);
  if (j < ESZ) pack_e(j, b, (double)emb[(size_t)sos[b] * ESZ + j], EA3);
}

// ---- pack Wout (f32 [K=1024][V]) into logits B single bf16, once ----
// WBL layout: [Nt=2000][kc=32][lane=64][e=8]
__global__ __launch_bounds__(256) void k_wpackL(const float* __restrict__ Wout,
                                                u16* __restrict__ WBL) {
  __shared__ float ls[32][64];
  int tid = threadIdx.x;
  int j0 = blockIdx.x * 64;
  int Nt0 = blockIdx.x * 4;
  for (int kc = 0; kc < 32; ++kc) {
    __syncthreads();
    #pragma unroll
    for (int rr = 0; rr < 8; ++rr) {
      int row = rr * 4 + (tid >> 6);
      ls[row][tid & 63] = Wout[(size_t)(kc * 32 + row) * VSZ + j0 + (tid & 63)];
    }
    __syncthreads();
    int lane = tid & 63, Ntl = tid >> 6;
    int col = Ntl * 16 + (lane & 15);
    int kb = (lane >> 4) * 8;
    alignas(16) u16 hibuf[8];
    #pragma unroll
    for (int e = 0; e < 8; ++e) hibuf[e] = f2bf(ls[kb + e][col]);
    size_t base = ((size_t)((Nt0 + Ntl) * 32 + kc)) * 512 + lane * 8;
    *(bf16x8*)&WBL[base] = *(const bf16x8*)hibuf;
  }
}

// ---- pack [Wx;Wh] (f32 [K=1536][4096]) into gates B 3-term, once ----
// WBG layout: [Nt=256][kc=48][term=3][lane=64][e=8]
__global__ __launch_bounds__(256) void k_wpackG(const float* __restrict__ Wx,
                                                const float* __restrict__ Wh,
                                                u16* __restrict__ WBG) {
  int tid = threadIdx.x;
  int Nt = blockIdx.x;  // 256 blocks
  int lane = tid & 63, w = tid >> 6;
  int col = Nt * 16 + (lane & 15);
  for (int i = 0; i < 12; ++i) {
    int kc = w * 12 + i;
    int kb = kc * 32 + (lane >> 4) * 8;
    alignas(16) u16 b0[8], b1[8], b2[8];
    #pragma unroll
    for (int e = 0; e < 8; ++e) {
      int k = kb + e;
      float v = (k < ESZ) ? Wx[(size_t)k * G4H + col]
                          : Wh[(size_t)(k - ESZ) * G4H + col];
      u16 s0, s1, s2;
      split3((double)v, s0, s1, s2);
      b0[e] = s0; b1[e] = s1; b2[e] = s2;
    }
    size_t base = ((size_t)(Nt * 48 + kc) * 3) * 512 + lane * 8;
    *(bf16x8*)&WBG[base] = *(const bf16x8*)b0;
    *(bf16x8*)&WBG[base + 512] = *(const bf16x8*)b1;
    *(bf16x8*)&WBG[base + 1024] = *(const bf16x8*)b2;
  }
}

// ---- fused gates+cell v2 + XCD swizzle: 256 blocks x 512 threads ----
// Swizzle: xcd=q&7, slot=q>>3; jt=xcd+8*(slot>>2), mg=slot&3. The 4 mg
// blocks of a jt share q&7 -> same XCD -> WBG tile hits L2 after 1st fetch.
// Wave w: gate g=w&3, K-half kh=w>>2 (24 chunks x 6 MFMA), batch tile mg.
// Cell = 256-thread pointwise f64 epilogue; halves summed in fixed order.
__global__ __launch_bounds__(512) void k_gatescell(
    const u16* __restrict__ EA3, const u16* __restrict__ HA3r,
    const u16* __restrict__ WBG, const float* __restrict__ bx,
    const float* __restrict__ bh, double* __restrict__ cT64,
    double* __restrict__ h64, u16* __restrict__ HA2,
    u16* __restrict__ HA3w) {
  __shared__ double gvL[8][256];  // 16 KB: [wave][jl*16+bl]
  int tid = threadIdx.x, lane = tid & 63, w = tid >> 6;  // 8 waves
  int g = w & 3, kh = w >> 2;
  int q = blockIdx.x;
  int jt = (q & 7) + 8 * ((q >> 3) >> 2);  // XCD-coherent j-tile
  int mg = (q >> 3) & 3;                   // batch group within jt
  int Nt = g * 64 + jt;

  double big[4];
  #pragma unroll
  for (int r = 0; r < 4; ++r) big[r] = 0.0;
  f32x4 accs = {0.f, 0.f, 0.f, 0.f};
  const f32x4 zz = {0.f, 0.f, 0.f, 0.f};

  for (int i = 0; i < 24; ++i) {
    int kc = kh * 24 + i;  // global K chunk (48 total)
    const u16* wb = WBG + ((size_t)(Nt * 48 + kc) * 3) * 512 + lane * 8;
    bf16x8 b0 = *(const bf16x8*)wb;
    bf16x8 b1 = *(const bf16x8*)(wb + 512);
    bf16x8 b2 = *(const bf16x8*)(wb + 1024);
    const u16* ha = (kc < 16)
        ? (EA3 + ((size_t)(kc * 4 + mg) * 3) * 512 + lane * 8)
        : (HA3r + ((size_t)((kc - 16) * 4 + mg) * 3) * 512 + lane * 8);
    bf16x8 a0 = *(const bf16x8*)ha;
    bf16x8 a1 = *(const bf16x8*)(ha + 512);
    bf16x8 a2 = *(const bf16x8*)(ha + 1024);
    // dominant term: isolated MFMA, promoted to f64 per chunk
    f32x4 tb = __builtin_amdgcn_mfma_f32_16x16x32_bf16(a0, b0, zz, 0, 0, 0);
    #pragma unroll
    for (int r = 0; r < 4; ++r) big[r] += (double)tb[r];
    // 5 cross terms (i+j<=2): chained f32 accumulation
    accs = __builtin_amdgcn_mfma_f32_16x16x32_bf16(a1, b0, accs, 0, 0, 0);
    accs = __builtin_amdgcn_mfma_f32_16x16x32_bf16(a0, b1, accs, 0, 0, 0);
    accs = __builtin_amdgcn_mfma_f32_16x16x32_bf16(a1, b1, accs, 0, 0, 0);
    accs = __builtin_amdgcn_mfma_f32_16x16x32_bf16(a2, b0, accs, 0, 0, 0);
    accs = __builtin_amdgcn_mfma_f32_16x16x32_bf16(a0, b2, accs, 0, 0, 0);
  }
  // partial (this K-half) -> LDS, keyed [jl*16+bl]
  #pragma unroll
  for (int r = 0; r < 4; ++r) {
    int bl = (lane >> 4) * 4 + r;  // C/D map (m89): row in 16-batch tile
    gvL[w][(lane & 15) * 16 + bl] = big[r] + (double)accs[r];
  }
  __syncthreads();

  // pointwise f64 cell: threads 0..255, one cell each (jl=tid>>4, bl=tid&15)
  if (tid < 256) {
    int jl = tid >> 4, bl = tid & 15;
    int j = jt * 16 + jl, b = mg * 16 + bl;
    double gv0 = (gvL[0][tid] + gvL[4][tid]) + (double)bx[j] + (double)bh[j];
    double gv1 = (gvL[1][tid] + gvL[5][tid]) + (double)bx[1024 + j] +
                 (double)bh[1024 + j];
    double gv2 = (gvL[2][tid] + gvL[6][tid]) + (double)bx[2048 + j] +
                 (double)bh[2048 + j];
    double gv3 = (gvL[3][tid] + gvL[7][tid]) + (double)bx[3072 + j] +
                 (double)bh[3072 + j];
    double c = cT64[(size_t)j * 64 + b];
    double f = 1.0 / (1.0 + exp(-gv0));
    double i = 1.0 / (1.0 + exp(-gv1));
    double gg = tanh(gv2);
    double o = 1.0 / (1.0 + exp(-gv3));
    c = f * c + i * gg;
    double h = o * tanh(c);
    cT64[(size_t)j * 64 + b] = c;
    h64[(size_t)j * 64 + b] = h;
    pack_h(j, b, h, HA2, HA3w);
  }
}

// ---- logits v4: K-split MFMA + LDS tile + coalesced stores + top4/block --
__global__ __launch_bounds__(512) void k_logits_mfma(
    int t, const u16* __restrict__ HA2, const u16* __restrict__ WBL,
    const float* __restrict__ bout, float* __restrict__ out,
    u64* __restrict__ p2) {
  __shared__ f32x4 pacc[4][64][4];  // 16 KB: [nl][lane][Mt]
  __shared__ float lv[4][64][17];   // 17.4 KB: [nl][batch][col], padded
  __shared__ u64 kk[4][64][2];      // 4 KB: per-Nt top2 keys per batch
  int tid = threadIdx.x, lane = tid & 63, w = tid >> 6;
  int nl = w & 3, half = w >> 2;
  int Nt = blockIdx.x * 4 + nl;
  int colw = Nt * 16 + (lane & 15);
  const u16* wb = WBL + (size_t)Nt * 16384 + lane * 8;
  f32x4 acc[4] = {};

  int kc0 = half * 16;
  #pragma unroll 4
  for (int kq = 0; kq < 16; ++kq) {
    int kc = kc0 + kq;
    bf16x8 bhv = *(const bf16x8*)(wb + (size_t)kc * 512);
    const u16* ha = HA2 + (size_t)kc * 2048 + lane * 8;
    #pragma unroll
    for (int Mt = 0; Mt < 4; ++Mt) {
      bf16x8 ah = *(const bf16x8*)(ha + Mt * 512);
      acc[Mt] = __builtin_amdgcn_mfma_f32_16x16x32_bf16(ah, bhv, acc[Mt], 0, 0, 0);
    }
  }
  if (half == 1) {
    #pragma unroll
    for (int Mt = 0; Mt < 4; ++Mt) pacc[nl][lane][Mt] = acc[Mt];
  }
  __syncthreads();
  if (half == 0) {
    #pragma unroll
    for (int Mt = 0; Mt < 4; ++Mt) acc[Mt] = acc[Mt] + pacc[nl][lane][Mt];
    float bo = bout[colw];
    #pragma unroll
    for (int Mt = 0; Mt < 4; ++Mt) {
      #pragma unroll
      for (int r = 0; r < 4; ++r) {
        int row = Mt * 16 + (lane >> 4) * 4 + r;  // batch (C/D map, m89)
        lv[nl][row][lane & 15] = acc[Mt][r] + bo;
      }
    }
  }
  __syncthreads();
  // coalesced store of the 64x64 block tile: all 512 threads, 8 floats each
  {
    float* orow = out + (size_t)t * BSZ * VSZ;
    int r = tid >> 3, cc0 = (tid & 7) * 8;
    int nl2 = cc0 >> 4, c2 = cc0 & 15;
    float tmp[8];
    #pragma unroll
    for (int u = 0; u < 8; ++u) tmp[u] = lv[nl2][r][c2 + u];
    float* dst = orow + (size_t)r * VSZ + blockIdx.x * 64 + cc0;
    *(float4*)dst = make_float4(tmp[0], tmp[1], tmp[2], tmp[3]);
    *(float4*)(dst + 4) = make_float4(tmp[4], tmp[5], tmp[6], tmp[7]);
  }
  if (half == 0) {
    // per-lane top-2 scan of batch=lane's 16 values (identical keys to r16)
    const float* rowp = lv[nl][lane];
    float m1 = rowp[0];
    int i1 = 0;
    float m2 = -__builtin_inff();
    int i2 = 1;
    #pragma unroll
    for (int c = 1; c < 16; ++c) {
      float v = rowp[c];
      bool top = v > m1;
      bool sec = v > m2;
      m2 = top ? m1 : (sec ? v : m2);
      i2 = top ? i1 : (sec ? c : i2);
      m1 = top ? v : m1;
      i1 = top ? c : i1;
    }
    int c1 = Nt * 16 + i1, c2 = Nt * 16 + i2;
    kk[nl][lane][0] = ((u64)ordf(m1) << 32) | (unsigned)(~c1);
    kk[nl][lane][1] = ((u64)ordf(m2) << 32) | (unsigned)(~c2);
  }
  __syncthreads();
  if (half == 0 && nl == 0) {
    // merge 4 Nt top-2s -> block top-4 (fixed order; distinct keys)
    u64 t0 = 0, t1 = 0, t2 = 0, t3 = 0;
    #pragma unroll
    for (int q = 0; q < 4; ++q) {
      ins4(kk[q][lane][0], t0, t1, t2, t3);
      ins4(kk[q][lane][1], t0, t1, t2, t3);
    }
    size_t s4 = ((size_t)lane * 500 + blockIdx.x) * 4;
    p2[s4] = t0;
    p2[s4 + 1] = t1;
    p2[s4 + 2] = t2;
    p2[s4 + 3] = t3;
  }
}

// ---- refine: global top-4 (from 500x4 keys); exact f64; pick; pack EA3 ----
// grid 64 (one block per batch) x 256 threads.
__global__ __launch_bounds__(256) void k_refine(
    const u64* __restrict__ p2, const double* __restrict__ h64,
    const float* __restrict__ Wout, const float* __restrict__ bout,
    int* __restrict__ tokbuf, const float* __restrict__ emb,
    u16* __restrict__ EA3) {
  __shared__ u64 sm[256][4];
  __shared__ double rr[256][4];
  __shared__ int s_i[4];
  __shared__ int s_sel;
  int b = blockIdx.x, tid = threadIdx.x;
  u64 t0 = 0, t1 = 0, t2 = 0, t3 = 0;
  for (int i = tid; i < 500; i += 256) {
    const u64* pp = &p2[((size_t)b * 500 + i) * 4];
    ins4(pp[0], t0, t1, t2, t3);
    ins4(pp[1], t0, t1, t2, t3);
    ins4(pp[2], t0, t1, t2, t3);
    ins4(pp[3], t0, t1, t2, t3);
  }
  sm[tid][0] = t0; sm[tid][1] = t1; sm[tid][2] = t2; sm[tid][3] = t3;
  __syncthreads();
  for (int off = 128; off > 0; off >>= 1) {
    if (tid < off) {
      u64 a0 = sm[tid][0], a1 = sm[tid][1], a2 = sm[tid][2], a3 = sm[tid][3];
      merge4(a0, a1, a2, a3, sm[tid + off][0], sm[tid + off][1],
             sm[tid + off][2], sm[tid + off][3]);
      sm[tid][0] = a0; sm[tid][1] = a1; sm[tid][2] = a2; sm[tid][3] = a3;
    }
    __syncthreads();
  }
  if (tid < 4) s_i[tid] = (int)(~(u32)(sm[0][tid] & 0xFFFFFFFFull));
  __syncthreads();
  int i0 = s_i[0], i1 = s_i[1], i2 = s_i[2], i3 = s_i[3];
  double a0 = 0.0, a1 = 0.0, a2 = 0.0, a3 = 0.0;
  #pragma unroll
  for (int q = 0; q < 4; ++q) {
    int k = tid * 4 + q;
    double h = h64[(size_t)k * 64 + b];
    const float* wr = Wout + (size_t)k * VSZ;
    a0 += h * (double)wr[i0];
    a1 += h * (double)wr[i1];
    a2 += h * (double)wr[i2];
    a3 += h * (double)wr[i3];
  }
  rr[tid][0] = a0; rr[tid][1] = a1; rr[tid][2] = a2; rr[tid][3] = a3;
  __syncthreads();
  for (int off = 128; off > 0; off >>= 1) {
    if (tid < off) {
      rr[tid][0] += rr[tid + off][0];
      rr[tid][1] += rr[tid + off][1];
      rr[tid][2] += rr[tid + off][2];
      rr[tid][3] += rr[tid + off][3];
    }
    __syncthreads();
  }
  if (tid == 0) {
    double v0 = rr[0][0] + (double)bout[i0];
    double v1 = rr[0][1] + (double)bout[i1];
    double v2 = rr[0][2] + (double)bout[i2];
    double v3 = rr[0][3] + (double)bout[i3];
    double bv = v0; int bi = i0;
    if (v1 > bv || (v1 == bv && i1 < bi)) { bv = v1; bi = i1; }
    if (v2 > bv || (v2 == bv && i2 < bi)) { bv = v2; bi = i2; }
    if (v3 > bv || (v3 == bv && i3 < bi)) { bv = v3; bi = i3; }
    tokbuf[b] = bi;
    s_sel = bi;
  }
  __syncthreads();
  // pack next step's embedding A-frags for this batch (512 elems, 2/thread)
  int tokf = s_sel;
  int k = tid * 2;
  pack_e(k, b, (double)emb[(size_t)tokf * ESZ + k], EA3);
  pack_e(k + 1, b, (double)emb[(size_t)tokf * ESZ + k + 1], EA3);
}

// ================= fallback all-f32 path (round-1, proven) =================

__global__ __launch_bounds__(256) void k_initF(const float* __restrict__ h0,
                                               const float* __restrict__ c0,
                                               float* __restrict__ hT,
                                               float* __restrict__ cT) {
  int idx = blockIdx.x * 256 + threadIdx.x;
  int j = idx >> 6, b = idx & 63;
  hT[idx] = h0[b * HSZ + j];
  cT[idx] = c0[b * HSZ + j];
}

__global__ __launch_bounds__(256) void k_gatesF(
    int t, const int* __restrict__ sos, const u64* __restrict__ partials,
    const float* __restrict__ emb, const float* __restrict__ Wx,
    const float* __restrict__ Wh, const float* __restrict__ hT,
    float* __restrict__ gP) {
  __shared__ float xs[128 * 64];
  __shared__ u64 s_red[256];
  __shared__ int s_tok[64];
  int tid = threadIdx.x;
  if (t == 0) {
    if (tid < 64) s_tok[tid] = sos[tid];
  } else {
    int b = tid >> 2, q = tid & 3;
    u64 best = 0ull;
    int i0 = q * 63, i1 = i0 + 63;
    if (i1 > 250) i1 = 250;
    for (int i = i0; i < i1; ++i) {
      u64 v = partials[b * 512 + i];
      if (v > best) best = v;
    }
    s_red[tid] = best;
    __syncthreads();
    if (q == 0) {
      u64 m = best;
      #pragma unroll
      for (int k = 1; k < 4; ++k) {
        u64 v = s_red[tid + k];
        if (v > m) m = v;
      }
      s_tok[b] = (int)(~(unsigned)(m & 0xFFFFFFFFull));
    }
  }
  __syncthreads();
  int colblk = blockIdx.x & 63, ks = blockIdx.x >> 6;
  int col = colblk * 16 + (tid & 15);
  int b0 = (tid >> 4) * 4;
  float acc[4][4];
  #pragma unroll
  for (int g = 0; g < 4; ++g)
    #pragma unroll
    for (int bb = 0; bb < 4; ++bb) acc[g][bb] = 0.f;
  for (int kc = 0; kc < 3; ++kc) {
    int k0 = ks * 384 + kc * 128;
    __syncthreads();
    if (k0 < 512) {
      int b = tid & 63;
      int kk0 = (tid >> 6) * 32;
      const float* erow = emb + (size_t)s_tok[b] * ESZ + k0 + kk0;
      #pragma unroll
      for (int i = 0; i < 32; i += 4) {
        float4 v = *(const float4*)(erow + i);
        xs[(kk0 + i) * 64 + b] = v.x;
        xs[(kk0 + i + 1) * 64 + b] = v.y;
        xs[(kk0 + i + 2) * 64 + b] = v.z;
        xs[(kk0 + i + 3) * 64 + b] = v.w;
      }
    } else {
      const float* src = hT + (size_t)(k0 - 512) * 64;
      #pragma unroll
      for (int i = 0; i < 8192; i += 1024)
        *(float4*)&xs[i + tid * 4] = *(const float4*)(src + i + tid * 4);
    }
    __syncthreads();
    const float* Wb = (k0 < 512) ? (Wx + (size_t)k0 * G4H + col)
                                 : (Wh + (size_t)(k0 - 512) * G4H + col);
    #pragma unroll 4
    for (int kk = 0; kk < 128; ++kk) {
      float4 xv = *(const float4*)&xs[kk * 64 + b0];
      const float* wr = Wb + (size_t)kk * G4H;
      float w0 = wr[0], w1 = wr[1024], w2 = wr[2048], w3 = wr[3072];
      acc[0][0] += w0 * xv.x; acc[0][1] += w0 * xv.y;
      acc[0][2] += w0 * xv.z; acc[0][3] += w0 * xv.w;
      acc[1][0] += w1 * xv.x; acc[1][1] += w1 * xv.y;
      acc[1][2] += w1 * xv.z; acc[1][3] += w1 * xv.w;
      acc[2][0] += w2 * xv.x; acc[2][1] += w2 * xv.y;
      acc[2][2] += w2 * xv.z; acc[2][3] += w2 * xv.w;
      acc[3][0] += w3 * xv.x; acc[3][1] += w3 * xv.y;
      acc[3][2] += w3 * xv.z; acc[3][3] += w3 * xv.w;
    }
  }
  #pragma unroll
  for (int g = 0; g < 4; ++g) {
    float4 v = make_float4(acc[g][0], acc[g][1], acc[g][2], acc[g][3]);
    *(float4*)&gP[((size_t)ks * G4H + g * 1024 + col) * 64 + b0] = v;
  }
}

__global__ __launch_bounds__(256) void k_cellF(const float* __restrict__ gP,
                                               const float* __restrict__ bx,
                                               const float* __restrict__ bh,
                                               float* __restrict__ hT,
                                               float* __restrict__ cT) {
  int flat = (blockIdx.x * 256 + threadIdx.x) * 2;
  int j = flat >> 6;
  float2 gv[4];
  #pragma unroll
  for (int g = 0; g < 4; ++g) {
    size_t base = ((size_t)g * 1024 + j) * 64 + (flat & 63);
    float2 s = *(const float2*)&gP[base];
    #pragma unroll
    for (int ks = 1; ks < 4; ++ks) {
      float2 p = *(const float2*)&gP[(size_t)ks * 262144 + base];
      s.x += p.x; s.y += p.y;
    }
    float bias = bx[g * 1024 + j] + bh[g * 1024 + j];
    s.x += bias; s.y += bias;
    gv[g] = s;
  }
  float2 c = *(const float2*)&cT[flat];
  float fx = 1.f / (1.f + expf(-gv[0].x)), fy = 1.f / (1.f + expf(-gv[0].y));
  float ix = 1.f / (1.f + expf(-gv[1].x)), iy = 1.f / (1.f + expf(-gv[1].y));
  float gx = tanhf(gv[2].x), gy = tanhf(gv[2].y);
  float ox = 1.f / (1.f + expf(-gv[3].x)), oy = 1.f / (1.f + expf(-gv[3].y));
  float cx = fx * c.x + ix * gx, cy = fy * c.y + iy * gy;
  float hx = ox * tanhf(cx), hy = oy * tanhf(cy);
  *(float2*)&cT[flat] = make_float2(cx, cy);
  *(float2*)&hT[flat] = make_float2(hx, hy);
}

__global__ __launch_bounds__(512) void k_logitsF(
    int t, const float* __restrict__ hT, const float* __restrict__ Wout,
    const float* __restrict__ bout, float* __restrict__ out,
    u64* __restrict__ partials) {
  __shared__ float hs[128 * 64];
  int tid = threadIdx.x;
  int lane = tid & 63;
  int bg = tid >> 6;
  int b0 = bg * 8;
  int j0 = blockIdx.x * 128 + lane * 2;
  float a0[8], a1[8];
  #pragma unroll
  for (int i = 0; i < 8; ++i) { a0[i] = 0.f; a1[i] = 0.f; }
  for (int kc = 0; kc < 8; ++kc) {
    int k0 = kc * 128;
    __syncthreads();
    #pragma unroll
    for (int i = 0; i < 8192; i += 2048)
      *(float4*)&hs[i + tid * 4] =
          *(const float4*)&hT[(size_t)k0 * 64 + i + tid * 4];
    __syncthreads();
    #pragma unroll 4
    for (int kk = 0; kk < 128; ++kk) {
      float2 wv = *(const float2*)(Wout + (size_t)(k0 + kk) * VSZ + j0);
      const float* hrow = &hs[kk * 64 + b0];
      float4 h0v = *(const float4*)(hrow);
      float4 h1v = *(const float4*)(hrow + 4);
      a0[0] += h0v.x * wv.x; a1[0] += h0v.x * wv.y;
      a0[1] += h0v.y * wv.x; a1[1] += h0v.y * wv.y;
      a0[2] += h0v.z * wv.x; a1[2] += h0v.z * wv.y;
      a0[3] += h0v.w * wv.x; a1[3] += h0v.w * wv.y;
      a0[4] += h1v.x * wv.x; a1[4] += h1v.x * wv.y;
      a0[5] += h1v.y * wv.x; a1[5] += h1v.y * wv.y;
      a0[6] += h1v.z * wv.x; a1[6] += h1v.z * wv.y;
      a0[7] += h1v.w * wv.x; a1[7] += h1v.w * wv.y;
    }
  }
  float bo0 = bout[j0], bo1 = bout[j0 + 1];
  float* orow = out + (size_t)t * BSZ * VSZ;
  #pragma unroll
  for (int bb = 0; bb < 8; ++bb) {
    float v0 = a0[bb] + bo0, v1 = a1[bb] + bo1;
    *(float2*)(orow + (size_t)(b0 + bb) * VSZ + j0) = make_float2(v0, v1);
    float m; int mi;
    if (v1 > v0) { m = v1; mi = j0 + 1; } else { m = v0; mi = j0; }
    u64 key = ((u64)ordf(m) << 32) | (unsigned)(~mi);
    #pragma unroll
    for (int s = 32; s > 0; s >>= 1) {
      u64 o = __shfl_xor(key, s, 64);
      if (o > key) key = o;
    }
    if (lane == bb) partials[(size_t)(b0 + bb) * 512 + blockIdx.x] = key;
  }
}

extern "C" void kernel_launch(void* const* d_in, const int* in_sizes, int n_in,
                              void* d_out, int out_size, void* d_ws,
                              size_t ws_size, hipStream_t stream) {
  const float* emb  = (const float*)d_in[0];
  const float* Wx   = (const float*)d_in[1];
  const float* bx   = (const float*)d_in[2];
  const float* Wh   = (const float*)d_in[3];
  const float* bh   = (const float*)d_in[4];
  const float* Wout = (const float*)d_in[5];
  const float* bout = (const float*)d_in[6];
  const float* h0   = (const float*)d_in[7];
  const float* c0   = (const float*)d_in[8];
  const int*   sos  = (const int*)d_in[9];
  float* out = (float*)d_out;

  bool mfma = ws_size >= 123814912ULL;

  // ws layout (cumulative byte offsets, audited r12):
  //   cT64 @ 0         size 524288
  //   h64  @ 524288    size 524288
  //   HA2  @ 1048576   size 131072   (128 tiles * 512 u16 * 2B)
  //   HA3a @ 1179648   size 393216   (128 tiles * 3 * 512 u16 * 2B)
  //   HA3b @ 1572864   size 393216
  //   EA3  @ 1966080   size 196608   (64 tiles * 3 * 512 u16 * 2B)
  //   tokb @ 2162688   size 256
  //   p2   @ 2166784   size 2048000  (now uses 64*500*4 u64 = 1024000)
  //   WBL  @ 4214784   size 65536000
  //   WBG  @ 69750784  size 37748736 -> end 107499520
  char* base = (char*)d_ws;
  double* cT64 = (double*)(base);
  double* h64  = (double*)(base + 524288);
  u16*    HA2  = (u16*)(base + 1048576);
  u16*    HA3a = (u16*)(base + 1179648);
  u16*    HA3b = (u16*)(base + 1572864);
  u16*    EA3  = (u16*)(base + 1966080);
  int*    tokb = (int*)(base + 2162688);
  u64*    p2   = (u64*)(base + 2166784);
  u16*    WBL  = (u16*)(base + 4214784);
  u16*    WBG  = (u16*)(base + 69750784);
  // f32-fallback layout overlaps (paths exclusive)
  float* hT = (float*)(base);
  float* cT = (float*)(base + 262144);
  float* gP = (float*)(base + 524288);
  u64* partials = (u64*)(base + 4718592);

  if (mfma) {
    k_wpackL<<<500, 256, 0, stream>>>(Wout, WBL);
    k_wpackG<<<256, 256, 0, stream>>>(Wx, Wh, WBG);
    k_init<<<256, 256, 0, stream>>>(h0, c0, sos, emb, cT64, h64, HA2, HA3b,
                                    EA3);
    for (int t = 0; t < TSZ; ++t) {
      const u16* HA3r = (t & 1) ? HA3a : HA3b;  // gates read h_{t-1}
      u16* HA3w = (t & 1) ? HA3b : HA3a;        // cell writes h_t
      k_gatescell<<<256, 512, 0, stream>>>(EA3, HA3r, WBG, bx, bh, cT64, h64,
                                           HA2, HA3w);
      k_logits_mfma<<<500, 512, 0, stream>>>(t, HA2, WBL, bout, out, p2);
      if (t + 1 < TSZ)  // last step's token is never consumed
        k_refine<<<64, 256, 0, stream>>>(p2, h64, Wout, bout, tokb, emb, EA3);
    }
  } else {
    k_initF<<<256, 256, 0, stream>>>(h0, c0, hT, cT);
    for (int t = 0; t < TSZ; ++t) {
      k_gatesF<<<256, 256, 0, stream>>>(t, sos, partials, emb, Wx, Wh, hT, gP);
      k_cellF<<<128, 256, 0, stream>>>(gP, bx, bh, hT, cT);
      k_logitsF<<<250, 512, 0, stream>>>(t, hT, Wout, bout, out, partials);
    }
  }
}